// Round 9
// baseline (773.359 us; speedup 1.0000x reference)
//
#include <hip/hip_runtime.h>
#include <hip/hip_bf16.h>
#include <cstddef>

constexpr int   kN  = 1024;
constexpr int   kE  = 16384;
constexpr int   kQ  = 8192;
constexpr int   kH  = 32;
constexpr size_t kNN = (size_t)kN * kN;
constexpr float kEPS = 1e-5f;
constexpr int   kCW = 8;              // channel chunk width, pinned (ws_size-proven)
constexpr int   kStatsBlocks = kN;    // one i-row per block

using short8 = __attribute__((ext_vector_type(8))) short;
using f32x4  = __attribute__((ext_vector_type(4))) float;

__device__ __forceinline__ unsigned short f2bf(float f) {
    __hip_bfloat16 h = __float2bfloat16(f);
    return *reinterpret_cast<unsigned short*>(&h);
}

// ---------------- small graph kernels ----------------

__global__ void k_edge(const int* __restrict__ ei, float* __restrict__ deg,
                       unsigned char* __restrict__ adj, unsigned char* __restrict__ adjT) {
    int e = blockIdx.x * 256 + threadIdx.x;
    if (e < kE) {
        int s = ei[e], d = ei[kE + e];
        atomicAdd(&deg[d], 1.0f);
        adj [s * kN + d] = 1;   // eim[s][d]
        adjT[d * kN + s] = 1;   // eim^T
    }
}

__global__ void k_dinv(const float* __restrict__ deg, float* __restrict__ dinv) {
    int n = blockIdx.x * 256 + threadIdx.x;
    if (n < kN) dinv[n] = rsqrtf(deg[n] + 1.0f);
}

__global__ void k_embed(const int* __restrict__ xids, const float* __restrict__ emb,
                        float* __restrict__ x0) {
    int t = blockIdx.x * 256 + threadIdx.x;  // kN*kH threads
    int n = t >> 5, c = t & 31;
    x0[t] = emb[xids[n] * kH + c];
}

// h = x @ W   (kN x 32) @ (32 x 32)
__global__ void k_node_mm(const float* __restrict__ x, const float* __restrict__ W,
                          float* __restrict__ h) {
    __shared__ float Ws[kH * kH];
    int t = threadIdx.x;
    for (int u = t; u < kH * kH; u += 256) Ws[u] = W[u];
    __syncthreads();
    int g = blockIdx.x * 256 + t;
    int n = g >> 5, c = g & 31;
    float acc = 0.f;
#pragma unroll
    for (int d = 0; d < kH; d++) acc = fmaf(x[n * kH + d], Ws[d * kH + c], acc);
    h[g] = acc;
}

__global__ void k_scatter(const int* __restrict__ ei, const float* __restrict__ h,
                          const float* __restrict__ dinv, float* __restrict__ agg) {
    int t = blockIdx.x * 256 + threadIdx.x;  // kE*kH threads
    int e = t >> 5, c = t & 31;
    int s = ei[e], d = ei[kE + e];
    atomicAdd(&agg[d * kH + c], h[s * kH + c] * dinv[s] * dinv[d]);
}

__global__ void k_gcn_post(float* __restrict__ agg, const float* __restrict__ h,
                           const float* __restrict__ dinv, const float* __restrict__ b) {
    int t = blockIdx.x * 256 + threadIdx.x;  // kN*kH
    int n = t >> 5, c = t & 31;
    agg[t] += h[t] * dinv[n] * dinv[n] + b[c];
}

// graphnorm over nodes (per channel), then relu. One block per channel.
__global__ void k_graphnorm(const float* __restrict__ x, float* __restrict__ out,
                            const float* __restrict__ g, const float* __restrict__ b,
                            const float* __restrict__ a, int M) {
    int c = blockIdx.x, t = threadIdx.x;
    float s = 0.f, ss = 0.f;
    for (int m = t; m < M; m += 256) { float v = x[m * kH + c]; s += v; ss += v * v; }
    __shared__ float rs[256], rss[256];
    rs[t] = s; rss[t] = ss;
    __syncthreads();
    for (int o = 128; o > 0; o >>= 1) {
        if (t < o) { rs[t] += rs[t + o]; rss[t] += rss[t + o]; }
        __syncthreads();
    }
    __shared__ float scale, shift;
    if (t == 0) {
        float mu  = rs[0] / (float)M;
        float ac  = a[c];
        float var = rss[0] / (float)M - 2.f * ac * mu * mu + ac * ac * mu * mu;
        float sc  = g[c] * rsqrtf(var + kEPS);
        scale = sc;
        shift = b[c] - sc * ac * mu;
    }
    __syncthreads();
    for (int m = t; m < M; m += 256) {
        float v = scale * x[m * kH + c] + shift;
        out[m * kH + c] = v > 0.f ? v : 0.f;
    }
}

// ---------------- fused x1 / x2^T generation (bf16, channel-major), CW=8 ----------------
// p computed once; X1 from adj, X2^T from adj^T (pair product symmetric).

template<int CW>
__global__ __launch_bounds__(256) void k_genx2(
        const float* __restrict__ xn,
        const unsigned char* __restrict__ adj, const unsigned char* __restrict__ adjT,
        const float* __restrict__ w1, const float* __restrict__ b1,
        const float* __restrict__ w2, const float* __restrict__ b2,
        __hip_bfloat16* __restrict__ X1, __hip_bfloat16* __restrict__ X2t, int c0) {
    __shared__ float W1s[33 * CW], W2s[33 * CW], b1s[CW], b2s[CW], xo[kH];
    __shared__ float xis[256][kH + 1];
    int o = blockIdx.y, i0 = blockIdx.x * 256, t = threadIdx.x;
    for (int u = t; u < 33 * CW; u += 256) {
        int d = u / CW, cc = u % CW;
        W1s[u] = w1[d * kH + c0 + cc];
        W2s[u] = w2[d * kH + c0 + cc];
    }
    if (t < CW) { b1s[t] = b1[c0 + t]; b2s[t] = b2[c0 + t]; }
    if (t < kH) xo[t] = xn[o * kH + t];
    for (int u = t; u < 256 * kH; u += 256) {
        xis[u >> 5][u & 31] = xn[(i0 + (u >> 5)) * kH + (u & 31)];
    }
    __syncthreads();
    int in = i0 + t;
    float p[kH];
#pragma unroll
    for (int d = 0; d < kH; d++) p[d] = xo[d] * xis[t][d];
    float e1 = (float)adj [o * kN + in];
    float e2 = (float)adjT[o * kN + in];
#pragma unroll
    for (int cc = 0; cc < CW; cc++) {
        float v1 = b1s[cc], v2 = b2s[cc];
#pragma unroll
        for (int d = 0; d < kH; d++) {
            v1 = fmaf(p[d], W1s[d * CW + cc], v1);
            v2 = fmaf(p[d], W2s[d * CW + cc], v2);
        }
        v1 = fmaf(e1, W1s[32 * CW + cc], v1);
        v2 = fmaf(e2, W2s[32 * CW + cc], v2);
        X1 [(size_t)cc * kNN + (size_t)o * kN + in] = __float2bfloat16(v1 > 0.f ? v1 : 0.f);
        X2t[(size_t)cc * kNN + (size_t)o * kN + in] = __float2bfloat16(v2 > 0.f ? v2 : 0.f);
    }
}

// ---------------- bf16 MFMA batched GEMM: C[c] = A[c] @ B[c], B given transposed ----------------

__device__ __forceinline__ void g2l16(const unsigned short* g, unsigned short* l) {
    __builtin_amdgcn_global_load_lds(
        (const __attribute__((address_space(1))) void*)g,
        (__attribute__((address_space(3))) void*)l, 16, 0, 0);
}

__global__ __launch_bounds__(256) void k_bgemm_bf16(
        const unsigned short* __restrict__ A_, const unsigned short* __restrict__ Bt_,
        float* __restrict__ C_) {
    int c = blockIdx.z;
    const unsigned short* A  = A_  + (size_t)c * kNN;
    const unsigned short* Bt = Bt_ + (size_t)c * kNN;
    float* C = C_ + (size_t)c * kNN;
    int i0 = blockIdx.y * 128, j0 = blockIdx.x * 128;
    __shared__ unsigned short As[128 * 32];
    __shared__ unsigned short Bs[128 * 32];
    int t = threadIdx.x;
    int lane = t & 63, w = t >> 6;
    int wr = (w >> 1) * 64, wc = (w & 1) * 64;
    int l15 = lane & 15, lhi = lane >> 4;  // 0..3
    int srow = t >> 2, skel = (t & 3) * 8;
    f32x4 acc[4][4] = {};
    for (int k0 = 0; k0 < kN; k0 += 32) {
        g2l16(A  + (size_t)(i0 + srow)      * kN + k0 + skel, As + (size_t)t * 8);
        g2l16(A  + (size_t)(i0 + srow + 64) * kN + k0 + skel, As + (size_t)(t + 256) * 8);
        g2l16(Bt + (size_t)(j0 + srow)      * kN + k0 + skel, Bs + (size_t)t * 8);
        g2l16(Bt + (size_t)(j0 + srow + 64) * kN + k0 + skel, Bs + (size_t)(t + 256) * 8);
        asm volatile("s_waitcnt vmcnt(0)" ::: "memory");
        __syncthreads();
        short8 af[4], bf[4];
#pragma unroll
        for (int m = 0; m < 4; m++)
            af[m] = *(const short8*)&As[(wr + m * 16 + l15) * 32 + lhi * 8];
#pragma unroll
        for (int n = 0; n < 4; n++)
            bf[n] = *(const short8*)&Bs[(wc + n * 16 + l15) * 32 + lhi * 8];
#pragma unroll
        for (int m = 0; m < 4; m++)
#pragma unroll
            for (int n = 0; n < 4; n++)
                acc[m][n] = __builtin_amdgcn_mfma_f32_16x16x32_bf16(af[m], bf[n], acc[m][n], 0, 0, 0);
        __syncthreads();
    }
#pragma unroll
    for (int m = 0; m < 4; m++) {
        int row = i0 + wr + m * 16 + lhi * 4;
#pragma unroll
        for (int n = 0; n < 4; n++) {
            int col = j0 + wc + n * 16 + l15;
#pragma unroll
            for (int r = 0; r < 4; r++)
                C[(size_t)(row + r) * kN + col] = acc[m][n][r];
        }
    }
}

// ---------------- gn3 statistics via MFMA (unchanged from R8) ----------------

__global__ __launch_bounds__(256) void k_stats_mfma(
        const float* __restrict__ xn, const unsigned char* __restrict__ adj,
        const float* __restrict__ prod, const float* __restrict__ w3,
        const float* __restrict__ b3, float* __restrict__ spart) {
    __shared__ unsigned short As[128 * 104];   // 26.6 KB feat tile
    __shared__ unsigned short Bs[32 * 104];    // 6.7 KB W3aug^T [c][k]
    __shared__ float xi[kH], lsum[kH], lssq[kH];
    int t = threadIdx.x;
    int i = blockIdx.x;
    int lane = t & 63, w = t >> 6;
    int l15 = lane & 15, lhi = lane >> 4;

    for (int u = t; u < 128 * 104 / 8; u += 256)
        *(short8*)&As[u * 8] = short8{0, 0, 0, 0, 0, 0, 0, 0};
    {   // W3aug^T: c = t&31, s-range (t>>5)*13..+13
        int c = t & 31, s0 = (t >> 5) * 13;
        for (int s = s0; s < s0 + 13; s++) {
            float v = 0.f;
            if (s <= 32)                 v = w3[s * kH + c];
            else if (s >= 34 && s <= 65) v = w3[(s - 1) * kH + c];
            else if (s == 66)            v = b3[c];
            Bs[c * 104 + s] = f2bf(v);
        }
    }
    if (t < kH) { xi[t] = xn[i * kH + t]; lsum[t] = 0.f; lssq[t] = 0.f; }
    __syncthreads();
    if (t < 128) As[t * 104 + 66] = f2bf(1.0f);   // bias column (persists)

    float s2[2] = {0.f, 0.f}, q22[2] = {0.f, 0.f};
    int wrow = w * 32;

    for (int kt = 0; kt < 8; kt++) {
        int kbase = kt * 128;
        {   // stage p (slots 0..31)
            int r = t >> 1, half = t & 1;
            int k = kbase + r;
            const float* xr = &xn[k * kH + half * 16];
            float4 v0 = *(const float4*)&xr[0];
            float4 v1 = *(const float4*)&xr[4];
            float4 v2 = *(const float4*)&xr[8];
            float4 v3 = *(const float4*)&xr[12];
            const float* xih = &xi[half * 16];
            short8 o0, o1;
            o0[0] = f2bf(xih[0] * v0.x);  o0[1] = f2bf(xih[1] * v0.y);
            o0[2] = f2bf(xih[2] * v0.z);  o0[3] = f2bf(xih[3] * v0.w);
            o0[4] = f2bf(xih[4] * v1.x);  o0[5] = f2bf(xih[5] * v1.y);
            o0[6] = f2bf(xih[6] * v1.z);  o0[7] = f2bf(xih[7] * v1.w);
            o1[0] = f2bf(xih[8] * v2.x);  o1[1] = f2bf(xih[9] * v2.y);
            o1[2] = f2bf(xih[10] * v2.z); o1[3] = f2bf(xih[11] * v2.w);
            o1[4] = f2bf(xih[12] * v3.x); o1[5] = f2bf(xih[13] * v3.y);
            o1[6] = f2bf(xih[14] * v3.z); o1[7] = f2bf(xih[15] * v3.w);
            *(short8*)&As[r * 104 + half * 16]     = o0;
            *(short8*)&As[r * 104 + half * 16 + 8] = o1;
        }
        if (t < 128) As[t * 104 + 32] = f2bf((float)adj[i * kN + kbase + t]);
        {   // stage pr (slots 34..65)
            int kq = t & 15, dp = t >> 4, d2 = dp * 2;
            const float* p0 = &prod[(size_t)d2 * kNN + (size_t)i * kN + kbase + kq * 8];
            const float* p1 = p0 + kNN;
            float4 a0 = *(const float4*)&p0[0];
            float4 a1 = *(const float4*)&p0[4];
            float4 b0 = *(const float4*)&p1[0];
            float4 b1 = *(const float4*)&p1[4];
            float r0[8] = {a0.x, a0.y, a0.z, a0.w, a1.x, a1.y, a1.z, a1.w};
            float r1[8] = {b0.x, b0.y, b0.z, b0.w, b1.x, b1.y, b1.z, b1.w};
            unsigned int* As32 = (unsigned int*)As;
#pragma unroll
            for (int j = 0; j < 8; j++) {
                int jr = (j + kq) & 7;
                int kl = kq * 8 + jr;
                unsigned int val = (unsigned int)f2bf(r0[jr]) |
                                   ((unsigned int)f2bf(r1[jr]) << 16);
                As32[kl * 52 + 17 + dp] = val;
            }
        }
        __syncthreads();
        f32x4 acc[2][2] = {};
#pragma unroll
        for (int ks = 0; ks < 3; ks++) {
            short8 af0 = *(const short8*)&As[(wrow + l15) * 104 + ks * 32 + lhi * 8];
            short8 af1 = *(const short8*)&As[(wrow + 16 + l15) * 104 + ks * 32 + lhi * 8];
            short8 bf0 = *(const short8*)&Bs[l15 * 104 + ks * 32 + lhi * 8];
            short8 bf1 = *(const short8*)&Bs[(16 + l15) * 104 + ks * 32 + lhi * 8];
            acc[0][0] = __builtin_amdgcn_mfma_f32_16x16x32_bf16(af0, bf0, acc[0][0], 0, 0, 0);
            acc[0][1] = __builtin_amdgcn_mfma_f32_16x16x32_bf16(af0, bf1, acc[0][1], 0, 0, 0);
            acc[1][0] = __builtin_amdgcn_mfma_f32_16x16x32_bf16(af1, bf0, acc[1][0], 0, 0, 0);
            acc[1][1] = __builtin_amdgcn_mfma_f32_16x16x32_bf16(af1, bf1, acc[1][1], 0, 0, 0);
        }
#pragma unroll
        for (int ct = 0; ct < 2; ct++)
#pragma unroll
            for (int rt = 0; rt < 2; rt++)
#pragma unroll
                for (int r = 0; r < 4; r++) {
                    float y = acc[rt][ct][r];
                    s2[ct] += y;
                    q22[ct] = fmaf(y, y, q22[ct]);
                }
        __syncthreads();
    }
#pragma unroll
    for (int ct = 0; ct < 2; ct++) {
        s2[ct]  += __shfl_xor(s2[ct], 16);  s2[ct]  += __shfl_xor(s2[ct], 32);
        q22[ct] += __shfl_xor(q22[ct], 16); q22[ct] += __shfl_xor(q22[ct], 32);
    }
    if (lane < 16) {
#pragma unroll
        for (int ct = 0; ct < 2; ct++) {
            atomicAdd(&lsum[ct * 16 + l15], s2[ct]);
            atomicAdd(&lssq[ct * 16 + l15], q22[ct]);
        }
    }
    __syncthreads();
    if (t < kH)          spart[(size_t)i * 64 + t]             = lsum[t];
    else if (t < 2 * kH) spart[(size_t)i * 64 + 32 + (t - kH)] = lssq[t - kH];
}

// parallel reduce spart[1024][64] -> stats[64]
__global__ __launch_bounds__(256) void k_reduce(const float* __restrict__ spart,
                                                float* __restrict__ stats) {
    int slot = blockIdx.x;   // 64 blocks
    int t = threadIdx.x;
    float acc = 0.f;
    for (int r = t; r < kStatsBlocks; r += 256) acc += spart[(size_t)r * 64 + slot];
    __shared__ float red[256];
    red[t] = acc;
    __syncthreads();
    for (int o = 128; o > 0; o >>= 1) {
        if (t < o) red[t] += red[t + o];
        __syncthreads();
    }
    if (t == 0) stats[slot] = red[0];
}

__global__ void k_finalize(const float* __restrict__ stats, const float* __restrict__ g,
                           const float* __restrict__ b, const float* __restrict__ a,
                           float* __restrict__ ss) {
    int c = threadIdx.x;  // 32 threads
    float M   = (float)((double)kNN);
    float mu  = stats[c] / M;
    float ac  = a[c];
    float var = stats[kH + c] / M - 2.f * ac * mu * mu + ac * ac * mu * mu;
    float sc  = g[c] * rsqrtf(var + kEPS);
    ss[c]      = sc;
    ss[kH + c] = b[c] - sc * ac * mu;
}

// ---------------- final: one wave per query, lanes = (direction, channel) ----------------
// lane = h*32 + c: h=0 computes y1[c] at (i,k); h=1 computes y2[c] at (k,i).
// Each lane loads ONE scattered prod value (d = lane&31 for its direction);
// p/pr distributed via shfl; z1*z2 paired via shfl_xor(32); butterfly over c.

__global__ __launch_bounds__(256) void k_out(
        const int* __restrict__ pos, const float* __restrict__ xn,
        const unsigned char* __restrict__ adj, const float* __restrict__ prod,
        const float* __restrict__ w3, const float* __restrict__ b3,
        const float* __restrict__ ss, const float* __restrict__ wdir,
        const float* __restrict__ bdir, float* __restrict__ out) {
    __shared__ float W3s[65 * kH], b3s[kH], scs[kH], shs[kH], wd[kH];
    int t = threadIdx.x;
    for (int u = t; u < 65 * kH; u += 256) W3s[u] = w3[u];
    if (t < kH) { b3s[t] = b3[t]; scs[t] = ss[t]; shs[t] = ss[kH + t]; wd[t] = wdir[t]; }
    __syncthreads();
    int q = blockIdx.x * 4 + (t >> 6);
    int lane = t & 63;
    int c = lane & 31, h = lane >> 5;
    int i = pos[2 * q], k = pos[2 * q + 1];
    size_t addr = h ? ((size_t)k * kN + i) : ((size_t)i * kN + k);
    // per-lane single loads
    float pr_reg = prod[(size_t)c * kNN + addr];      // my direction, channel index c
    float p_reg  = xn[i * kH + c] * xn[k * kH + c];   // symmetric in (i,k)
    float e_reg  = (float)adj[addr];
    // y for (direction h, channel c)
    float y = b3s[c];
#pragma unroll
    for (int d = 0; d < kH; d++)
        y = fmaf(__shfl(p_reg, d), W3s[d * kH + c], y);
    y = fmaf(e_reg, W3s[32 * kH + c], y);
#pragma unroll
    for (int d = 0; d < kH; d++)
        y = fmaf(__shfl(pr_reg, (h << 5) + d), W3s[(33 + d) * kH + c], y);
    float z = scs[c] * y + shs[c];
    z = z > 0.f ? z : 0.f;
    float zo = __shfl_xor(z, 32);        // other direction, same channel
    float v = z * zo * wd[c];
#pragma unroll
    for (int o = 16; o > 0; o >>= 1) v += __shfl_xor(v, o);
    if (lane == 0) out[q] = v + bdir[0];
}

// ---------------- launch ----------------

extern "C" void kernel_launch(void* const* d_in, const int* in_sizes, int n_in,
                              void* d_out, int out_size, void* d_ws, size_t ws_size,
                              hipStream_t stream) {
    const int*   x_ids = (const int*)d_in[0];
    const int*   ei    = (const int*)d_in[1];
    const int*   pos   = (const int*)d_in[2];
    const float* emb   = (const float*)d_in[3];
    const float* gw0   = (const float*)d_in[4];
    const float* gb0   = (const float*)d_in[5];
    const float* g0g   = (const float*)d_in[6];
    const float* g0b   = (const float*)d_in[7];
    const float* g0a   = (const float*)d_in[8];
    const float* gw1   = (const float*)d_in[9];
    const float* gb1   = (const float*)d_in[10];
    const float* g1g   = (const float*)d_in[11];
    const float* g1b   = (const float*)d_in[12];
    const float* g1a   = (const float*)d_in[13];
    const float* wm1   = (const float*)d_in[14];
    const float* bm1   = (const float*)d_in[15];
    const float* wm2   = (const float*)d_in[16];
    const float* bm2   = (const float*)d_in[17];
    const float* wm3   = (const float*)d_in[18];
    const float* bm3   = (const float*)d_in[19];
    const float* g3g   = (const float*)d_in[20];
    const float* g3b   = (const float*)d_in[21];
    const float* g3a   = (const float*)d_in[22];
    const float* wdir  = (const float*)d_in[23];
    const float* bdir  = (const float*)d_in[24];
    float* out = (float*)d_out;

    // workspace layout — fixed CW=8, total demand ~162.9 MB (ws_size-proven fit)
    const size_t fixedF = (size_t)kH * kNN;                       // prod floats
    float* prod = (float*)d_ws;                                   // 128 MB
    unsigned short* X1c = (unsigned short*)(prod + fixedF);       // 16 MB bf16
    unsigned short* X2c = X1c + (size_t)kCW * kNN;                // 16 MB bf16 (transposed)
    unsigned char* adj  = (unsigned char*)(X2c + (size_t)kCW * kNN);  // 1 MB
    unsigned char* adjT = adj + kNN;                                   // 1 MB
    float* deg   = (float*)(adjT + kNN);
    float* dinv  = deg + kN;
    float* x0    = dinv + kN;
    float* h     = x0 + kN * kH;
    float* agg   = h + kN * kH;
    float* xa    = agg + kN * kH;
    float* xb    = xa + kN * kH;
    float* spart = xb + kN * kH;                 // 1024*64 floats (256 KB)
    float* stats = spart + (size_t)kStatsBlocks * 64;
    float* ss    = stats + 2 * kH;

    hipMemsetAsync(deg, 0, kN * sizeof(float), stream);
    hipMemsetAsync(adj, 0, 2 * kNN, stream);   // adj + adjT contiguous
    hipMemsetAsync(agg, 0, kN * kH * sizeof(float), stream);

    k_edge<<<(kE + 255) / 256, 256, 0, stream>>>(ei, deg, adj, adjT);
    k_dinv<<<4, 256, 0, stream>>>(deg, dinv);
    k_embed<<<kN * kH / 256, 256, 0, stream>>>(x_ids, emb, x0);

    // GCN layer 0
    k_node_mm<<<kN * kH / 256, 256, 0, stream>>>(x0, gw0, h);
    k_scatter<<<kE * kH / 256, 256, 0, stream>>>(ei, h, dinv, agg);
    k_gcn_post<<<kN * kH / 256, 256, 0, stream>>>(agg, h, dinv, gb0);
    k_graphnorm<<<kH, 256, 0, stream>>>(agg, xa, g0g, g0b, g0a, kN);

    // GCN layer 1
    hipMemsetAsync(agg, 0, kN * kH * sizeof(float), stream);
    k_node_mm<<<kN * kH / 256, 256, 0, stream>>>(xa, gw1, h);
    k_scatter<<<kE * kH / 256, 256, 0, stream>>>(ei, h, dinv, agg);
    k_gcn_post<<<kN * kH / 256, 256, 0, stream>>>(agg, h, dinv, gb1);
    k_graphnorm<<<kH, 256, 0, stream>>>(agg, xb, g1g, g1b, g1a, kN);

    // fused pairwise bf16 features + batched MFMA GEMMs, CW=8
    for (int c0 = 0; c0 < kH; c0 += kCW) {
        k_genx2<kCW><<<dim3(4, kN), 256, 0, stream>>>(
            xb, adj, adjT, wm1, bm1, wm2, bm2,
            (__hip_bfloat16*)X1c, (__hip_bfloat16*)X2c, c0);
        k_bgemm_bf16<<<dim3(8, 8, kCW), 256, 0, stream>>>(X1c, X2c, prod + (size_t)c0 * kNN);
    }

    // gn3 stats: MFMA projection, y never materialized
    k_stats_mfma<<<kStatsBlocks, 256, 0, stream>>>(xb, adj, prod, wm3, bm3, spart);
    k_reduce<<<64, 256, 0, stream>>>(spart, stats);
    k_finalize<<<1, 32, 0, stream>>>(stats, g3g, g3b, g3a, ss);

    // final gather: one wave per query
    k_out<<<kQ / 4, 256, 0, stream>>>(pos, xb, adj, prod, wm3, bm3, ss, wdir, bdir, out);
}

// Round 10
// 541.861 us; speedup vs baseline: 1.4272x; 1.4272x over previous
//
#include <hip/hip_runtime.h>
#include <hip/hip_bf16.h>
#include <cstddef>

constexpr int   kN  = 1024;
constexpr int   kE  = 16384;
constexpr int   kQ  = 8192;
constexpr int   kH  = 32;
constexpr size_t kNN = (size_t)kN * kN;
constexpr float kEPS = 1e-5f;
constexpr int   kCW = 8;              // channel chunk width, pinned; UNFUSED genx only
constexpr int   kStatsBlocks = kN;    // one i-row per block

using short8 = __attribute__((ext_vector_type(8))) short;
using f32x4  = __attribute__((ext_vector_type(4))) float;

__device__ __forceinline__ unsigned short f2bf(float f) {
    __hip_bfloat16 h = __float2bfloat16(f);
    return *reinterpret_cast<unsigned short*>(&h);
}

// ---------------- small graph kernels ----------------

__global__ void k_edge(const int* __restrict__ ei, float* __restrict__ deg,
                       unsigned char* __restrict__ adj, unsigned char* __restrict__ adjT) {
    int e = blockIdx.x * 256 + threadIdx.x;
    if (e < kE) {
        int s = ei[e], d = ei[kE + e];
        atomicAdd(&deg[d], 1.0f);
        adj [s * kN + d] = 1;   // eim[s][d]
        adjT[d * kN + s] = 1;   // eim^T
    }
}

__global__ void k_dinv(const float* __restrict__ deg, float* __restrict__ dinv) {
    int n = blockIdx.x * 256 + threadIdx.x;
    if (n < kN) dinv[n] = rsqrtf(deg[n] + 1.0f);
}

__global__ void k_embed(const int* __restrict__ xids, const float* __restrict__ emb,
                        float* __restrict__ x0) {
    int t = blockIdx.x * 256 + threadIdx.x;  // kN*kH threads
    int n = t >> 5, c = t & 31;
    x0[t] = emb[xids[n] * kH + c];
}

// h = x @ W   (kN x 32) @ (32 x 32)
__global__ void k_node_mm(const float* __restrict__ x, const float* __restrict__ W,
                          float* __restrict__ h) {
    __shared__ float Ws[kH * kH];
    int t = threadIdx.x;
    for (int u = t; u < kH * kH; u += 256) Ws[u] = W[u];
    __syncthreads();
    int g = blockIdx.x * 256 + t;
    int n = g >> 5, c = g & 31;
    float acc = 0.f;
#pragma unroll
    for (int d = 0; d < kH; d++) acc = fmaf(x[n * kH + d], Ws[d * kH + c], acc);
    h[g] = acc;
}

__global__ void k_scatter(const int* __restrict__ ei, const float* __restrict__ h,
                          const float* __restrict__ dinv, float* __restrict__ agg) {
    int t = blockIdx.x * 256 + threadIdx.x;  // kE*kH threads
    int e = t >> 5, c = t & 31;
    int s = ei[e], d = ei[kE + e];
    atomicAdd(&agg[d * kH + c], h[s * kH + c] * dinv[s] * dinv[d]);
}

__global__ void k_gcn_post(float* __restrict__ agg, const float* __restrict__ h,
                           const float* __restrict__ dinv, const float* __restrict__ b) {
    int t = blockIdx.x * 256 + threadIdx.x;  // kN*kH
    int n = t >> 5, c = t & 31;
    agg[t] += h[t] * dinv[n] * dinv[n] + b[c];
}

// graphnorm over nodes (per channel), then relu. One block per channel.
__global__ void k_graphnorm(const float* __restrict__ x, float* __restrict__ out,
                            const float* __restrict__ g, const float* __restrict__ b,
                            const float* __restrict__ a, int M) {
    int c = blockIdx.x, t = threadIdx.x;
    float s = 0.f, ss = 0.f;
    for (int m = t; m < M; m += 256) { float v = x[m * kH + c]; s += v; ss += v * v; }
    __shared__ float rs[256], rss[256];
    rs[t] = s; rss[t] = ss;
    __syncthreads();
    for (int o = 128; o > 0; o >>= 1) {
        if (t < o) { rs[t] += rs[t + o]; rss[t] += rss[t + o]; }
        __syncthreads();
    }
    __shared__ float scale, shift;
    if (t == 0) {
        float mu  = rs[0] / (float)M;
        float ac  = a[c];
        float var = rss[0] / (float)M - 2.f * ac * mu * mu + ac * ac * mu * mu;
        float sc  = g[c] * rsqrtf(var + kEPS);
        scale = sc;
        shift = b[c] - sc * ac * mu;
    }
    __syncthreads();
    for (int m = t; m < M; m += 256) {
        float v = scale * x[m * kH + c] + shift;
        out[m * kH + c] = v > 0.f ? v : 0.f;
    }
}

// ---------------- x1 / x2^T generation (bf16, channel-major) — UNFUSED, R8-proven ----------------
// NOTE: do NOT fuse X1+X2 into one kernel (R4/R9 regressions: dual-accumulator
// full unroll -> 144 VGPR, 10% occupancy, 3.4x slower).

template<int CW>
__global__ __launch_bounds__(256) void k_genx(
        const float* __restrict__ xn, const unsigned char* __restrict__ adjX,
        const float* __restrict__ w, const float* __restrict__ b,
        __hip_bfloat16* __restrict__ X, int c0) {
    __shared__ float Ws[33 * CW], bs[CW], xo[kH];
    __shared__ float xis[256][kH + 1];
    int o = blockIdx.y, i0 = blockIdx.x * 256, t = threadIdx.x;
    for (int u = t; u < 33 * CW; u += 256) {
        int d = u / CW, cc = u % CW;
        Ws[u] = w[d * kH + c0 + cc];
    }
    if (t < CW) bs[t] = b[c0 + t];
    if (t < kH) xo[t] = xn[o * kH + t];
    for (int u = t; u < 256 * kH; u += 256) {
        xis[u >> 5][u & 31] = xn[(i0 + (u >> 5)) * kH + (u & 31)];
    }
    __syncthreads();
    int in = i0 + t;
    float p[kH];
#pragma unroll
    for (int d = 0; d < kH; d++) p[d] = xo[d] * xis[t][d];
    float e = (float)adjX[o * kN + in];
#pragma unroll
    for (int cc = 0; cc < CW; cc++) {
        float v = bs[cc];
#pragma unroll
        for (int d = 0; d < kH; d++) v = fmaf(p[d], Ws[d * CW + cc], v);
        v = fmaf(e, Ws[32 * CW + cc], v);
        X[(size_t)cc * kNN + (size_t)o * kN + in] = __float2bfloat16(v > 0.f ? v : 0.f);
    }
}

// ---------------- bf16 MFMA batched GEMM: C[c] = A[c] @ B[c], B given transposed ----------------

__device__ __forceinline__ void g2l16(const unsigned short* g, unsigned short* l) {
    __builtin_amdgcn_global_load_lds(
        (const __attribute__((address_space(1))) void*)g,
        (__attribute__((address_space(3))) void*)l, 16, 0, 0);
}

__global__ __launch_bounds__(256) void k_bgemm_bf16(
        const unsigned short* __restrict__ A_, const unsigned short* __restrict__ Bt_,
        float* __restrict__ C_) {
    int c = blockIdx.z;
    const unsigned short* A  = A_  + (size_t)c * kNN;
    const unsigned short* Bt = Bt_ + (size_t)c * kNN;
    float* C = C_ + (size_t)c * kNN;
    int i0 = blockIdx.y * 128, j0 = blockIdx.x * 128;
    __shared__ unsigned short As[128 * 32];
    __shared__ unsigned short Bs[128 * 32];
    int t = threadIdx.x;
    int lane = t & 63, w = t >> 6;
    int wr = (w >> 1) * 64, wc = (w & 1) * 64;
    int l15 = lane & 15, lhi = lane >> 4;  // 0..3
    int srow = t >> 2, skel = (t & 3) * 8;
    f32x4 acc[4][4] = {};
    for (int k0 = 0; k0 < kN; k0 += 32) {
        g2l16(A  + (size_t)(i0 + srow)      * kN + k0 + skel, As + (size_t)t * 8);
        g2l16(A  + (size_t)(i0 + srow + 64) * kN + k0 + skel, As + (size_t)(t + 256) * 8);
        g2l16(Bt + (size_t)(j0 + srow)      * kN + k0 + skel, Bs + (size_t)t * 8);
        g2l16(Bt + (size_t)(j0 + srow + 64) * kN + k0 + skel, Bs + (size_t)(t + 256) * 8);
        asm volatile("s_waitcnt vmcnt(0)" ::: "memory");
        __syncthreads();
        short8 af[4], bf[4];
#pragma unroll
        for (int m = 0; m < 4; m++)
            af[m] = *(const short8*)&As[(wr + m * 16 + l15) * 32 + lhi * 8];
#pragma unroll
        for (int n = 0; n < 4; n++)
            bf[n] = *(const short8*)&Bs[(wc + n * 16 + l15) * 32 + lhi * 8];
#pragma unroll
        for (int m = 0; m < 4; m++)
#pragma unroll
            for (int n = 0; n < 4; n++)
                acc[m][n] = __builtin_amdgcn_mfma_f32_16x16x32_bf16(af[m], bf[n], acc[m][n], 0, 0, 0);
        __syncthreads();
    }
#pragma unroll
    for (int m = 0; m < 4; m++) {
        int row = i0 + wr + m * 16 + lhi * 4;
#pragma unroll
        for (int n = 0; n < 4; n++) {
            int col = j0 + wc + n * 16 + l15;
#pragma unroll
            for (int r = 0; r < 4; r++)
                C[(size_t)(row + r) * kN + col] = acc[m][n][r];
        }
    }
}

// ---------------- gn3 statistics via MFMA (R8-proven) ----------------

__global__ __launch_bounds__(256) void k_stats_mfma(
        const float* __restrict__ xn, const unsigned char* __restrict__ adj,
        const float* __restrict__ prod, const float* __restrict__ w3,
        const float* __restrict__ b3, float* __restrict__ spart) {
    __shared__ unsigned short As[128 * 104];   // 26.6 KB feat tile
    __shared__ unsigned short Bs[32 * 104];    // 6.7 KB W3aug^T [c][k]
    __shared__ float xi[kH], lsum[kH], lssq[kH];
    int t = threadIdx.x;
    int i = blockIdx.x;
    int lane = t & 63, w = t >> 6;
    int l15 = lane & 15, lhi = lane >> 4;

    for (int u = t; u < 128 * 104 / 8; u += 256)
        *(short8*)&As[u * 8] = short8{0, 0, 0, 0, 0, 0, 0, 0};
    {   // W3aug^T: c = t&31, s-range (t>>5)*13..+13
        int c = t & 31, s0 = (t >> 5) * 13;
        for (int s = s0; s < s0 + 13; s++) {
            float v = 0.f;
            if (s <= 32)                 v = w3[s * kH + c];
            else if (s >= 34 && s <= 65) v = w3[(s - 1) * kH + c];
            else if (s == 66)            v = b3[c];
            Bs[c * 104 + s] = f2bf(v);
        }
    }
    if (t < kH) { xi[t] = xn[i * kH + t]; lsum[t] = 0.f; lssq[t] = 0.f; }
    __syncthreads();
    if (t < 128) As[t * 104 + 66] = f2bf(1.0f);   // bias column (persists)

    float s2[2] = {0.f, 0.f}, q22[2] = {0.f, 0.f};
    int wrow = w * 32;

    for (int kt = 0; kt < 8; kt++) {
        int kbase = kt * 128;
        {   // stage p (slots 0..31)
            int r = t >> 1, half = t & 1;
            int k = kbase + r;
            const float* xr = &xn[k * kH + half * 16];
            float4 v0 = *(const float4*)&xr[0];
            float4 v1 = *(const float4*)&xr[4];
            float4 v2 = *(const float4*)&xr[8];
            float4 v3 = *(const float4*)&xr[12];
            const float* xih = &xi[half * 16];
            short8 o0, o1;
            o0[0] = f2bf(xih[0] * v0.x);  o0[1] = f2bf(xih[1] * v0.y);
            o0[2] = f2bf(xih[2] * v0.z);  o0[3] = f2bf(xih[3] * v0.w);
            o0[4] = f2bf(xih[4] * v1.x);  o0[5] = f2bf(xih[5] * v1.y);
            o0[6] = f2bf(xih[6] * v1.z);  o0[7] = f2bf(xih[7] * v1.w);
            o1[0] = f2bf(xih[8] * v2.x);  o1[1] = f2bf(xih[9] * v2.y);
            o1[2] = f2bf(xih[10] * v2.z); o1[3] = f2bf(xih[11] * v2.w);
            o1[4] = f2bf(xih[12] * v3.x); o1[5] = f2bf(xih[13] * v3.y);
            o1[6] = f2bf(xih[14] * v3.z); o1[7] = f2bf(xih[15] * v3.w);
            *(short8*)&As[r * 104 + half * 16]     = o0;
            *(short8*)&As[r * 104 + half * 16 + 8] = o1;
        }
        if (t < 128) As[t * 104 + 32] = f2bf((float)adj[i * kN + kbase + t]);
        {   // stage pr (slots 34..65)
            int kq = t & 15, dp = t >> 4, d2 = dp * 2;
            const float* p0 = &prod[(size_t)d2 * kNN + (size_t)i * kN + kbase + kq * 8];
            const float* p1 = p0 + kNN;
            float4 a0 = *(const float4*)&p0[0];
            float4 a1 = *(const float4*)&p0[4];
            float4 b0 = *(const float4*)&p1[0];
            float4 b1 = *(const float4*)&p1[4];
            float r0[8] = {a0.x, a0.y, a0.z, a0.w, a1.x, a1.y, a1.z, a1.w};
            float r1[8] = {b0.x, b0.y, b0.z, b0.w, b1.x, b1.y, b1.z, b1.w};
            unsigned int* As32 = (unsigned int*)As;
#pragma unroll
            for (int j = 0; j < 8; j++) {
                int jr = (j + kq) & 7;
                int kl = kq * 8 + jr;
                unsigned int val = (unsigned int)f2bf(r0[jr]) |
                                   ((unsigned int)f2bf(r1[jr]) << 16);
                As32[kl * 52 + 17 + dp] = val;
            }
        }
        __syncthreads();
        f32x4 acc[2][2] = {};
#pragma unroll
        for (int ks = 0; ks < 3; ks++) {
            short8 af0 = *(const short8*)&As[(wrow + l15) * 104 + ks * 32 + lhi * 8];
            short8 af1 = *(const short8*)&As[(wrow + 16 + l15) * 104 + ks * 32 + lhi * 8];
            short8 bf0 = *(const short8*)&Bs[l15 * 104 + ks * 32 + lhi * 8];
            short8 bf1 = *(const short8*)&Bs[(16 + l15) * 104 + ks * 32 + lhi * 8];
            acc[0][0] = __builtin_amdgcn_mfma_f32_16x16x32_bf16(af0, bf0, acc[0][0], 0, 0, 0);
            acc[0][1] = __builtin_amdgcn_mfma_f32_16x16x32_bf16(af0, bf1, acc[0][1], 0, 0, 0);
            acc[1][0] = __builtin_amdgcn_mfma_f32_16x16x32_bf16(af1, bf0, acc[1][0], 0, 0, 0);
            acc[1][1] = __builtin_amdgcn_mfma_f32_16x16x32_bf16(af1, bf1, acc[1][1], 0, 0, 0);
        }
#pragma unroll
        for (int ct = 0; ct < 2; ct++)
#pragma unroll
            for (int rt = 0; rt < 2; rt++)
#pragma unroll
                for (int r = 0; r < 4; r++) {
                    float y = acc[rt][ct][r];
                    s2[ct] += y;
                    q22[ct] = fmaf(y, y, q22[ct]);
                }
        __syncthreads();
    }
#pragma unroll
    for (int ct = 0; ct < 2; ct++) {
        s2[ct]  += __shfl_xor(s2[ct], 16);  s2[ct]  += __shfl_xor(s2[ct], 32);
        q22[ct] += __shfl_xor(q22[ct], 16); q22[ct] += __shfl_xor(q22[ct], 32);
    }
    if (lane < 16) {
#pragma unroll
        for (int ct = 0; ct < 2; ct++) {
            atomicAdd(&lsum[ct * 16 + l15], s2[ct]);
            atomicAdd(&lssq[ct * 16 + l15], q22[ct]);
        }
    }
    __syncthreads();
    if (t < kH)          spart[(size_t)i * 64 + t]             = lsum[t];
    else if (t < 2 * kH) spart[(size_t)i * 64 + 32 + (t - kH)] = lssq[t - kH];
}

// parallel reduce spart[1024][64] -> stats[64]
__global__ __launch_bounds__(256) void k_reduce(const float* __restrict__ spart,
                                                float* __restrict__ stats) {
    int slot = blockIdx.x;   // 64 blocks
    int t = threadIdx.x;
    float acc = 0.f;
    for (int r = t; r < kStatsBlocks; r += 256) acc += spart[(size_t)r * 64 + slot];
    __shared__ float red[256];
    red[t] = acc;
    __syncthreads();
    for (int o = 128; o > 0; o >>= 1) {
        if (t < o) red[t] += red[t + o];
        __syncthreads();
    }
    if (t == 0) stats[slot] = red[0];
}

__global__ void k_finalize(const float* __restrict__ stats, const float* __restrict__ g,
                           const float* __restrict__ b, const float* __restrict__ a,
                           float* __restrict__ ss) {
    int c = threadIdx.x;  // 32 threads
    float M   = (float)((double)kNN);
    float mu  = stats[c] / M;
    float ac  = a[c];
    float var = stats[kH + c] / M - 2.f * ac * mu * mu + ac * ac * mu * mu;
    float sc  = g[c] * rsqrtf(var + kEPS);
    ss[c]      = sc;
    ss[kH + c] = b[c] - sc * ac * mu;
}

// ---------------- final: one wave per query (R9-verified) ----------------

__global__ __launch_bounds__(256) void k_out(
        const int* __restrict__ pos, const float* __restrict__ xn,
        const unsigned char* __restrict__ adj, const float* __restrict__ prod,
        const float* __restrict__ w3, const float* __restrict__ b3,
        const float* __restrict__ ss, const float* __restrict__ wdir,
        const float* __restrict__ bdir, float* __restrict__ out) {
    __shared__ float W3s[65 * kH], b3s[kH], scs[kH], shs[kH], wd[kH];
    int t = threadIdx.x;
    for (int u = t; u < 65 * kH; u += 256) W3s[u] = w3[u];
    if (t < kH) { b3s[t] = b3[t]; scs[t] = ss[t]; shs[t] = ss[kH + t]; wd[t] = wdir[t]; }
    __syncthreads();
    int q = blockIdx.x * 4 + (t >> 6);
    int lane = t & 63;
    int c = lane & 31, h = lane >> 5;
    int i = pos[2 * q], k = pos[2 * q + 1];
    size_t addr = h ? ((size_t)k * kN + i) : ((size_t)i * kN + k);
    float pr_reg = prod[(size_t)c * kNN + addr];      // my direction, channel index c
    float p_reg  = xn[i * kH + c] * xn[k * kH + c];   // symmetric in (i,k)
    float e_reg  = (float)adj[addr];
    float y = b3s[c];
#pragma unroll
    for (int d = 0; d < kH; d++)
        y = fmaf(__shfl(p_reg, d), W3s[d * kH + c], y);
    y = fmaf(e_reg, W3s[32 * kH + c], y);
#pragma unroll
    for (int d = 0; d < kH; d++)
        y = fmaf(__shfl(pr_reg, (h << 5) + d), W3s[(33 + d) * kH + c], y);
    float z = scs[c] * y + shs[c];
    z = z > 0.f ? z : 0.f;
    float zo = __shfl_xor(z, 32);        // other direction, same channel
    float v = z * zo * wd[c];
#pragma unroll
    for (int o = 16; o > 0; o >>= 1) v += __shfl_xor(v, o);
    if (lane == 0) out[q] = v + bdir[0];
}

// ---------------- launch ----------------

extern "C" void kernel_launch(void* const* d_in, const int* in_sizes, int n_in,
                              void* d_out, int out_size, void* d_ws, size_t ws_size,
                              hipStream_t stream) {
    const int*   x_ids = (const int*)d_in[0];
    const int*   ei    = (const int*)d_in[1];
    const int*   pos   = (const int*)d_in[2];
    const float* emb   = (const float*)d_in[3];
    const float* gw0   = (const float*)d_in[4];
    const float* gb0   = (const float*)d_in[5];
    const float* g0g   = (const float*)d_in[6];
    const float* g0b   = (const float*)d_in[7];
    const float* g0a   = (const float*)d_in[8];
    const float* gw1   = (const float*)d_in[9];
    const float* gb1   = (const float*)d_in[10];
    const float* g1g   = (const float*)d_in[11];
    const float* g1b   = (const float*)d_in[12];
    const float* g1a   = (const float*)d_in[13];
    const float* wm1   = (const float*)d_in[14];
    const float* bm1   = (const float*)d_in[15];
    const float* wm2   = (const float*)d_in[16];
    const float* bm2   = (const float*)d_in[17];
    const float* wm3   = (const float*)d_in[18];
    const float* bm3   = (const float*)d_in[19];
    const float* g3g   = (const float*)d_in[20];
    const float* g3b   = (const float*)d_in[21];
    const float* g3a   = (const float*)d_in[22];
    const float* wdir  = (const float*)d_in[23];
    const float* bdir  = (const float*)d_in[24];
    float* out = (float*)d_out;

    // workspace layout — fixed CW=8, total demand ~162.9 MB (proven fit)
    const size_t fixedF = (size_t)kH * kNN;                       // prod floats
    float* prod = (float*)d_ws;                                   // 128 MB
    unsigned short* X1c = (unsigned short*)(prod + fixedF);       // 16 MB bf16
    unsigned short* X2c = X1c + (size_t)kCW * kNN;                // 16 MB bf16 (transposed)
    unsigned char* adj  = (unsigned char*)(X2c + (size_t)kCW * kNN);  // 1 MB
    unsigned char* adjT = adj + kNN;                                   // 1 MB
    float* deg   = (float*)(adjT + kNN);
    float* dinv  = deg + kN;
    float* x0    = dinv + kN;
    float* h     = x0 + kN * kH;
    float* agg   = h + kN * kH;
    float* xa    = agg + kN * kH;
    float* xb    = xa + kN * kH;
    float* spart = xb + kN * kH;                 // 1024*64 floats (256 KB)
    float* stats = spart + (size_t)kStatsBlocks * 64;
    float* ss    = stats + 2 * kH;

    hipMemsetAsync(deg, 0, kN * sizeof(float), stream);
    hipMemsetAsync(adj, 0, 2 * kNN, stream);   // adj + adjT contiguous
    hipMemsetAsync(agg, 0, kN * kH * sizeof(float), stream);

    k_edge<<<(kE + 255) / 256, 256, 0, stream>>>(ei, deg, adj, adjT);
    k_dinv<<<4, 256, 0, stream>>>(deg, dinv);
    k_embed<<<kN * kH / 256, 256, 0, stream>>>(x_ids, emb, x0);

    // GCN layer 0
    k_node_mm<<<kN * kH / 256, 256, 0, stream>>>(x0, gw0, h);
    k_scatter<<<kE * kH / 256, 256, 0, stream>>>(ei, h, dinv, agg);
    k_gcn_post<<<kN * kH / 256, 256, 0, stream>>>(agg, h, dinv, gb0);
    k_graphnorm<<<kH, 256, 0, stream>>>(agg, xa, g0g, g0b, g0a, kN);

    // GCN layer 1
    hipMemsetAsync(agg, 0, kN * kH * sizeof(float), stream);
    k_node_mm<<<kN * kH / 256, 256, 0, stream>>>(xa, gw1, h);
    k_scatter<<<kE * kH / 256, 256, 0, stream>>>(ei, h, dinv, agg);
    k_gcn_post<<<kN * kH / 256, 256, 0, stream>>>(agg, h, dinv, gb1);
    k_graphnorm<<<kH, 256, 0, stream>>>(agg, xb, g1g, g1b, g1a, kN);

    // pairwise bf16 features (UNFUSED) + batched MFMA GEMMs, CW=8
    for (int c0 = 0; c0 < kH; c0 += kCW) {
        k_genx<kCW><<<dim3(4, kN), 256, 0, stream>>>(xb, adj,  wm1, bm1,
                                                     (__hip_bfloat16*)X1c, c0);
        k_genx<kCW><<<dim3(4, kN), 256, 0, stream>>>(xb, adjT, wm2, bm2,
                                                     (__hip_bfloat16*)X2c, c0);
        k_bgemm_bf16<<<dim3(8, 8, kCW), 256, 0, stream>>>(X1c, X2c, prod + (size_t)c0 * kNN);
    }

    // gn3 stats: MFMA projection, y never materialized
    k_stats_mfma<<<kStatsBlocks, 256, 0, stream>>>(xb, adj, prod, wm3, bm3, spart);
    k_reduce<<<64, 256, 0, stream>>>(spart, stats);
    k_finalize<<<1, 32, 0, stream>>>(stats, g3g, g3b, g3a, ss);

    // final gather: one wave per query
    k_out<<<kQ / 4, 256, 0, stream>>>(pos, xb, adj, prod, wm3, bm3, ss, wdir, bdir, out);
}

// Round 11
// 497.033 us; speedup vs baseline: 1.5560x; 1.0902x over previous
//
#include <hip/hip_runtime.h>
#include <hip/hip_bf16.h>
#include <cstddef>

constexpr int   kN  = 1024;
constexpr int   kE  = 16384;
constexpr int   kQ  = 8192;
constexpr int   kH  = 32;
constexpr size_t kNN = (size_t)kN * kN;
constexpr float kEPS = 1e-5f;
constexpr int   kCW = 8;              // channel chunk width, pinned; UNFUSED genx only
constexpr int   kStatsBlocks = kN;    // one i-row per block

using short8 = __attribute__((ext_vector_type(8))) short;
using f32x4  = __attribute__((ext_vector_type(4))) float;

__device__ __forceinline__ unsigned short f2bf(float f) {
    __hip_bfloat16 h = __float2bfloat16(f);
    return *reinterpret_cast<unsigned short*>(&h);
}

// ---------------- small graph kernels ----------------

__global__ void k_edge(const int* __restrict__ ei, float* __restrict__ deg,
                       unsigned char* __restrict__ adj, unsigned char* __restrict__ adjT) {
    int e = blockIdx.x * 256 + threadIdx.x;
    if (e < kE) {
        int s = ei[e], d = ei[kE + e];
        atomicAdd(&deg[d], 1.0f);
        adj [s * kN + d] = 1;   // eim[s][d]
        adjT[d * kN + s] = 1;   // eim^T
    }
}

__global__ void k_dinv(const float* __restrict__ deg, float* __restrict__ dinv) {
    int n = blockIdx.x * 256 + threadIdx.x;
    if (n < kN) dinv[n] = rsqrtf(deg[n] + 1.0f);
}

__global__ void k_embed(const int* __restrict__ xids, const float* __restrict__ emb,
                        float* __restrict__ x0) {
    int t = blockIdx.x * 256 + threadIdx.x;  // kN*kH threads
    int n = t >> 5, c = t & 31;
    x0[t] = emb[xids[n] * kH + c];
}

// h = x @ W   (kN x 32) @ (32 x 32)
__global__ void k_node_mm(const float* __restrict__ x, const float* __restrict__ W,
                          float* __restrict__ h) {
    __shared__ float Ws[kH * kH];
    int t = threadIdx.x;
    for (int u = t; u < kH * kH; u += 256) Ws[u] = W[u];
    __syncthreads();
    int g = blockIdx.x * 256 + t;
    int n = g >> 5, c = g & 31;
    float acc = 0.f;
#pragma unroll
    for (int d = 0; d < kH; d++) acc = fmaf(x[n * kH + d], Ws[d * kH + c], acc);
    h[g] = acc;
}

__global__ void k_scatter(const int* __restrict__ ei, const float* __restrict__ h,
                          const float* __restrict__ dinv, float* __restrict__ agg) {
    int t = blockIdx.x * 256 + threadIdx.x;  // kE*kH threads
    int e = t >> 5, c = t & 31;
    int s = ei[e], d = ei[kE + e];
    atomicAdd(&agg[d * kH + c], h[s * kH + c] * dinv[s] * dinv[d]);
}

__global__ void k_gcn_post(float* __restrict__ agg, const float* __restrict__ h,
                           const float* __restrict__ dinv, const float* __restrict__ b) {
    int t = blockIdx.x * 256 + threadIdx.x;  // kN*kH
    int n = t >> 5, c = t & 31;
    agg[t] += h[t] * dinv[n] * dinv[n] + b[c];
}

// graphnorm over nodes (per channel), then relu. One block per channel.
__global__ void k_graphnorm(const float* __restrict__ x, float* __restrict__ out,
                            const float* __restrict__ g, const float* __restrict__ b,
                            const float* __restrict__ a, int M) {
    int c = blockIdx.x, t = threadIdx.x;
    float s = 0.f, ss = 0.f;
    for (int m = t; m < M; m += 256) { float v = x[m * kH + c]; s += v; ss += v * v; }
    __shared__ float rs[256], rss[256];
    rs[t] = s; rss[t] = ss;
    __syncthreads();
    for (int o = 128; o > 0; o >>= 1) {
        if (t < o) { rs[t] += rs[t + o]; rss[t] += rss[t + o]; }
        __syncthreads();
    }
    __shared__ float scale, shift;
    if (t == 0) {
        float mu  = rs[0] / (float)M;
        float ac  = a[c];
        float var = rss[0] / (float)M - 2.f * ac * mu * mu + ac * ac * mu * mu;
        float sc  = g[c] * rsqrtf(var + kEPS);
        scale = sc;
        shift = b[c] - sc * ac * mu;
    }
    __syncthreads();
    for (int m = t; m < M; m += 256) {
        float v = scale * x[m * kH + c] + shift;
        out[m * kH + c] = v > 0.f ? v : 0.f;
    }
}

// ---------------- x1 / x2^T generation (bf16, channel-major) — LDS-free ----------------
// All weight/xo/bias indices are wave-uniform -> compiler promotes to s_load
// (scalar cache); d-outer/cc-inner makes each d's 8 weights one s_load_dwordx8.
// NOTE: do NOT fuse X1+X2 into one kernel (R4/R9: 144 VGPR, 10% occ, 3.4x slower).

template<int CW>
__global__ __launch_bounds__(256) void k_genx(
        const float* __restrict__ xn, const unsigned char* __restrict__ adjX,
        const float* __restrict__ w, const float* __restrict__ b,
        __hip_bfloat16* __restrict__ X, int c0) {
    int o = blockIdx.y;
    int in = blockIdx.x * 256 + threadIdx.x;
    float p[kH];
#pragma unroll
    for (int q = 0; q < 8; q++) {
        float4 vj = *(const float4*)&xn[in * kH + 4 * q];
        p[4 * q + 0] = xn[o * kH + 4 * q + 0] * vj.x;   // xn[o*..] uniform -> SGPR
        p[4 * q + 1] = xn[o * kH + 4 * q + 1] * vj.y;
        p[4 * q + 2] = xn[o * kH + 4 * q + 2] * vj.z;
        p[4 * q + 3] = xn[o * kH + 4 * q + 3] * vj.w;
    }
    float e = (float)adjX[o * kN + in];
    float v[CW];
#pragma unroll
    for (int cc = 0; cc < CW; cc++) v[cc] = b[c0 + cc];
#pragma unroll
    for (int d = 0; d < kH; d++) {
#pragma unroll
        for (int cc = 0; cc < CW; cc++)
            v[cc] = fmaf(p[d], w[d * kH + c0 + cc], v[cc]);   // 32B s_load per d
    }
#pragma unroll
    for (int cc = 0; cc < CW; cc++) {
        float r = fmaf(e, w[32 * kH + c0 + cc], v[cc]);
        X[(size_t)cc * kNN + (size_t)o * kN + in] = __float2bfloat16(r > 0.f ? r : 0.f);
    }
}

// ---------------- bf16 MFMA batched GEMM: C[c] = A[c] @ B[c], B given transposed ----------------

__device__ __forceinline__ void g2l16(const unsigned short* g, unsigned short* l) {
    __builtin_amdgcn_global_load_lds(
        (const __attribute__((address_space(1))) void*)g,
        (__attribute__((address_space(3))) void*)l, 16, 0, 0);
}

__global__ __launch_bounds__(256) void k_bgemm_bf16(
        const unsigned short* __restrict__ A_, const unsigned short* __restrict__ Bt_,
        float* __restrict__ C_) {
    int c = blockIdx.z;
    const unsigned short* A  = A_  + (size_t)c * kNN;
    const unsigned short* Bt = Bt_ + (size_t)c * kNN;
    float* C = C_ + (size_t)c * kNN;
    int i0 = blockIdx.y * 128, j0 = blockIdx.x * 128;
    __shared__ unsigned short As[128 * 32];
    __shared__ unsigned short Bs[128 * 32];
    int t = threadIdx.x;
    int lane = t & 63, w = t >> 6;
    int wr = (w >> 1) * 64, wc = (w & 1) * 64;
    int l15 = lane & 15, lhi = lane >> 4;  // 0..3
    int srow = t >> 2, skel = (t & 3) * 8;
    f32x4 acc[4][4] = {};
    for (int k0 = 0; k0 < kN; k0 += 32) {
        g2l16(A  + (size_t)(i0 + srow)      * kN + k0 + skel, As + (size_t)t * 8);
        g2l16(A  + (size_t)(i0 + srow + 64) * kN + k0 + skel, As + (size_t)(t + 256) * 8);
        g2l16(Bt + (size_t)(j0 + srow)      * kN + k0 + skel, Bs + (size_t)t * 8);
        g2l16(Bt + (size_t)(j0 + srow + 64) * kN + k0 + skel, Bs + (size_t)(t + 256) * 8);
        asm volatile("s_waitcnt vmcnt(0)" ::: "memory");
        __syncthreads();
        short8 af[4], bf[4];
#pragma unroll
        for (int m = 0; m < 4; m++)
            af[m] = *(const short8*)&As[(wr + m * 16 + l15) * 32 + lhi * 8];
#pragma unroll
        for (int n = 0; n < 4; n++)
            bf[n] = *(const short8*)&Bs[(wc + n * 16 + l15) * 32 + lhi * 8];
#pragma unroll
        for (int m = 0; m < 4; m++)
#pragma unroll
            for (int n = 0; n < 4; n++)
                acc[m][n] = __builtin_amdgcn_mfma_f32_16x16x32_bf16(af[m], bf[n], acc[m][n], 0, 0, 0);
        __syncthreads();
    }
#pragma unroll
    for (int m = 0; m < 4; m++) {
        int row = i0 + wr + m * 16 + lhi * 4;
#pragma unroll
        for (int n = 0; n < 4; n++) {
            int col = j0 + wc + n * 16 + l15;
#pragma unroll
            for (int r = 0; r < 4; r++)
                C[(size_t)(row + r) * kN + col] = acc[m][n][r];
        }
    }
}

// ---------------- gn3 statistics via MFMA (R8-proven) ----------------

__global__ __launch_bounds__(256) void k_stats_mfma(
        const float* __restrict__ xn, const unsigned char* __restrict__ adj,
        const float* __restrict__ prod, const float* __restrict__ w3,
        const float* __restrict__ b3, float* __restrict__ spart) {
    __shared__ unsigned short As[128 * 104];   // 26.6 KB feat tile
    __shared__ unsigned short Bs[32 * 104];    // 6.7 KB W3aug^T [c][k]
    __shared__ float xi[kH], lsum[kH], lssq[kH];
    int t = threadIdx.x;
    int i = blockIdx.x;
    int lane = t & 63, w = t >> 6;
    int l15 = lane & 15, lhi = lane >> 4;

    for (int u = t; u < 128 * 104 / 8; u += 256)
        *(short8*)&As[u * 8] = short8{0, 0, 0, 0, 0, 0, 0, 0};
    {   // W3aug^T: c = t&31, s-range (t>>5)*13..+13
        int c = t & 31, s0 = (t >> 5) * 13;
        for (int s = s0; s < s0 + 13; s++) {
            float v = 0.f;
            if (s <= 32)                 v = w3[s * kH + c];
            else if (s >= 34 && s <= 65) v = w3[(s - 1) * kH + c];
            else if (s == 66)            v = b3[c];
            Bs[c * 104 + s] = f2bf(v);
        }
    }
    if (t < kH) { xi[t] = xn[i * kH + t]; lsum[t] = 0.f; lssq[t] = 0.f; }
    __syncthreads();
    if (t < 128) As[t * 104 + 66] = f2bf(1.0f);   // bias column (persists)

    float s2[2] = {0.f, 0.f}, q22[2] = {0.f, 0.f};
    int wrow = w * 32;

    for (int kt = 0; kt < 8; kt++) {
        int kbase = kt * 128;
        {   // stage p (slots 0..31)
            int r = t >> 1, half = t & 1;
            int k = kbase + r;
            const float* xr = &xn[k * kH + half * 16];
            float4 v0 = *(const float4*)&xr[0];
            float4 v1 = *(const float4*)&xr[4];
            float4 v2 = *(const float4*)&xr[8];
            float4 v3 = *(const float4*)&xr[12];
            const float* xih = &xi[half * 16];
            short8 o0, o1;
            o0[0] = f2bf(xih[0] * v0.x);  o0[1] = f2bf(xih[1] * v0.y);
            o0[2] = f2bf(xih[2] * v0.z);  o0[3] = f2bf(xih[3] * v0.w);
            o0[4] = f2bf(xih[4] * v1.x);  o0[5] = f2bf(xih[5] * v1.y);
            o0[6] = f2bf(xih[6] * v1.z);  o0[7] = f2bf(xih[7] * v1.w);
            o1[0] = f2bf(xih[8] * v2.x);  o1[1] = f2bf(xih[9] * v2.y);
            o1[2] = f2bf(xih[10] * v2.z); o1[3] = f2bf(xih[11] * v2.w);
            o1[4] = f2bf(xih[12] * v3.x); o1[5] = f2bf(xih[13] * v3.y);
            o1[6] = f2bf(xih[14] * v3.z); o1[7] = f2bf(xih[15] * v3.w);
            *(short8*)&As[r * 104 + half * 16]     = o0;
            *(short8*)&As[r * 104 + half * 16 + 8] = o1;
        }
        if (t < 128) As[t * 104 + 32] = f2bf((float)adj[i * kN + kbase + t]);
        {   // stage pr (slots 34..65)
            int kq = t & 15, dp = t >> 4, d2 = dp * 2;
            const float* p0 = &prod[(size_t)d2 * kNN + (size_t)i * kN + kbase + kq * 8];
            const float* p1 = p0 + kNN;
            float4 a0 = *(const float4*)&p0[0];
            float4 a1 = *(const float4*)&p0[4];
            float4 b0 = *(const float4*)&p1[0];
            float4 b1 = *(const float4*)&p1[4];
            float r0[8] = {a0.x, a0.y, a0.z, a0.w, a1.x, a1.y, a1.z, a1.w};
            float r1[8] = {b0.x, b0.y, b0.z, b0.w, b1.x, b1.y, b1.z, b1.w};
            unsigned int* As32 = (unsigned int*)As;
#pragma unroll
            for (int j = 0; j < 8; j++) {
                int jr = (j + kq) & 7;
                int kl = kq * 8 + jr;
                unsigned int val = (unsigned int)f2bf(r0[jr]) |
                                   ((unsigned int)f2bf(r1[jr]) << 16);
                As32[kl * 52 + 17 + dp] = val;
            }
        }
        __syncthreads();
        f32x4 acc[2][2] = {};
#pragma unroll
        for (int ks = 0; ks < 3; ks++) {
            short8 af0 = *(const short8*)&As[(wrow + l15) * 104 + ks * 32 + lhi * 8];
            short8 af1 = *(const short8*)&As[(wrow + 16 + l15) * 104 + ks * 32 + lhi * 8];
            short8 bf0 = *(const short8*)&Bs[l15 * 104 + ks * 32 + lhi * 8];
            short8 bf1 = *(const short8*)&Bs[(16 + l15) * 104 + ks * 32 + lhi * 8];
            acc[0][0] = __builtin_amdgcn_mfma_f32_16x16x32_bf16(af0, bf0, acc[0][0], 0, 0, 0);
            acc[0][1] = __builtin_amdgcn_mfma_f32_16x16x32_bf16(af0, bf1, acc[0][1], 0, 0, 0);
            acc[1][0] = __builtin_amdgcn_mfma_f32_16x16x32_bf16(af1, bf0, acc[1][0], 0, 0, 0);
            acc[1][1] = __builtin_amdgcn_mfma_f32_16x16x32_bf16(af1, bf1, acc[1][1], 0, 0, 0);
        }
#pragma unroll
        for (int ct = 0; ct < 2; ct++)
#pragma unroll
            for (int rt = 0; rt < 2; rt++)
#pragma unroll
                for (int r = 0; r < 4; r++) {
                    float y = acc[rt][ct][r];
                    s2[ct] += y;
                    q22[ct] = fmaf(y, y, q22[ct]);
                }
        __syncthreads();
    }
#pragma unroll
    for (int ct = 0; ct < 2; ct++) {
        s2[ct]  += __shfl_xor(s2[ct], 16);  s2[ct]  += __shfl_xor(s2[ct], 32);
        q22[ct] += __shfl_xor(q22[ct], 16); q22[ct] += __shfl_xor(q22[ct], 32);
    }
    if (lane < 16) {
#pragma unroll
        for (int ct = 0; ct < 2; ct++) {
            atomicAdd(&lsum[ct * 16 + l15], s2[ct]);
            atomicAdd(&lssq[ct * 16 + l15], q22[ct]);
        }
    }
    __syncthreads();
    if (t < kH)          spart[(size_t)i * 64 + t]             = lsum[t];
    else if (t < 2 * kH) spart[(size_t)i * 64 + 32 + (t - kH)] = lssq[t - kH];
}

// parallel reduce spart[1024][64] -> stats[64]
__global__ __launch_bounds__(256) void k_reduce(const float* __restrict__ spart,
                                                float* __restrict__ stats) {
    int slot = blockIdx.x;   // 64 blocks
    int t = threadIdx.x;
    float acc = 0.f;
    for (int r = t; r < kStatsBlocks; r += 256) acc += spart[(size_t)r * 64 + slot];
    __shared__ float red[256];
    red[t] = acc;
    __syncthreads();
    for (int o = 128; o > 0; o >>= 1) {
        if (t < o) red[t] += red[t + o];
        __syncthreads();
    }
    if (t == 0) stats[slot] = red[0];
}

__global__ void k_finalize(const float* __restrict__ stats, const float* __restrict__ g,
                           const float* __restrict__ b, const float* __restrict__ a,
                           float* __restrict__ ss) {
    int c = threadIdx.x;  // 32 threads
    float M   = (float)((double)kNN);
    float mu  = stats[c] / M;
    float ac  = a[c];
    float var = stats[kH + c] / M - 2.f * ac * mu * mu + ac * ac * mu * mu;
    float sc  = g[c] * rsqrtf(var + kEPS);
    ss[c]      = sc;
    ss[kH + c] = b[c] - sc * ac * mu;
}

// ---------------- final: one wave per query (R9-verified) ----------------

__global__ __launch_bounds__(256) void k_out(
        const int* __restrict__ pos, const float* __restrict__ xn,
        const unsigned char* __restrict__ adj, const float* __restrict__ prod,
        const float* __restrict__ w3, const float* __restrict__ b3,
        const float* __restrict__ ss, const float* __restrict__ wdir,
        const float* __restrict__ bdir, float* __restrict__ out) {
    __shared__ float W3s[65 * kH], b3s[kH], scs[kH], shs[kH], wd[kH];
    int t = threadIdx.x;
    for (int u = t; u < 65 * kH; u += 256) W3s[u] = w3[u];
    if (t < kH) { b3s[t] = b3[t]; scs[t] = ss[t]; shs[t] = ss[kH + t]; wd[t] = wdir[t]; }
    __syncthreads();
    int q = blockIdx.x * 4 + (t >> 6);
    int lane = t & 63;
    int c = lane & 31, h = lane >> 5;
    int i = pos[2 * q], k = pos[2 * q + 1];
    size_t addr = h ? ((size_t)k * kN + i) : ((size_t)i * kN + k);
    float pr_reg = prod[(size_t)c * kNN + addr];      // my direction, channel index c
    float p_reg  = xn[i * kH + c] * xn[k * kH + c];   // symmetric in (i,k)
    float e_reg  = (float)adj[addr];
    float y = b3s[c];
#pragma unroll
    for (int d = 0; d < kH; d++)
        y = fmaf(__shfl(p_reg, d), W3s[d * kH + c], y);
    y = fmaf(e_reg, W3s[32 * kH + c], y);
#pragma unroll
    for (int d = 0; d < kH; d++)
        y = fmaf(__shfl(pr_reg, (h << 5) + d), W3s[(33 + d) * kH + c], y);
    float z = scs[c] * y + shs[c];
    z = z > 0.f ? z : 0.f;
    float zo = __shfl_xor(z, 32);        // other direction, same channel
    float v = z * zo * wd[c];
#pragma unroll
    for (int o = 16; o > 0; o >>= 1) v += __shfl_xor(v, o);
    if (lane == 0) out[q] = v + bdir[0];
}

// ---------------- launch ----------------

extern "C" void kernel_launch(void* const* d_in, const int* in_sizes, int n_in,
                              void* d_out, int out_size, void* d_ws, size_t ws_size,
                              hipStream_t stream) {
    const int*   x_ids = (const int*)d_in[0];
    const int*   ei    = (const int*)d_in[1];
    const int*   pos   = (const int*)d_in[2];
    const float* emb   = (const float*)d_in[3];
    const float* gw0   = (const float*)d_in[4];
    const float* gb0   = (const float*)d_in[5];
    const float* g0g   = (const float*)d_in[6];
    const float* g0b   = (const float*)d_in[7];
    const float* g0a   = (const float*)d_in[8];
    const float* gw1   = (const float*)d_in[9];
    const float* gb1   = (const float*)d_in[10];
    const float* g1g   = (const float*)d_in[11];
    const float* g1b   = (const float*)d_in[12];
    const float* g1a   = (const float*)d_in[13];
    const float* wm1   = (const float*)d_in[14];
    const float* bm1   = (const float*)d_in[15];
    const float* wm2   = (const float*)d_in[16];
    const float* bm2   = (const float*)d_in[17];
    const float* wm3   = (const float*)d_in[18];
    const float* bm3   = (const float*)d_in[19];
    const float* g3g   = (const float*)d_in[20];
    const float* g3b   = (const float*)d_in[21];
    const float* g3a   = (const float*)d_in[22];
    const float* wdir  = (const float*)d_in[23];
    const float* bdir  = (const float*)d_in[24];
    float* out = (float*)d_out;

    // workspace layout — fixed CW=8, total demand ~162.9 MB (ws_size = 256 MiB)
    const size_t fixedF = (size_t)kH * kNN;                       // prod floats
    float* prod = (float*)d_ws;                                   // 128 MB
    unsigned short* X1c = (unsigned short*)(prod + fixedF);       // 16 MB bf16
    unsigned short* X2c = X1c + (size_t)kCW * kNN;                // 16 MB bf16 (transposed)
    unsigned char* adj  = (unsigned char*)(X2c + (size_t)kCW * kNN);  // 1 MB
    unsigned char* adjT = adj + kNN;                                   // 1 MB
    float* deg   = (float*)(adjT + kNN);
    float* dinv  = deg + kN;
    float* x0    = dinv + kN;
    float* h     = x0 + kN * kH;
    float* agg   = h + kN * kH;
    float* xa    = agg + kN * kH;
    float* xb    = xa + kN * kH;
    float* spart = xb + kN * kH;                 // 1024*64 floats (256 KB)
    float* stats = spart + (size_t)kStatsBlocks * 64;
    float* ss    = stats + 2 * kH;

    hipMemsetAsync(deg, 0, kN * sizeof(float), stream);
    hipMemsetAsync(adj, 0, 2 * kNN, stream);   // adj + adjT contiguous
    hipMemsetAsync(agg, 0, kN * kH * sizeof(float), stream);

    k_edge<<<(kE + 255) / 256, 256, 0, stream>>>(ei, deg, adj, adjT);
    k_dinv<<<4, 256, 0, stream>>>(deg, dinv);
    k_embed<<<kN * kH / 256, 256, 0, stream>>>(x_ids, emb, x0);

    // GCN layer 0
    k_node_mm<<<kN * kH / 256, 256, 0, stream>>>(x0, gw0, h);
    k_scatter<<<kE * kH / 256, 256, 0, stream>>>(ei, h, dinv, agg);
    k_gcn_post<<<kN * kH / 256, 256, 0, stream>>>(agg, h, dinv, gb0);
    k_graphnorm<<<kH, 256, 0, stream>>>(agg, xa, g0g, g0b, g0a, kN);

    // GCN layer 1
    hipMemsetAsync(agg, 0, kN * kH * sizeof(float), stream);
    k_node_mm<<<kN * kH / 256, 256, 0, stream>>>(xa, gw1, h);
    k_scatter<<<kE * kH / 256, 256, 0, stream>>>(ei, h, dinv, agg);
    k_gcn_post<<<kN * kH / 256, 256, 0, stream>>>(agg, h, dinv, gb1);
    k_graphnorm<<<kH, 256, 0, stream>>>(agg, xb, g1g, g1b, g1a, kN);

    // pairwise bf16 features (UNFUSED, LDS-free) + batched MFMA GEMMs, CW=8
    for (int c0 = 0; c0 < kH; c0 += kCW) {
        k_genx<kCW><<<dim3(4, kN), 256, 0, stream>>>(xb, adj,  wm1, bm1,
                                                     (__hip_bfloat16*)X1c, c0);
        k_genx<kCW><<<dim3(4, kN), 256, 0, stream>>>(xb, adjT, wm2, bm2,
                                                     (__hip_bfloat16*)X2c, c0);
        k_bgemm_bf16<<<dim3(8, 8, kCW), 256, 0, stream>>>(X1c, X2c, prod + (size_t)c0 * kNN);
    }

    // gn3 stats: MFMA projection, y never materialized
    k_stats_mfma<<<kStatsBlocks, 256, 0, stream>>>(xb, adj, prod, wm3, bm3, spart);
    k_reduce<<<64, 256, 0, stream>>>(spart, stats);
    k_finalize<<<1, 32, 0, stream>>>(stats, g3g, g3b, g3a, ss);

    // final gather: one wave per query
    k_out<<<kQ / 4, 256, 0, stream>>>(pos, xb, adj, prod, wm3, bm3, ss, wdir, bdir, out);
}

// Round 12
// 465.004 us; speedup vs baseline: 1.6631x; 1.0689x over previous
//
#include <hip/hip_runtime.h>
#include <hip/hip_bf16.h>
#include <cstddef>

constexpr int   kN  = 1024;
constexpr int   kE  = 16384;
constexpr int   kQ  = 8192;
constexpr int   kH  = 32;
constexpr size_t kNN = (size_t)kN * kN;
constexpr float kEPS = 1e-5f;
constexpr int   kCWg = 8;             // genx channels per z-slice (register-proven shape)
constexpr int   kCWb = 16;            // bgemm channels per launch (1024 blocks = 4/CU)
constexpr int   kStatsBlocks = kN;    // one i-row per block

using short8 = __attribute__((ext_vector_type(8))) short;
using f32x4  = __attribute__((ext_vector_type(4))) float;

__device__ __forceinline__ unsigned short f2bf(float f) {
    __hip_bfloat16 h = __float2bfloat16(f);
    return *reinterpret_cast<unsigned short*>(&h);
}

// ---------------- small graph kernels ----------------

__global__ void k_edge(const int* __restrict__ ei, float* __restrict__ deg,
                       unsigned char* __restrict__ adj, unsigned char* __restrict__ adjT) {
    int e = blockIdx.x * 256 + threadIdx.x;
    if (e < kE) {
        int s = ei[e], d = ei[kE + e];
        atomicAdd(&deg[d], 1.0f);
        adj [s * kN + d] = 1;   // eim[s][d]
        adjT[d * kN + s] = 1;   // eim^T
    }
}

__global__ void k_dinv(const float* __restrict__ deg, float* __restrict__ dinv) {
    int n = blockIdx.x * 256 + threadIdx.x;
    if (n < kN) dinv[n] = rsqrtf(deg[n] + 1.0f);
}

__global__ void k_embed(const int* __restrict__ xids, const float* __restrict__ emb,
                        float* __restrict__ x0) {
    int t = blockIdx.x * 256 + threadIdx.x;  // kN*kH threads
    int n = t >> 5, c = t & 31;
    x0[t] = emb[xids[n] * kH + c];
}

// h = x @ W   (kN x 32) @ (32 x 32)
__global__ void k_node_mm(const float* __restrict__ x, const float* __restrict__ W,
                          float* __restrict__ h) {
    __shared__ float Ws[kH * kH];
    int t = threadIdx.x;
    for (int u = t; u < kH * kH; u += 256) Ws[u] = W[u];
    __syncthreads();
    int g = blockIdx.x * 256 + t;
    int n = g >> 5, c = g & 31;
    float acc = 0.f;
#pragma unroll
    for (int d = 0; d < kH; d++) acc = fmaf(x[n * kH + d], Ws[d * kH + c], acc);
    h[g] = acc;
}

__global__ void k_scatter(const int* __restrict__ ei, const float* __restrict__ h,
                          const float* __restrict__ dinv, float* __restrict__ agg) {
    int t = blockIdx.x * 256 + threadIdx.x;  // kE*kH threads
    int e = t >> 5, c = t & 31;
    int s = ei[e], d = ei[kE + e];
    atomicAdd(&agg[d * kH + c], h[s * kH + c] * dinv[s] * dinv[d]);
}

__global__ void k_gcn_post(float* __restrict__ agg, const float* __restrict__ h,
                           const float* __restrict__ dinv, const float* __restrict__ b) {
    int t = blockIdx.x * 256 + threadIdx.x;  // kN*kH
    int n = t >> 5, c = t & 31;
    agg[t] += h[t] * dinv[n] * dinv[n] + b[c];
}

// graphnorm over nodes (per channel), then relu. One block per channel.
__global__ void k_graphnorm(const float* __restrict__ x, float* __restrict__ out,
                            const float* __restrict__ g, const float* __restrict__ b,
                            const float* __restrict__ a, int M) {
    int c = blockIdx.x, t = threadIdx.x;
    float s = 0.f, ss = 0.f;
    for (int m = t; m < M; m += 256) { float v = x[m * kH + c]; s += v; ss += v * v; }
    __shared__ float rs[256], rss[256];
    rs[t] = s; rss[t] = ss;
    __syncthreads();
    for (int o = 128; o > 0; o >>= 1) {
        if (t < o) { rs[t] += rs[t + o]; rss[t] += rss[t + o]; }
        __syncthreads();
    }
    __shared__ float scale, shift;
    if (t == 0) {
        float mu  = rs[0] / (float)M;
        float ac  = a[c];
        float var = rss[0] / (float)M - 2.f * ac * mu * mu + ac * ac * mu * mu;
        float sc  = g[c] * rsqrtf(var + kEPS);
        scale = sc;
        shift = b[c] - sc * ac * mu;
    }
    __syncthreads();
    for (int m = t; m < M; m += 256) {
        float v = scale * x[m * kH + c] + shift;
        out[m * kH + c] = v > 0.f ? v : 0.f;
    }
}

// ---------------- x1 / x2^T generation (bf16, channel-major) — LDS-free, z-merged ----------------
// blockIdx.z selects X1 (adj,w1) vs X2^T (adjT,w2): wave-uniform, hoisted, so the
// per-thread register shape is IDENTICAL to the proven unfused kernel.
// NOTE: do NOT fuse X1+X2 per-thread (R4/R9: dual accumulators -> 144 VGPR, 3.4x slower).

template<int CW>
__global__ __launch_bounds__(256) void k_genxz(
        const float* __restrict__ xn,
        const unsigned char* __restrict__ adj, const unsigned char* __restrict__ adjT,
        const float* __restrict__ w1, const float* __restrict__ b1,
        const float* __restrict__ w2, const float* __restrict__ b2,
        __hip_bfloat16* __restrict__ X1, __hip_bfloat16* __restrict__ X2t, int c0) {
    const unsigned char* adjX = blockIdx.z ? adjT : adj;
    const float* w = blockIdx.z ? w2 : w1;
    const float* b = blockIdx.z ? b2 : b1;
    __hip_bfloat16* X = blockIdx.z ? X2t : X1;
    int o = blockIdx.y;
    int in = blockIdx.x * 256 + threadIdx.x;
    float p[kH];
#pragma unroll
    for (int q = 0; q < 8; q++) {
        float4 vj = *(const float4*)&xn[in * kH + 4 * q];
        p[4 * q + 0] = xn[o * kH + 4 * q + 0] * vj.x;   // xn[o*..] uniform -> SGPR
        p[4 * q + 1] = xn[o * kH + 4 * q + 1] * vj.y;
        p[4 * q + 2] = xn[o * kH + 4 * q + 2] * vj.z;
        p[4 * q + 3] = xn[o * kH + 4 * q + 3] * vj.w;
    }
    float e = (float)adjX[o * kN + in];
    float v[CW];
#pragma unroll
    for (int cc = 0; cc < CW; cc++) v[cc] = b[c0 + cc];
#pragma unroll
    for (int d = 0; d < kH; d++) {
#pragma unroll
        for (int cc = 0; cc < CW; cc++)
            v[cc] = fmaf(p[d], w[d * kH + c0 + cc], v[cc]);   // 32B s_load per d
    }
#pragma unroll
    for (int cc = 0; cc < CW; cc++) {
        float r = fmaf(e, w[32 * kH + c0 + cc], v[cc]);
        X[(size_t)cc * kNN + (size_t)o * kN + in] = __float2bfloat16(r > 0.f ? r : 0.f);
    }
}

// ---------------- bf16 MFMA batched GEMM: C[c] = A[c] @ B[c], B given transposed ----------------

__device__ __forceinline__ void g2l16(const unsigned short* g, unsigned short* l) {
    __builtin_amdgcn_global_load_lds(
        (const __attribute__((address_space(1))) void*)g,
        (__attribute__((address_space(3))) void*)l, 16, 0, 0);
}

__global__ __launch_bounds__(256) void k_bgemm_bf16(
        const unsigned short* __restrict__ A_, const unsigned short* __restrict__ Bt_,
        float* __restrict__ C_) {
    int c = blockIdx.z;
    const unsigned short* A  = A_  + (size_t)c * kNN;
    const unsigned short* Bt = Bt_ + (size_t)c * kNN;
    float* C = C_ + (size_t)c * kNN;
    int i0 = blockIdx.y * 128, j0 = blockIdx.x * 128;
    __shared__ unsigned short As[128 * 32];
    __shared__ unsigned short Bs[128 * 32];
    int t = threadIdx.x;
    int lane = t & 63, w = t >> 6;
    int wr = (w >> 1) * 64, wc = (w & 1) * 64;
    int l15 = lane & 15, lhi = lane >> 4;  // 0..3
    int srow = t >> 2, skel = (t & 3) * 8;
    f32x4 acc[4][4] = {};
    for (int k0 = 0; k0 < kN; k0 += 32) {
        g2l16(A  + (size_t)(i0 + srow)      * kN + k0 + skel, As + (size_t)t * 8);
        g2l16(A  + (size_t)(i0 + srow + 64) * kN + k0 + skel, As + (size_t)(t + 256) * 8);
        g2l16(Bt + (size_t)(j0 + srow)      * kN + k0 + skel, Bs + (size_t)t * 8);
        g2l16(Bt + (size_t)(j0 + srow + 64) * kN + k0 + skel, Bs + (size_t)(t + 256) * 8);
        asm volatile("s_waitcnt vmcnt(0)" ::: "memory");
        __syncthreads();
        short8 af[4], bf[4];
#pragma unroll
        for (int m = 0; m < 4; m++)
            af[m] = *(const short8*)&As[(wr + m * 16 + l15) * 32 + lhi * 8];
#pragma unroll
        for (int n = 0; n < 4; n++)
            bf[n] = *(const short8*)&Bs[(wc + n * 16 + l15) * 32 + lhi * 8];
#pragma unroll
        for (int m = 0; m < 4; m++)
#pragma unroll
            for (int n = 0; n < 4; n++)
                acc[m][n] = __builtin_amdgcn_mfma_f32_16x16x32_bf16(af[m], bf[n], acc[m][n], 0, 0, 0);
        __syncthreads();
    }
#pragma unroll
    for (int m = 0; m < 4; m++) {
        int row = i0 + wr + m * 16 + lhi * 4;
#pragma unroll
        for (int n = 0; n < 4; n++) {
            int col = j0 + wc + n * 16 + l15;
#pragma unroll
            for (int r = 0; r < 4; r++)
                C[(size_t)(row + r) * kN + col] = acc[m][n][r];
        }
    }
}

// ---------------- gn3 statistics via MFMA (R8-proven) ----------------

__global__ __launch_bounds__(256) void k_stats_mfma(
        const float* __restrict__ xn, const unsigned char* __restrict__ adj,
        const float* __restrict__ prod, const float* __restrict__ w3,
        const float* __restrict__ b3, float* __restrict__ spart) {
    __shared__ unsigned short As[128 * 104];   // 26.6 KB feat tile
    __shared__ unsigned short Bs[32 * 104];    // 6.7 KB W3aug^T [c][k]
    __shared__ float xi[kH], lsum[kH], lssq[kH];
    int t = threadIdx.x;
    int i = blockIdx.x;
    int lane = t & 63, w = t >> 6;
    int l15 = lane & 15, lhi = lane >> 4;

    for (int u = t; u < 128 * 104 / 8; u += 256)
        *(short8*)&As[u * 8] = short8{0, 0, 0, 0, 0, 0, 0, 0};
    {   // W3aug^T: c = t&31, s-range (t>>5)*13..+13
        int c = t & 31, s0 = (t >> 5) * 13;
        for (int s = s0; s < s0 + 13; s++) {
            float v = 0.f;
            if (s <= 32)                 v = w3[s * kH + c];
            else if (s >= 34 && s <= 65) v = w3[(s - 1) * kH + c];
            else if (s == 66)            v = b3[c];
            Bs[c * 104 + s] = f2bf(v);
        }
    }
    if (t < kH) { xi[t] = xn[i * kH + t]; lsum[t] = 0.f; lssq[t] = 0.f; }
    __syncthreads();
    if (t < 128) As[t * 104 + 66] = f2bf(1.0f);   // bias column (persists)

    float s2[2] = {0.f, 0.f}, q22[2] = {0.f, 0.f};
    int wrow = w * 32;

    for (int kt = 0; kt < 8; kt++) {
        int kbase = kt * 128;
        {   // stage p (slots 0..31)
            int r = t >> 1, half = t & 1;
            int k = kbase + r;
            const float* xr = &xn[k * kH + half * 16];
            float4 v0 = *(const float4*)&xr[0];
            float4 v1 = *(const float4*)&xr[4];
            float4 v2 = *(const float4*)&xr[8];
            float4 v3 = *(const float4*)&xr[12];
            const float* xih = &xi[half * 16];
            short8 o0, o1;
            o0[0] = f2bf(xih[0] * v0.x);  o0[1] = f2bf(xih[1] * v0.y);
            o0[2] = f2bf(xih[2] * v0.z);  o0[3] = f2bf(xih[3] * v0.w);
            o0[4] = f2bf(xih[4] * v1.x);  o0[5] = f2bf(xih[5] * v1.y);
            o0[6] = f2bf(xih[6] * v1.z);  o0[7] = f2bf(xih[7] * v1.w);
            o1[0] = f2bf(xih[8] * v2.x);  o1[1] = f2bf(xih[9] * v2.y);
            o1[2] = f2bf(xih[10] * v2.z); o1[3] = f2bf(xih[11] * v2.w);
            o1[4] = f2bf(xih[12] * v3.x); o1[5] = f2bf(xih[13] * v3.y);
            o1[6] = f2bf(xih[14] * v3.z); o1[7] = f2bf(xih[15] * v3.w);
            *(short8*)&As[r * 104 + half * 16]     = o0;
            *(short8*)&As[r * 104 + half * 16 + 8] = o1;
        }
        if (t < 128) As[t * 104 + 32] = f2bf((float)adj[i * kN + kbase + t]);
        {   // stage pr (slots 34..65)
            int kq = t & 15, dp = t >> 4, d2 = dp * 2;
            const float* p0 = &prod[(size_t)d2 * kNN + (size_t)i * kN + kbase + kq * 8];
            const float* p1 = p0 + kNN;
            float4 a0 = *(const float4*)&p0[0];
            float4 a1 = *(const float4*)&p0[4];
            float4 b0 = *(const float4*)&p1[0];
            float4 b1 = *(const float4*)&p1[4];
            float r0[8] = {a0.x, a0.y, a0.z, a0.w, a1.x, a1.y, a1.z, a1.w};
            float r1[8] = {b0.x, b0.y, b0.z, b0.w, b1.x, b1.y, b1.z, b1.w};
            unsigned int* As32 = (unsigned int*)As;
#pragma unroll
            for (int j = 0; j < 8; j++) {
                int jr = (j + kq) & 7;
                int kl = kq * 8 + jr;
                unsigned int val = (unsigned int)f2bf(r0[jr]) |
                                   ((unsigned int)f2bf(r1[jr]) << 16);
                As32[kl * 52 + 17 + dp] = val;
            }
        }
        __syncthreads();
        f32x4 acc[2][2] = {};
#pragma unroll
        for (int ks = 0; ks < 3; ks++) {
            short8 af0 = *(const short8*)&As[(wrow + l15) * 104 + ks * 32 + lhi * 8];
            short8 af1 = *(const short8*)&As[(wrow + 16 + l15) * 104 + ks * 32 + lhi * 8];
            short8 bf0 = *(const short8*)&Bs[l15 * 104 + ks * 32 + lhi * 8];
            short8 bf1 = *(const short8*)&Bs[(16 + l15) * 104 + ks * 32 + lhi * 8];
            acc[0][0] = __builtin_amdgcn_mfma_f32_16x16x32_bf16(af0, bf0, acc[0][0], 0, 0, 0);
            acc[0][1] = __builtin_amdgcn_mfma_f32_16x16x32_bf16(af0, bf1, acc[0][1], 0, 0, 0);
            acc[1][0] = __builtin_amdgcn_mfma_f32_16x16x32_bf16(af1, bf0, acc[1][0], 0, 0, 0);
            acc[1][1] = __builtin_amdgcn_mfma_f32_16x16x32_bf16(af1, bf1, acc[1][1], 0, 0, 0);
        }
#pragma unroll
        for (int ct = 0; ct < 2; ct++)
#pragma unroll
            for (int rt = 0; rt < 2; rt++)
#pragma unroll
                for (int r = 0; r < 4; r++) {
                    float y = acc[rt][ct][r];
                    s2[ct] += y;
                    q22[ct] = fmaf(y, y, q22[ct]);
                }
        __syncthreads();
    }
#pragma unroll
    for (int ct = 0; ct < 2; ct++) {
        s2[ct]  += __shfl_xor(s2[ct], 16);  s2[ct]  += __shfl_xor(s2[ct], 32);
        q22[ct] += __shfl_xor(q22[ct], 16); q22[ct] += __shfl_xor(q22[ct], 32);
    }
    if (lane < 16) {
#pragma unroll
        for (int ct = 0; ct < 2; ct++) {
            atomicAdd(&lsum[ct * 16 + l15], s2[ct]);
            atomicAdd(&lssq[ct * 16 + l15], q22[ct]);
        }
    }
    __syncthreads();
    if (t < kH)          spart[(size_t)i * 64 + t]             = lsum[t];
    else if (t < 2 * kH) spart[(size_t)i * 64 + 32 + (t - kH)] = lssq[t - kH];
}

// parallel reduce spart[1024][64] -> stats[64]
__global__ __launch_bounds__(256) void k_reduce(const float* __restrict__ spart,
                                                float* __restrict__ stats) {
    int slot = blockIdx.x;   // 64 blocks
    int t = threadIdx.x;
    float acc = 0.f;
    for (int r = t; r < kStatsBlocks; r += 256) acc += spart[(size_t)r * 64 + slot];
    __shared__ float red[256];
    red[t] = acc;
    __syncthreads();
    for (int o = 128; o > 0; o >>= 1) {
        if (t < o) red[t] += red[t + o];
        __syncthreads();
    }
    if (t == 0) stats[slot] = red[0];
}

__global__ void k_finalize(const float* __restrict__ stats, const float* __restrict__ g,
                           const float* __restrict__ b, const float* __restrict__ a,
                           float* __restrict__ ss) {
    int c = threadIdx.x;  // 32 threads
    float M   = (float)((double)kNN);
    float mu  = stats[c] / M;
    float ac  = a[c];
    float var = stats[kH + c] / M - 2.f * ac * mu * mu + ac * ac * mu * mu;
    float sc  = g[c] * rsqrtf(var + kEPS);
    ss[c]      = sc;
    ss[kH + c] = b[c] - sc * ac * mu;
}

// ---------------- final: one wave per query (R9-verified) ----------------

__global__ __launch_bounds__(256) void k_out(
        const int* __restrict__ pos, const float* __restrict__ xn,
        const unsigned char* __restrict__ adj, const float* __restrict__ prod,
        const float* __restrict__ w3, const float* __restrict__ b3,
        const float* __restrict__ ss, const float* __restrict__ wdir,
        const float* __restrict__ bdir, float* __restrict__ out) {
    __shared__ float W3s[65 * kH], b3s[kH], scs[kH], shs[kH], wd[kH];
    int t = threadIdx.x;
    for (int u = t; u < 65 * kH; u += 256) W3s[u] = w3[u];
    if (t < kH) { b3s[t] = b3[t]; scs[t] = ss[t]; shs[t] = ss[kH + t]; wd[t] = wdir[t]; }
    __syncthreads();
    int q = blockIdx.x * 4 + (t >> 6);
    int lane = t & 63;
    int c = lane & 31, h = lane >> 5;
    int i = pos[2 * q], k = pos[2 * q + 1];
    size_t addr = h ? ((size_t)k * kN + i) : ((size_t)i * kN + k);
    float pr_reg = prod[(size_t)c * kNN + addr];      // my direction, channel index c
    float p_reg  = xn[i * kH + c] * xn[k * kH + c];   // symmetric in (i,k)
    float e_reg  = (float)adj[addr];
    float y = b3s[c];
#pragma unroll
    for (int d = 0; d < kH; d++)
        y = fmaf(__shfl(p_reg, d), W3s[d * kH + c], y);
    y = fmaf(e_reg, W3s[32 * kH + c], y);
#pragma unroll
    for (int d = 0; d < kH; d++)
        y = fmaf(__shfl(pr_reg, (h << 5) + d), W3s[(33 + d) * kH + c], y);
    float z = scs[c] * y + shs[c];
    z = z > 0.f ? z : 0.f;
    float zo = __shfl_xor(z, 32);        // other direction, same channel
    float v = z * zo * wd[c];
#pragma unroll
    for (int o = 16; o > 0; o >>= 1) v += __shfl_xor(v, o);
    if (lane == 0) out[q] = v + bdir[0];
}

// ---------------- launch ----------------

extern "C" void kernel_launch(void* const* d_in, const int* in_sizes, int n_in,
                              void* d_out, int out_size, void* d_ws, size_t ws_size,
                              hipStream_t stream) {
    const int*   x_ids = (const int*)d_in[0];
    const int*   ei    = (const int*)d_in[1];
    const int*   pos   = (const int*)d_in[2];
    const float* emb   = (const float*)d_in[3];
    const float* gw0   = (const float*)d_in[4];
    const float* gb0   = (const float*)d_in[5];
    const float* g0g   = (const float*)d_in[6];
    const float* g0b   = (const float*)d_in[7];
    const float* g0a   = (const float*)d_in[8];
    const float* gw1   = (const float*)d_in[9];
    const float* gb1   = (const float*)d_in[10];
    const float* g1g   = (const float*)d_in[11];
    const float* g1b   = (const float*)d_in[12];
    const float* g1a   = (const float*)d_in[13];
    const float* wm1   = (const float*)d_in[14];
    const float* bm1   = (const float*)d_in[15];
    const float* wm2   = (const float*)d_in[16];
    const float* bm2   = (const float*)d_in[17];
    const float* wm3   = (const float*)d_in[18];
    const float* bm3   = (const float*)d_in[19];
    const float* g3g   = (const float*)d_in[20];
    const float* g3b   = (const float*)d_in[21];
    const float* g3a   = (const float*)d_in[22];
    const float* wdir  = (const float*)d_in[23];
    const float* bdir  = (const float*)d_in[24];
    float* out = (float*)d_out;

    // workspace layout — CW=16 bgemm batching: 128 + 32 + 32 + ~2.3 MiB ≈ 194 MiB (ws = 256 MiB)
    const size_t fixedF = (size_t)kH * kNN;                       // prod floats
    float* prod = (float*)d_ws;                                   // 128 MiB
    unsigned short* X1c = (unsigned short*)(prod + fixedF);       // 32 MiB bf16 (16 ch)
    unsigned short* X2c = X1c + (size_t)kCWb * kNN;               // 32 MiB bf16 (transposed)
    unsigned char* adj  = (unsigned char*)(X2c + (size_t)kCWb * kNN);  // 1 MiB
    unsigned char* adjT = adj + kNN;                                    // 1 MiB
    float* deg   = (float*)(adjT + kNN);
    float* dinv  = deg + kN;
    float* x0    = dinv + kN;
    float* h     = x0 + kN * kH;
    float* agg   = h + kN * kH;
    float* xa    = agg + kN * kH;
    float* xb    = xa + kN * kH;
    float* spart = xb + kN * kH;                 // 1024*64 floats (256 KB)
    float* stats = spart + (size_t)kStatsBlocks * 64;
    float* ss    = stats + 2 * kH;

    hipMemsetAsync(deg, 0, kN * sizeof(float), stream);
    hipMemsetAsync(adj, 0, 2 * kNN, stream);   // adj + adjT contiguous
    hipMemsetAsync(agg, 0, kN * kH * sizeof(float), stream);

    k_edge<<<(kE + 255) / 256, 256, 0, stream>>>(ei, deg, adj, adjT);
    k_dinv<<<4, 256, 0, stream>>>(deg, dinv);
    k_embed<<<kN * kH / 256, 256, 0, stream>>>(x_ids, emb, x0);

    // GCN layer 0
    k_node_mm<<<kN * kH / 256, 256, 0, stream>>>(x0, gw0, h);
    k_scatter<<<kE * kH / 256, 256, 0, stream>>>(ei, h, dinv, agg);
    k_gcn_post<<<kN * kH / 256, 256, 0, stream>>>(agg, h, dinv, gb0);
    k_graphnorm<<<kH, 256, 0, stream>>>(agg, xa, g0g, g0b, g0a, kN);

    // GCN layer 1
    hipMemsetAsync(agg, 0, kN * kH * sizeof(float), stream);
    k_node_mm<<<kN * kH / 256, 256, 0, stream>>>(xa, gw1, h);
    k_scatter<<<kE * kH / 256, 256, 0, stream>>>(ei, h, dinv, agg);
    k_gcn_post<<<kN * kH / 256, 256, 0, stream>>>(agg, h, dinv, gb1);
    k_graphnorm<<<kH, 256, 0, stream>>>(agg, xb, g1g, g1b, g1a, kN);

    // pairwise bf16 features (z-merged, LDS-free) + 16-channel-batched MFMA GEMMs
    for (int c0 = 0; c0 < kH; c0 += kCWb) {
        k_genxz<kCWg><<<dim3(4, kN, 2), 256, 0, stream>>>(
            xb, adj, adjT, wm1, bm1, wm2, bm2,
            (__hip_bfloat16*)X1c, (__hip_bfloat16*)X2c, c0);
        k_genxz<kCWg><<<dim3(4, kN, 2), 256, 0, stream>>>(
            xb, adj, adjT, wm1, bm1, wm2, bm2,
            (__hip_bfloat16*)(X1c + (size_t)kCWg * kNN),
            (__hip_bfloat16*)(X2c + (size_t)kCWg * kNN), c0 + kCWg);
        k_bgemm_bf16<<<dim3(8, 8, kCWb), 256, 0, stream>>>(X1c, X2c, prod + (size_t)c0 * kNN);
    }

    // gn3 stats: MFMA projection, y never materialized
    k_stats_mfma<<<kStatsBlocks, 256, 0, stream>>>(xb, adj, prod, wm3, bm3, spart);
    k_reduce<<<64, 256, 0, stream>>>(spart, stats);
    k_finalize<<<1, 32, 0, stream>>>(stats, g3g, g3b, g3a, ss);

    // final gather: one wave per query
    k_out<<<kQ / 4, 256, 0, stream>>>(pos, xb, adj, prod, wm3, bm3, ss, wdir, bdir, out);
}

// Round 13
// 459.548 us; speedup vs baseline: 1.6829x; 1.0119x over previous
//
#include <hip/hip_runtime.h>
#include <hip/hip_bf16.h>
#include <cstddef>

constexpr int   kN  = 1024;
constexpr int   kE  = 16384;
constexpr int   kQ  = 8192;
constexpr int   kH  = 32;
constexpr size_t kNN = (size_t)kN * kN;
constexpr float kEPS = 1e-5f;
constexpr int   kCWg = 8;             // genx channels per z-slice (register-proven shape)
constexpr int   kCWb = 16;            // bgemm channels per launch (1024 blocks = 4/CU)
constexpr int   kStatsBlocks = kN;    // one i-row per block

using short8 = __attribute__((ext_vector_type(8))) short;
using f32x4  = __attribute__((ext_vector_type(4))) float;

__device__ __forceinline__ unsigned short f2bf(float f) {
    __hip_bfloat16 h = __float2bfloat16(f);
    return *reinterpret_cast<unsigned short*>(&h);
}

// ---------------- small graph kernels ----------------

__global__ void k_edge(const int* __restrict__ ei, float* __restrict__ deg,
                       unsigned char* __restrict__ adj, unsigned char* __restrict__ adjT) {
    int e = blockIdx.x * 256 + threadIdx.x;
    if (e < kE) {
        int s = ei[e], d = ei[kE + e];
        atomicAdd(&deg[d], 1.0f);
        adj [s * kN + d] = 1;   // eim[s][d]
        adjT[d * kN + s] = 1;   // eim^T
    }
}

__global__ void k_dinv(const float* __restrict__ deg, float* __restrict__ dinv) {
    int n = blockIdx.x * 256 + threadIdx.x;
    if (n < kN) dinv[n] = rsqrtf(deg[n] + 1.0f);
}

__global__ void k_embed(const int* __restrict__ xids, const float* __restrict__ emb,
                        float* __restrict__ x0) {
    int t = blockIdx.x * 256 + threadIdx.x;  // kN*kH threads
    int n = t >> 5, c = t & 31;
    x0[t] = emb[xids[n] * kH + c];
}

// h = x @ W   (kN x 32) @ (32 x 32)
__global__ void k_node_mm(const float* __restrict__ x, const float* __restrict__ W,
                          float* __restrict__ h) {
    __shared__ float Ws[kH * kH];
    int t = threadIdx.x;
    for (int u = t; u < kH * kH; u += 256) Ws[u] = W[u];
    __syncthreads();
    int g = blockIdx.x * 256 + t;
    int n = g >> 5, c = g & 31;
    float acc = 0.f;
#pragma unroll
    for (int d = 0; d < kH; d++) acc = fmaf(x[n * kH + d], Ws[d * kH + c], acc);
    h[g] = acc;
}

__global__ void k_scatter(const int* __restrict__ ei, const float* __restrict__ h,
                          const float* __restrict__ dinv, float* __restrict__ agg) {
    int t = blockIdx.x * 256 + threadIdx.x;  // kE*kH threads
    int e = t >> 5, c = t & 31;
    int s = ei[e], d = ei[kE + e];
    atomicAdd(&agg[d * kH + c], h[s * kH + c] * dinv[s] * dinv[d]);
}

__global__ void k_gcn_post(float* __restrict__ agg, const float* __restrict__ h,
                           const float* __restrict__ dinv, const float* __restrict__ b) {
    int t = blockIdx.x * 256 + threadIdx.x;  // kN*kH
    int n = t >> 5, c = t & 31;
    agg[t] += h[t] * dinv[n] * dinv[n] + b[c];
}

// graphnorm over nodes (per channel), then relu. One block per channel.
__global__ void k_graphnorm(const float* __restrict__ x, float* __restrict__ out,
                            const float* __restrict__ g, const float* __restrict__ b,
                            const float* __restrict__ a, int M) {
    int c = blockIdx.x, t = threadIdx.x;
    float s = 0.f, ss = 0.f;
    for (int m = t; m < M; m += 256) { float v = x[m * kH + c]; s += v; ss += v * v; }
    __shared__ float rs[256], rss[256];
    rs[t] = s; rss[t] = ss;
    __syncthreads();
    for (int o = 128; o > 0; o >>= 1) {
        if (t < o) { rs[t] += rs[t + o]; rss[t] += rss[t + o]; }
        __syncthreads();
    }
    __shared__ float scale, shift;
    if (t == 0) {
        float mu  = rs[0] / (float)M;
        float ac  = a[c];
        float var = rss[0] / (float)M - 2.f * ac * mu * mu + ac * ac * mu * mu;
        float sc  = g[c] * rsqrtf(var + kEPS);
        scale = sc;
        shift = b[c] - sc * ac * mu;
    }
    __syncthreads();
    for (int m = t; m < M; m += 256) {
        float v = scale * x[m * kH + c] + shift;
        out[m * kH + c] = v > 0.f ? v : 0.f;
    }
}

// ---------------- x1 / x2^T generation (bf16, channel-major) — LDS-free, z-merged ----------------
// blockIdx.z in [0,4): bit0 selects X1 (adj,w1) vs X2^T (adjT,w2), bit1 selects the
// 8-channel half. All selection is wave-uniform (hoisted), so the per-thread register
// shape is IDENTICAL to the proven unfused kernel.
// NOTE: do NOT fuse X1+X2 per-thread (R4/R9: dual accumulators -> 144 VGPR, 3.4x slower).

template<int CW>
__global__ __launch_bounds__(256) void k_genxz(
        const float* __restrict__ xn,
        const unsigned char* __restrict__ adj, const unsigned char* __restrict__ adjT,
        const float* __restrict__ w1, const float* __restrict__ b1,
        const float* __restrict__ w2, const float* __restrict__ b2,
        __hip_bfloat16* __restrict__ X1, __hip_bfloat16* __restrict__ X2t, int c0base) {
    int zc = blockIdx.z;
    int c0 = c0base + (zc >> 1) * CW;
    const unsigned char* adjX = (zc & 1) ? adjT : adj;
    const float* w = (zc & 1) ? w2 : w1;
    const float* b = (zc & 1) ? b2 : b1;
    __hip_bfloat16* X = ((zc & 1) ? X2t : X1) + (size_t)(zc >> 1) * CW * kNN;
    int o = blockIdx.y;
    int in = blockIdx.x * 256 + threadIdx.x;
    float p[kH];
#pragma unroll
    for (int q = 0; q < 8; q++) {
        float4 vj = *(const float4*)&xn[in * kH + 4 * q];
        p[4 * q + 0] = xn[o * kH + 4 * q + 0] * vj.x;   // xn[o*..] uniform -> SGPR
        p[4 * q + 1] = xn[o * kH + 4 * q + 1] * vj.y;
        p[4 * q + 2] = xn[o * kH + 4 * q + 2] * vj.z;
        p[4 * q + 3] = xn[o * kH + 4 * q + 3] * vj.w;
    }
    float e = (float)adjX[o * kN + in];
    float v[CW];
#pragma unroll
    for (int cc = 0; cc < CW; cc++) v[cc] = b[c0 + cc];
#pragma unroll
    for (int d = 0; d < kH; d++) {
#pragma unroll
        for (int cc = 0; cc < CW; cc++)
            v[cc] = fmaf(p[d], w[d * kH + c0 + cc], v[cc]);   // 32B s_load per d
    }
#pragma unroll
    for (int cc = 0; cc < CW; cc++) {
        float r = fmaf(e, w[32 * kH + c0 + cc], v[cc]);
        X[(size_t)cc * kNN + (size_t)o * kN + in] = __float2bfloat16(r > 0.f ? r : 0.f);
    }
}

// ---------------- bf16 MFMA batched GEMM: C[c] = A[c] @ B[c], B given transposed ----------------
// XCD-aware remap (grid MUST be (8,8,16)): linear b = x+8y+64z, XCD = b&7 (round-robin).
// XCD g owns channels {2g, 2g+1}, sweeping their 64 tiles in order -> per-XCD L2 working
// set = one channel's A+B (4 MB) instead of all 16 channels' panels (~36 MB).
// C written with non-temporal stores (stream, no L2/L3 pollution of A/B).

__device__ __forceinline__ void g2l16(const unsigned short* g, unsigned short* l) {
    __builtin_amdgcn_global_load_lds(
        (const __attribute__((address_space(1))) void*)g,
        (__attribute__((address_space(3))) void*)l, 16, 0, 0);
}

__global__ __launch_bounds__(256) void k_bgemm_bf16(
        const unsigned short* __restrict__ A_, const unsigned short* __restrict__ Bt_,
        float* __restrict__ C_) {
    int b = blockIdx.x + 8 * blockIdx.y + 64 * blockIdx.z;   // [0,1024)
    int g = b & 7;                  // XCD id under round-robin dispatch
    int r = b >> 3;                 // [0,128): per-XCD sequence
    int c = 2 * g + (r >> 6);       // channel
    int tile = r & 63;
    int j0 = (tile & 7) * 128;
    int i0 = (tile >> 3) * 128;
    const unsigned short* A  = A_  + (size_t)c * kNN;
    const unsigned short* Bt = Bt_ + (size_t)c * kNN;
    float* C = C_ + (size_t)c * kNN;
    __shared__ unsigned short As[128 * 32];
    __shared__ unsigned short Bs[128 * 32];
    int t = threadIdx.x;
    int lane = t & 63, w = t >> 6;
    int wr = (w >> 1) * 64, wc = (w & 1) * 64;
    int l15 = lane & 15, lhi = lane >> 4;  // 0..3
    int srow = t >> 2, skel = (t & 3) * 8;
    f32x4 acc[4][4] = {};
    for (int k0 = 0; k0 < kN; k0 += 32) {
        g2l16(A  + (size_t)(i0 + srow)      * kN + k0 + skel, As + (size_t)t * 8);
        g2l16(A  + (size_t)(i0 + srow + 64) * kN + k0 + skel, As + (size_t)(t + 256) * 8);
        g2l16(Bt + (size_t)(j0 + srow)      * kN + k0 + skel, Bs + (size_t)t * 8);
        g2l16(Bt + (size_t)(j0 + srow + 64) * kN + k0 + skel, Bs + (size_t)(t + 256) * 8);
        asm volatile("s_waitcnt vmcnt(0)" ::: "memory");
        __syncthreads();
        short8 af[4], bf[4];
#pragma unroll
        for (int m = 0; m < 4; m++)
            af[m] = *(const short8*)&As[(wr + m * 16 + l15) * 32 + lhi * 8];
#pragma unroll
        for (int n = 0; n < 4; n++)
            bf[n] = *(const short8*)&Bs[(wc + n * 16 + l15) * 32 + lhi * 8];
#pragma unroll
        for (int m = 0; m < 4; m++)
#pragma unroll
            for (int n = 0; n < 4; n++)
                acc[m][n] = __builtin_amdgcn_mfma_f32_16x16x32_bf16(af[m], bf[n], acc[m][n], 0, 0, 0);
        __syncthreads();
    }
#pragma unroll
    for (int m = 0; m < 4; m++) {
        int row = i0 + wr + m * 16 + lhi * 4;
#pragma unroll
        for (int n = 0; n < 4; n++) {
            int col = j0 + wc + n * 16 + l15;
#pragma unroll
            for (int r2 = 0; r2 < 4; r2++)
                __builtin_nontemporal_store(acc[m][n][r2],
                                            &C[(size_t)(row + r2) * kN + col]);
        }
    }
}

// ---------------- gn3 statistics via MFMA (R8-proven) ----------------

__global__ __launch_bounds__(256) void k_stats_mfma(
        const float* __restrict__ xn, const unsigned char* __restrict__ adj,
        const float* __restrict__ prod, const float* __restrict__ w3,
        const float* __restrict__ b3, float* __restrict__ spart) {
    __shared__ unsigned short As[128 * 104];   // 26.6 KB feat tile
    __shared__ unsigned short Bs[32 * 104];    // 6.7 KB W3aug^T [c][k]
    __shared__ float xi[kH], lsum[kH], lssq[kH];
    int t = threadIdx.x;
    int i = blockIdx.x;
    int lane = t & 63, w = t >> 6;
    int l15 = lane & 15, lhi = lane >> 4;

    for (int u = t; u < 128 * 104 / 8; u += 256)
        *(short8*)&As[u * 8] = short8{0, 0, 0, 0, 0, 0, 0, 0};
    {   // W3aug^T: c = t&31, s-range (t>>5)*13..+13
        int c = t & 31, s0 = (t >> 5) * 13;
        for (int s = s0; s < s0 + 13; s++) {
            float v = 0.f;
            if (s <= 32)                 v = w3[s * kH + c];
            else if (s >= 34 && s <= 65) v = w3[(s - 1) * kH + c];
            else if (s == 66)            v = b3[c];
            Bs[c * 104 + s] = f2bf(v);
        }
    }
    if (t < kH) { xi[t] = xn[i * kH + t]; lsum[t] = 0.f; lssq[t] = 0.f; }
    __syncthreads();
    if (t < 128) As[t * 104 + 66] = f2bf(1.0f);   // bias column (persists)

    float s2[2] = {0.f, 0.f}, q22[2] = {0.f, 0.f};
    int wrow = w * 32;

    for (int kt = 0; kt < 8; kt++) {
        int kbase = kt * 128;
        {   // stage p (slots 0..31)
            int r = t >> 1, half = t & 1;
            int k = kbase + r;
            const float* xr = &xn[k * kH + half * 16];
            float4 v0 = *(const float4*)&xr[0];
            float4 v1 = *(const float4*)&xr[4];
            float4 v2 = *(const float4*)&xr[8];
            float4 v3 = *(const float4*)&xr[12];
            const float* xih = &xi[half * 16];
            short8 o0, o1;
            o0[0] = f2bf(xih[0] * v0.x);  o0[1] = f2bf(xih[1] * v0.y);
            o0[2] = f2bf(xih[2] * v0.z);  o0[3] = f2bf(xih[3] * v0.w);
            o0[4] = f2bf(xih[4] * v1.x);  o0[5] = f2bf(xih[5] * v1.y);
            o0[6] = f2bf(xih[6] * v1.z);  o0[7] = f2bf(xih[7] * v1.w);
            o1[0] = f2bf(xih[8] * v2.x);  o1[1] = f2bf(xih[9] * v2.y);
            o1[2] = f2bf(xih[10] * v2.z); o1[3] = f2bf(xih[11] * v2.w);
            o1[4] = f2bf(xih[12] * v3.x); o1[5] = f2bf(xih[13] * v3.y);
            o1[6] = f2bf(xih[14] * v3.z); o1[7] = f2bf(xih[15] * v3.w);
            *(short8*)&As[r * 104 + half * 16]     = o0;
            *(short8*)&As[r * 104 + half * 16 + 8] = o1;
        }
        if (t < 128) As[t * 104 + 32] = f2bf((float)adj[i * kN + kbase + t]);
        {   // stage pr (slots 34..65)
            int kq = t & 15, dp = t >> 4, d2 = dp * 2;
            const float* p0 = &prod[(size_t)d2 * kNN + (size_t)i * kN + kbase + kq * 8];
            const float* p1 = p0 + kNN;
            float4 a0 = *(const float4*)&p0[0];
            float4 a1 = *(const float4*)&p0[4];
            float4 b0 = *(const float4*)&p1[0];
            float4 b1 = *(const float4*)&p1[4];
            float r0[8] = {a0.x, a0.y, a0.z, a0.w, a1.x, a1.y, a1.z, a1.w};
            float r1[8] = {b0.x, b0.y, b0.z, b0.w, b1.x, b1.y, b1.z, b1.w};
            unsigned int* As32 = (unsigned int*)As;
#pragma unroll
            for (int j = 0; j < 8; j++) {
                int jr = (j + kq) & 7;
                int kl = kq * 8 + jr;
                unsigned int val = (unsigned int)f2bf(r0[jr]) |
                                   ((unsigned int)f2bf(r1[jr]) << 16);
                As32[kl * 52 + 17 + dp] = val;
            }
        }
        __syncthreads();
        f32x4 acc[2][2] = {};
#pragma unroll
        for (int ks = 0; ks < 3; ks++) {
            short8 af0 = *(const short8*)&As[(wrow + l15) * 104 + ks * 32 + lhi * 8];
            short8 af1 = *(const short8*)&As[(wrow + 16 + l15) * 104 + ks * 32 + lhi * 8];
            short8 bf0 = *(const short8*)&Bs[l15 * 104 + ks * 32 + lhi * 8];
            short8 bf1 = *(const short8*)&Bs[(16 + l15) * 104 + ks * 32 + lhi * 8];
            acc[0][0] = __builtin_amdgcn_mfma_f32_16x16x32_bf16(af0, bf0, acc[0][0], 0, 0, 0);
            acc[0][1] = __builtin_amdgcn_mfma_f32_16x16x32_bf16(af0, bf1, acc[0][1], 0, 0, 0);
            acc[1][0] = __builtin_amdgcn_mfma_f32_16x16x32_bf16(af1, bf0, acc[1][0], 0, 0, 0);
            acc[1][1] = __builtin_amdgcn_mfma_f32_16x16x32_bf16(af1, bf1, acc[1][1], 0, 0, 0);
        }
#pragma unroll
        for (int ct = 0; ct < 2; ct++)
#pragma unroll
            for (int rt = 0; rt < 2; rt++)
#pragma unroll
                for (int r = 0; r < 4; r++) {
                    float y = acc[rt][ct][r];
                    s2[ct] += y;
                    q22[ct] = fmaf(y, y, q22[ct]);
                }
        __syncthreads();
    }
#pragma unroll
    for (int ct = 0; ct < 2; ct++) {
        s2[ct]  += __shfl_xor(s2[ct], 16);  s2[ct]  += __shfl_xor(s2[ct], 32);
        q22[ct] += __shfl_xor(q22[ct], 16); q22[ct] += __shfl_xor(q22[ct], 32);
    }
    if (lane < 16) {
#pragma unroll
        for (int ct = 0; ct < 2; ct++) {
            atomicAdd(&lsum[ct * 16 + l15], s2[ct]);
            atomicAdd(&lssq[ct * 16 + l15], q22[ct]);
        }
    }
    __syncthreads();
    if (t < kH)          spart[(size_t)i * 64 + t]             = lsum[t];
    else if (t < 2 * kH) spart[(size_t)i * 64 + 32 + (t - kH)] = lssq[t - kH];
}

// parallel reduce spart[1024][64] -> stats[64]
__global__ __launch_bounds__(256) void k_reduce(const float* __restrict__ spart,
                                                float* __restrict__ stats) {
    int slot = blockIdx.x;   // 64 blocks
    int t = threadIdx.x;
    float acc = 0.f;
    for (int r = t; r < kStatsBlocks; r += 256) acc += spart[(size_t)r * 64 + slot];
    __shared__ float red[256];
    red[t] = acc;
    __syncthreads();
    for (int o = 128; o > 0; o >>= 1) {
        if (t < o) red[t] += red[t + o];
        __syncthreads();
    }
    if (t == 0) stats[slot] = red[0];
}

__global__ void k_finalize(const float* __restrict__ stats, const float* __restrict__ g,
                           const float* __restrict__ b, const float* __restrict__ a,
                           float* __restrict__ ss) {
    int c = threadIdx.x;  // 32 threads
    float M   = (float)((double)kNN);
    float mu  = stats[c] / M;
    float ac  = a[c];
    float var = stats[kH + c] / M - 2.f * ac * mu * mu + ac * ac * mu * mu;
    float sc  = g[c] * rsqrtf(var + kEPS);
    ss[c]      = sc;
    ss[kH + c] = b[c] - sc * ac * mu;
}

// ---------------- final: one wave per query (R9-verified) ----------------

__global__ __launch_bounds__(256) void k_out(
        const int* __restrict__ pos, const float* __restrict__ xn,
        const unsigned char* __restrict__ adj, const float* __restrict__ prod,
        const float* __restrict__ w3, const float* __restrict__ b3,
        const float* __restrict__ ss, const float* __restrict__ wdir,
        const float* __restrict__ bdir, float* __restrict__ out) {
    __shared__ float W3s[65 * kH], b3s[kH], scs[kH], shs[kH], wd[kH];
    int t = threadIdx.x;
    for (int u = t; u < 65 * kH; u += 256) W3s[u] = w3[u];
    if (t < kH) { b3s[t] = b3[t]; scs[t] = ss[t]; shs[t] = ss[kH + t]; wd[t] = wdir[t]; }
    __syncthreads();
    int q = blockIdx.x * 4 + (t >> 6);
    int lane = t & 63;
    int c = lane & 31, h = lane >> 5;
    int i = pos[2 * q], k = pos[2 * q + 1];
    size_t addr = h ? ((size_t)k * kN + i) : ((size_t)i * kN + k);
    float pr_reg = prod[(size_t)c * kNN + addr];      // my direction, channel index c
    float p_reg  = xn[i * kH + c] * xn[k * kH + c];   // symmetric in (i,k)
    float e_reg  = (float)adj[addr];
    float y = b3s[c];
#pragma unroll
    for (int d = 0; d < kH; d++)
        y = fmaf(__shfl(p_reg, d), W3s[d * kH + c], y);
    y = fmaf(e_reg, W3s[32 * kH + c], y);
#pragma unroll
    for (int d = 0; d < kH; d++)
        y = fmaf(__shfl(pr_reg, (h << 5) + d), W3s[(33 + d) * kH + c], y);
    float z = scs[c] * y + shs[c];
    z = z > 0.f ? z : 0.f;
    float zo = __shfl_xor(z, 32);        // other direction, same channel
    float v = z * zo * wd[c];
#pragma unroll
    for (int o = 16; o > 0; o >>= 1) v += __shfl_xor(v, o);
    if (lane == 0) out[q] = v + bdir[0];
}

// ---------------- launch ----------------

extern "C" void kernel_launch(void* const* d_in, const int* in_sizes, int n_in,
                              void* d_out, int out_size, void* d_ws, size_t ws_size,
                              hipStream_t stream) {
    const int*   x_ids = (const int*)d_in[0];
    const int*   ei    = (const int*)d_in[1];
    const int*   pos   = (const int*)d_in[2];
    const float* emb   = (const float*)d_in[3];
    const float* gw0   = (const float*)d_in[4];
    const float* gb0   = (const float*)d_in[5];
    const float* g0g   = (const float*)d_in[6];
    const float* g0b   = (const float*)d_in[7];
    const float* g0a   = (const float*)d_in[8];
    const float* gw1   = (const float*)d_in[9];
    const float* gb1   = (const float*)d_in[10];
    const float* g1g   = (const float*)d_in[11];
    const float* g1b   = (const float*)d_in[12];
    const float* g1a   = (const float*)d_in[13];
    const float* wm1   = (const float*)d_in[14];
    const float* bm1   = (const float*)d_in[15];
    const float* wm2   = (const float*)d_in[16];
    const float* bm2   = (const float*)d_in[17];
    const float* wm3   = (const float*)d_in[18];
    const float* bm3   = (const float*)d_in[19];
    const float* g3g   = (const float*)d_in[20];
    const float* g3b   = (const float*)d_in[21];
    const float* g3a   = (const float*)d_in[22];
    const float* wdir  = (const float*)d_in[23];
    const float* bdir  = (const float*)d_in[24];
    float* out = (float*)d_out;

    // workspace layout — 128 + 32 + 32 + ~2.3 MiB ≈ 194 MiB (ws = 256 MiB)
    const size_t fixedF = (size_t)kH * kNN;                       // prod floats
    float* prod = (float*)d_ws;                                   // 128 MiB
    unsigned short* X1c = (unsigned short*)(prod + fixedF);       // 32 MiB bf16 (16 ch)
    unsigned short* X2c = X1c + (size_t)kCWb * kNN;               // 32 MiB bf16 (transposed)
    unsigned char* adj  = (unsigned char*)(X2c + (size_t)kCWb * kNN);  // 1 MiB
    unsigned char* adjT = adj + kNN;                                    // 1 MiB
    float* deg   = (float*)(adjT + kNN);
    float* dinv  = deg + kN;
    float* x0    = dinv + kN;
    float* h     = x0 + kN * kH;
    float* agg   = h + kN * kH;
    float* xa    = agg + kN * kH;
    float* xb    = xa + kN * kH;
    float* spart = xb + kN * kH;                 // 1024*64 floats (256 KB)
    float* stats = spart + (size_t)kStatsBlocks * 64;
    float* ss    = stats + 2 * kH;

    hipMemsetAsync(deg, 0, kN * sizeof(float), stream);
    hipMemsetAsync(adj, 0, 2 * kNN, stream);   // adj + adjT contiguous
    hipMemsetAsync(agg, 0, kN * kH * sizeof(float), stream);

    k_edge<<<(kE + 255) / 256, 256, 0, stream>>>(ei, deg, adj, adjT);
    k_dinv<<<4, 256, 0, stream>>>(deg, dinv);
    k_embed<<<kN * kH / 256, 256, 0, stream>>>(x_ids, emb, x0);

    // GCN layer 0
    k_node_mm<<<kN * kH / 256, 256, 0, stream>>>(x0, gw0, h);
    k_scatter<<<kE * kH / 256, 256, 0, stream>>>(ei, h, dinv, agg);
    k_gcn_post<<<kN * kH / 256, 256, 0, stream>>>(agg, h, dinv, gb0);
    k_graphnorm<<<kH, 256, 0, stream>>>(agg, xa, g0g, g0b, g0a, kN);

    // GCN layer 1
    hipMemsetAsync(agg, 0, kN * kH * sizeof(float), stream);
    k_node_mm<<<kN * kH / 256, 256, 0, stream>>>(xa, gw1, h);
    k_scatter<<<kE * kH / 256, 256, 0, stream>>>(ei, h, dinv, agg);
    k_gcn_post<<<kN * kH / 256, 256, 0, stream>>>(agg, h, dinv, gb1);
    k_graphnorm<<<kH, 256, 0, stream>>>(agg, xb, g1g, g1b, g1a, kN);

    // pairwise bf16 features (z-merged, LDS-free) + 16-channel-batched MFMA GEMMs
    for (int c0 = 0; c0 < kH; c0 += kCWb) {
        k_genxz<kCWg><<<dim3(4, kN, 4), 256, 0, stream>>>(
            xb, adj, adjT, wm1, bm1, wm2, bm2,
            (__hip_bfloat16*)X1c, (__hip_bfloat16*)X2c, c0);
        k_bgemm_bf16<<<dim3(8, 8, kCWb), 256, 0, stream>>>(X1c, X2c, prod + (size_t)c0 * kNN);
    }

    // gn3 stats: MFMA projection, y never materialized
    k_stats_mfma<<<kStatsBlocks, 256, 0, stream>>>(xb, adj, prod, wm3, bm3, spart);
    k_reduce<<<64, 256, 0, stream>>>(spart, stats);
    k_finalize<<<1, 32, 0, stream>>>(stats, g3g, g3b, g3a, ss);

    // final gather: one wave per query
    k_out<<<kQ / 4, 256, 0, stream>>>(pos, xb, adj, prod, wm3, bm3, ss, wdir, bdir, out);
}

// Round 14
// 453.437 us; speedup vs baseline: 1.7056x; 1.0135x over previous
//
#include <hip/hip_runtime.h>
#include <hip/hip_bf16.h>
#include <cstddef>

constexpr int   kN  = 1024;
constexpr int   kE  = 16384;
constexpr int   kQ  = 8192;
constexpr int   kH  = 32;
constexpr size_t kNN = (size_t)kN * kN;
constexpr float kEPS = 1e-5f;
constexpr int   kCWg = 8;             // genx channels per z-slice (register-proven shape)
constexpr int   kCWb = 16;            // bgemm channels per launch (1024 blocks = 4/CU)
constexpr int   kStatsBlocks = kN;    // one i-row per block

using short8 = __attribute__((ext_vector_type(8))) short;
using f32x4  = __attribute__((ext_vector_type(4))) float;

__device__ __forceinline__ unsigned short f2bf(float f) {
    __hip_bfloat16 h = __float2bfloat16(f);
    return *reinterpret_cast<unsigned short*>(&h);
}

// ---------------- small graph kernels ----------------

__global__ void k_edge(const int* __restrict__ ei, float* __restrict__ deg,
                       unsigned char* __restrict__ adj, unsigned char* __restrict__ adjT) {
    int e = blockIdx.x * 256 + threadIdx.x;
    if (e < kE) {
        int s = ei[e], d = ei[kE + e];
        atomicAdd(&deg[d], 1.0f);
        adj [s * kN + d] = 1;   // eim[s][d]
        adjT[d * kN + s] = 1;   // eim^T
    }
}

__global__ void k_dinv(const float* __restrict__ deg, float* __restrict__ dinv) {
    int n = blockIdx.x * 256 + threadIdx.x;
    if (n < kN) dinv[n] = rsqrtf(deg[n] + 1.0f);
}

__global__ void k_embed(const int* __restrict__ xids, const float* __restrict__ emb,
                        float* __restrict__ x0) {
    int t = blockIdx.x * 256 + threadIdx.x;  // kN*kH threads
    int n = t >> 5, c = t & 31;
    x0[t] = emb[xids[n] * kH + c];
}

// h = x @ W   (kN x 32) @ (32 x 32)
__global__ void k_node_mm(const float* __restrict__ x, const float* __restrict__ W,
                          float* __restrict__ h) {
    __shared__ float Ws[kH * kH];
    int t = threadIdx.x;
    for (int u = t; u < kH * kH; u += 256) Ws[u] = W[u];
    __syncthreads();
    int g = blockIdx.x * 256 + t;
    int n = g >> 5, c = g & 31;
    float acc = 0.f;
#pragma unroll
    for (int d = 0; d < kH; d++) acc = fmaf(x[n * kH + d], Ws[d * kH + c], acc);
    h[g] = acc;
}

__global__ void k_scatter(const int* __restrict__ ei, const float* __restrict__ h,
                          const float* __restrict__ dinv, float* __restrict__ agg) {
    int t = blockIdx.x * 256 + threadIdx.x;  // kE*kH threads
    int e = t >> 5, c = t & 31;
    int s = ei[e], d = ei[kE + e];
    atomicAdd(&agg[d * kH + c], h[s * kH + c] * dinv[s] * dinv[d]);
}

__global__ void k_gcn_post(float* __restrict__ agg, const float* __restrict__ h,
                           const float* __restrict__ dinv, const float* __restrict__ b) {
    int t = blockIdx.x * 256 + threadIdx.x;  // kN*kH
    int n = t >> 5, c = t & 31;
    agg[t] += h[t] * dinv[n] * dinv[n] + b[c];
}

// graphnorm over nodes (per channel), then relu. One block per channel.
__global__ void k_graphnorm(const float* __restrict__ x, float* __restrict__ out,
                            const float* __restrict__ g, const float* __restrict__ b,
                            const float* __restrict__ a, int M) {
    int c = blockIdx.x, t = threadIdx.x;
    float s = 0.f, ss = 0.f;
    for (int m = t; m < M; m += 256) { float v = x[m * kH + c]; s += v; ss += v * v; }
    __shared__ float rs[256], rss[256];
    rs[t] = s; rss[t] = ss;
    __syncthreads();
    for (int o = 128; o > 0; o >>= 1) {
        if (t < o) { rs[t] += rs[t + o]; rss[t] += rss[t + o]; }
        __syncthreads();
    }
    __shared__ float scale, shift;
    if (t == 0) {
        float mu  = rs[0] / (float)M;
        float ac  = a[c];
        float var = rss[0] / (float)M - 2.f * ac * mu * mu + ac * ac * mu * mu;
        float sc  = g[c] * rsqrtf(var + kEPS);
        scale = sc;
        shift = b[c] - sc * ac * mu;
    }
    __syncthreads();
    for (int m = t; m < M; m += 256) {
        float v = scale * x[m * kH + c] + shift;
        out[m * kH + c] = v > 0.f ? v : 0.f;
    }
}

// ---------------- x1 / x2^T generation (bf16, channel-major) — LDS-free math, LDS-transposed stores ----------------
// blockIdx.z in [0,4): bit0 selects X1 (adj,w1) vs X2^T (adjT,w2), bit1 selects the
// 8-channel half. All selection is wave-uniform (hoisted); per-thread math shape is
// the proven unfused kernel. Results staged through a 4KB LDS tile so each thread
// emits ONE 16B store (was 8x 2B scattered stores -> store-issue bound, R13).
// NOTE: do NOT fuse X1+X2 per-thread (R4/R9: dual accumulators -> 144 VGPR, 3.4x slower).

template<int CW>
__global__ __launch_bounds__(256) void k_genxz(
        const float* __restrict__ xn,
        const unsigned char* __restrict__ adj, const unsigned char* __restrict__ adjT,
        const float* __restrict__ w1, const float* __restrict__ b1,
        const float* __restrict__ w2, const float* __restrict__ b2,
        __hip_bfloat16* __restrict__ X1, __hip_bfloat16* __restrict__ X2t, int c0base) {
    static_assert(CW * 32 == 256, "store re-partition assumes CW*32 == blockDim");
    int zc = blockIdx.z;
    int c0 = c0base + (zc >> 1) * CW;
    const unsigned char* adjX = (zc & 1) ? adjT : adj;
    const float* w = (zc & 1) ? w2 : w1;
    const float* b = (zc & 1) ? b2 : b1;
    __hip_bfloat16* X = ((zc & 1) ? X2t : X1) + (size_t)(zc >> 1) * CW * kNN;
    int o = blockIdx.y;
    int t = threadIdx.x;
    int i0 = blockIdx.x * 256;
    int in = i0 + t;
    float p[kH];
#pragma unroll
    for (int q = 0; q < 8; q++) {
        float4 vj = *(const float4*)&xn[in * kH + 4 * q];
        p[4 * q + 0] = xn[o * kH + 4 * q + 0] * vj.x;   // xn[o*..] uniform -> SGPR
        p[4 * q + 1] = xn[o * kH + 4 * q + 1] * vj.y;
        p[4 * q + 2] = xn[o * kH + 4 * q + 2] * vj.z;
        p[4 * q + 3] = xn[o * kH + 4 * q + 3] * vj.w;
    }
    float e = (float)adjX[o * kN + in];
    float v[CW];
#pragma unroll
    for (int cc = 0; cc < CW; cc++) v[cc] = b[c0 + cc];
#pragma unroll
    for (int d = 0; d < kH; d++) {
#pragma unroll
        for (int cc = 0; cc < CW; cc++)
            v[cc] = fmaf(p[d], w[d * kH + c0 + cc], v[cc]);   // 32B s_load per d
    }
    __shared__ unsigned short lds[CW][256];
#pragma unroll
    for (int cc = 0; cc < CW; cc++) {
        float r = fmaf(e, w[32 * kH + c0 + cc], v[cc]);
        lds[cc][t] = f2bf(r > 0.f ? r : 0.f);
    }
    __syncthreads();
    // re-partition: thread t -> channel t>>5, 8-elem segment t&31; one 16B store
    int cc = t >> 5, seg = t & 31;
    short8 val = *(const short8*)&lds[cc][seg * 8];
    unsigned short* Xp = (unsigned short*)X;
    *(short8*)&Xp[(size_t)cc * kNN + (size_t)o * kN + i0 + seg * 8] = val;
}

// ---------------- bf16 MFMA batched GEMM: C[c] = A[c] @ B[c], B given transposed ----------------
// XCD-aware remap (grid MUST be (8,8,16)): linear b = x+8y+64z, XCD = b&7 (round-robin).
// XCD g owns channels {2g, 2g+1}; C written with non-temporal stores.

__device__ __forceinline__ void g2l16(const unsigned short* g, unsigned short* l) {
    __builtin_amdgcn_global_load_lds(
        (const __attribute__((address_space(1))) void*)g,
        (__attribute__((address_space(3))) void*)l, 16, 0, 0);
}

__global__ __launch_bounds__(256) void k_bgemm_bf16(
        const unsigned short* __restrict__ A_, const unsigned short* __restrict__ Bt_,
        float* __restrict__ C_) {
    int b = blockIdx.x + 8 * blockIdx.y + 64 * blockIdx.z;   // [0,1024)
    int g = b & 7;                  // XCD id under round-robin dispatch
    int r = b >> 3;                 // [0,128): per-XCD sequence
    int c = 2 * g + (r >> 6);       // channel
    int tile = r & 63;
    int j0 = (tile & 7) * 128;
    int i0 = (tile >> 3) * 128;
    const unsigned short* A  = A_  + (size_t)c * kNN;
    const unsigned short* Bt = Bt_ + (size_t)c * kNN;
    float* C = C_ + (size_t)c * kNN;
    __shared__ unsigned short As[128 * 32];
    __shared__ unsigned short Bs[128 * 32];
    int t = threadIdx.x;
    int lane = t & 63, w = t >> 6;
    int wr = (w >> 1) * 64, wc = (w & 1) * 64;
    int l15 = lane & 15, lhi = lane >> 4;  // 0..3
    int srow = t >> 2, skel = (t & 3) * 8;
    f32x4 acc[4][4] = {};
    for (int k0 = 0; k0 < kN; k0 += 32) {
        g2l16(A  + (size_t)(i0 + srow)      * kN + k0 + skel, As + (size_t)t * 8);
        g2l16(A  + (size_t)(i0 + srow + 64) * kN + k0 + skel, As + (size_t)(t + 256) * 8);
        g2l16(Bt + (size_t)(j0 + srow)      * kN + k0 + skel, Bs + (size_t)t * 8);
        g2l16(Bt + (size_t)(j0 + srow + 64) * kN + k0 + skel, Bs + (size_t)(t + 256) * 8);
        asm volatile("s_waitcnt vmcnt(0)" ::: "memory");
        __syncthreads();
        short8 af[4], bf[4];
#pragma unroll
        for (int m = 0; m < 4; m++)
            af[m] = *(const short8*)&As[(wr + m * 16 + l15) * 32 + lhi * 8];
#pragma unroll
        for (int n = 0; n < 4; n++)
            bf[n] = *(const short8*)&Bs[(wc + n * 16 + l15) * 32 + lhi * 8];
#pragma unroll
        for (int m = 0; m < 4; m++)
#pragma unroll
            for (int n = 0; n < 4; n++)
                acc[m][n] = __builtin_amdgcn_mfma_f32_16x16x32_bf16(af[m], bf[n], acc[m][n], 0, 0, 0);
        __syncthreads();
    }
#pragma unroll
    for (int m = 0; m < 4; m++) {
        int row = i0 + wr + m * 16 + lhi * 4;
#pragma unroll
        for (int n = 0; n < 4; n++) {
            int col = j0 + wc + n * 16 + l15;
#pragma unroll
            for (int r2 = 0; r2 < 4; r2++)
                __builtin_nontemporal_store(acc[m][n][r2],
                                            &C[(size_t)(row + r2) * kN + col]);
        }
    }
}

// ---------------- gn3 statistics via MFMA (R8-proven) ----------------

__global__ __launch_bounds__(256) void k_stats_mfma(
        const float* __restrict__ xn, const unsigned char* __restrict__ adj,
        const float* __restrict__ prod, const float* __restrict__ w3,
        const float* __restrict__ b3, float* __restrict__ spart) {
    __shared__ unsigned short As[128 * 104];   // 26.6 KB feat tile
    __shared__ unsigned short Bs[32 * 104];    // 6.7 KB W3aug^T [c][k]
    __shared__ float xi[kH], lsum[kH], lssq[kH];
    int t = threadIdx.x;
    int i = blockIdx.x;
    int lane = t & 63, w = t >> 6;
    int l15 = lane & 15, lhi = lane >> 4;

    for (int u = t; u < 128 * 104 / 8; u += 256)
        *(short8*)&As[u * 8] = short8{0, 0, 0, 0, 0, 0, 0, 0};
    {   // W3aug^T: c = t&31, s-range (t>>5)*13..+13
        int c = t & 31, s0 = (t >> 5) * 13;
        for (int s = s0; s < s0 + 13; s++) {
            float v = 0.f;
            if (s <= 32)                 v = w3[s * kH + c];
            else if (s >= 34 && s <= 65) v = w3[(s - 1) * kH + c];
            else if (s == 66)            v = b3[c];
            Bs[c * 104 + s] = f2bf(v);
        }
    }
    if (t < kH) { xi[t] = xn[i * kH + t]; lsum[t] = 0.f; lssq[t] = 0.f; }
    __syncthreads();
    if (t < 128) As[t * 104 + 66] = f2bf(1.0f);   // bias column (persists)

    float s2[2] = {0.f, 0.f}, q22[2] = {0.f, 0.f};
    int wrow = w * 32;

    for (int kt = 0; kt < 8; kt++) {
        int kbase = kt * 128;
        {   // stage p (slots 0..31)
            int r = t >> 1, half = t & 1;
            int k = kbase + r;
            const float* xr = &xn[k * kH + half * 16];
            float4 v0 = *(const float4*)&xr[0];
            float4 v1 = *(const float4*)&xr[4];
            float4 v2 = *(const float4*)&xr[8];
            float4 v3 = *(const float4*)&xr[12];
            const float* xih = &xi[half * 16];
            short8 o0, o1;
            o0[0] = f2bf(xih[0] * v0.x);  o0[1] = f2bf(xih[1] * v0.y);
            o0[2] = f2bf(xih[2] * v0.z);  o0[3] = f2bf(xih[3] * v0.w);
            o0[4] = f2bf(xih[4] * v1.x);  o0[5] = f2bf(xih[5] * v1.y);
            o0[6] = f2bf(xih[6] * v1.z);  o0[7] = f2bf(xih[7] * v1.w);
            o1[0] = f2bf(xih[8] * v2.x);  o1[1] = f2bf(xih[9] * v2.y);
            o1[2] = f2bf(xih[10] * v2.z); o1[3] = f2bf(xih[11] * v2.w);
            o1[4] = f2bf(xih[12] * v3.x); o1[5] = f2bf(xih[13] * v3.y);
            o1[6] = f2bf(xih[14] * v3.z); o1[7] = f2bf(xih[15] * v3.w);
            *(short8*)&As[r * 104 + half * 16]     = o0;
            *(short8*)&As[r * 104 + half * 16 + 8] = o1;
        }
        if (t < 128) As[t * 104 + 32] = f2bf((float)adj[i * kN + kbase + t]);
        {   // stage pr (slots 34..65)
            int kq = t & 15, dp = t >> 4, d2 = dp * 2;
            const float* p0 = &prod[(size_t)d2 * kNN + (size_t)i * kN + kbase + kq * 8];
            const float* p1 = p0 + kNN;
            float4 a0 = *(const float4*)&p0[0];
            float4 a1 = *(const float4*)&p0[4];
            float4 b0 = *(const float4*)&p1[0];
            float4 b1 = *(const float4*)&p1[4];
            float r0[8] = {a0.x, a0.y, a0.z, a0.w, a1.x, a1.y, a1.z, a1.w};
            float r1[8] = {b0.x, b0.y, b0.z, b0.w, b1.x, b1.y, b1.z, b1.w};
            unsigned int* As32 = (unsigned int*)As;
#pragma unroll
            for (int j = 0; j < 8; j++) {
                int jr = (j + kq) & 7;
                int kl = kq * 8 + jr;
                unsigned int val = (unsigned int)f2bf(r0[jr]) |
                                   ((unsigned int)f2bf(r1[jr]) << 16);
                As32[kl * 52 + 17 + dp] = val;
            }
        }
        __syncthreads();
        f32x4 acc[2][2] = {};
#pragma unroll
        for (int ks = 0; ks < 3; ks++) {
            short8 af0 = *(const short8*)&As[(wrow + l15) * 104 + ks * 32 + lhi * 8];
            short8 af1 = *(const short8*)&As[(wrow + 16 + l15) * 104 + ks * 32 + lhi * 8];
            short8 bf0 = *(const short8*)&Bs[l15 * 104 + ks * 32 + lhi * 8];
            short8 bf1 = *(const short8*)&Bs[(16 + l15) * 104 + ks * 32 + lhi * 8];
            acc[0][0] = __builtin_amdgcn_mfma_f32_16x16x32_bf16(af0, bf0, acc[0][0], 0, 0, 0);
            acc[0][1] = __builtin_amdgcn_mfma_f32_16x16x32_bf16(af0, bf1, acc[0][1], 0, 0, 0);
            acc[1][0] = __builtin_amdgcn_mfma_f32_16x16x32_bf16(af1, bf0, acc[1][0], 0, 0, 0);
            acc[1][1] = __builtin_amdgcn_mfma_f32_16x16x32_bf16(af1, bf1, acc[1][1], 0, 0, 0);
        }
#pragma unroll
        for (int ct = 0; ct < 2; ct++)
#pragma unroll
            for (int rt = 0; rt < 2; rt++)
#pragma unroll
                for (int r = 0; r < 4; r++) {
                    float y = acc[rt][ct][r];
                    s2[ct] += y;
                    q22[ct] = fmaf(y, y, q22[ct]);
                }
        __syncthreads();
    }
#pragma unroll
    for (int ct = 0; ct < 2; ct++) {
        s2[ct]  += __shfl_xor(s2[ct], 16);  s2[ct]  += __shfl_xor(s2[ct], 32);
        q22[ct] += __shfl_xor(q22[ct], 16); q22[ct] += __shfl_xor(q22[ct], 32);
    }
    if (lane < 16) {
#pragma unroll
        for (int ct = 0; ct < 2; ct++) {
            atomicAdd(&lsum[ct * 16 + l15], s2[ct]);
            atomicAdd(&lssq[ct * 16 + l15], q22[ct]);
        }
    }
    __syncthreads();
    if (t < kH)          spart[(size_t)i * 64 + t]             = lsum[t];
    else if (t < 2 * kH) spart[(size_t)i * 64 + 32 + (t - kH)] = lssq[t - kH];
}

// parallel reduce spart[1024][64] -> stats[64]
__global__ __launch_bounds__(256) void k_reduce(const float* __restrict__ spart,
                                                float* __restrict__ stats) {
    int slot = blockIdx.x;   // 64 blocks
    int t = threadIdx.x;
    float acc = 0.f;
    for (int r = t; r < kStatsBlocks; r += 256) acc += spart[(size_t)r * 64 + slot];
    __shared__ float red[256];
    red[t] = acc;
    __syncthreads();
    for (int o = 128; o > 0; o >>= 1) {
        if (t < o) red[t] += red[t + o];
        __syncthreads();
    }
    if (t == 0) stats[slot] = red[0];
}

__global__ void k_finalize(const float* __restrict__ stats, const float* __restrict__ g,
                           const float* __restrict__ b, const float* __restrict__ a,
                           float* __restrict__ ss) {
    int c = threadIdx.x;  // 32 threads
    float M   = (float)((double)kNN);
    float mu  = stats[c] / M;
    float ac  = a[c];
    float var = stats[kH + c] / M - 2.f * ac * mu * mu + ac * ac * mu * mu;
    float sc  = g[c] * rsqrtf(var + kEPS);
    ss[c]      = sc;
    ss[kH + c] = b[c] - sc * ac * mu;
}

// ---------------- final: one wave per query (R9-verified) ----------------

__global__ __launch_bounds__(256) void k_out(
        const int* __restrict__ pos, const float* __restrict__ xn,
        const unsigned char* __restrict__ adj, const float* __restrict__ prod,
        const float* __restrict__ w3, const float* __restrict__ b3,
        const float* __restrict__ ss, const float* __restrict__ wdir,
        const float* __restrict__ bdir, float* __restrict__ out) {
    __shared__ float W3s[65 * kH], b3s[kH], scs[kH], shs[kH], wd[kH];
    int t = threadIdx.x;
    for (int u = t; u < 65 * kH; u += 256) W3s[u] = w3[u];
    if (t < kH) { b3s[t] = b3[t]; scs[t] = ss[t]; shs[t] = ss[kH + t]; wd[t] = wdir[t]; }
    __syncthreads();
    int q = blockIdx.x * 4 + (t >> 6);
    int lane = t & 63;
    int c = lane & 31, h = lane >> 5;
    int i = pos[2 * q], k = pos[2 * q + 1];
    size_t addr = h ? ((size_t)k * kN + i) : ((size_t)i * kN + k);
    float pr_reg = prod[(size_t)c * kNN + addr];      // my direction, channel index c
    float p_reg  = xn[i * kH + c] * xn[k * kH + c];   // symmetric in (i,k)
    float e_reg  = (float)adj[addr];
    float y = b3s[c];
#pragma unroll
    for (int d = 0; d < kH; d++)
        y = fmaf(__shfl(p_reg, d), W3s[d * kH + c], y);
    y = fmaf(e_reg, W3s[32 * kH + c], y);
#pragma unroll
    for (int d = 0; d < kH; d++)
        y = fmaf(__shfl(pr_reg, (h << 5) + d), W3s[(33 + d) * kH + c], y);
    float z = scs[c] * y + shs[c];
    z = z > 0.f ? z : 0.f;
    float zo = __shfl_xor(z, 32);        // other direction, same channel
    float v = z * zo * wd[c];
#pragma unroll
    for (int o = 16; o > 0; o >>= 1) v += __shfl_xor(v, o);
    if (lane == 0) out[q] = v + bdir[0];
}

// ---------------- launch ----------------

extern "C" void kernel_launch(void* const* d_in, const int* in_sizes, int n_in,
                              void* d_out, int out_size, void* d_ws, size_t ws_size,
                              hipStream_t stream) {
    const int*   x_ids = (const int*)d_in[0];
    const int*   ei    = (const int*)d_in[1];
    const int*   pos   = (const int*)d_in[2];
    const float* emb   = (const float*)d_in[3];
    const float* gw0   = (const float*)d_in[4];
    const float* gb0   = (const float*)d_in[5];
    const float* g0g   = (const float*)d_in[6];
    const float* g0b   = (const float*)d_in[7];
    const float* g0a   = (const float*)d_in[8];
    const float* gw1   = (const float*)d_in[9];
    const float* gb1   = (const float*)d_in[10];
    const float* g1g   = (const float*)d_in[11];
    const float* g1b   = (const float*)d_in[12];
    const float* g1a   = (const float*)d_in[13];
    const float* wm1   = (const float*)d_in[14];
    const float* bm1   = (const float*)d_in[15];
    const float* wm2   = (const float*)d_in[16];
    const float* bm2   = (const float*)d_in[17];
    const float* wm3   = (const float*)d_in[18];
    const float* bm3   = (const float*)d_in[19];
    const float* g3g   = (const float*)d_in[20];
    const float* g3b   = (const float*)d_in[21];
    const float* g3a   = (const float*)d_in[22];
    const float* wdir  = (const float*)d_in[23];
    const float* bdir  = (const float*)d_in[24];
    float* out = (float*)d_out;

    // workspace layout — 128 + 32 + 32 + ~2.3 MiB ≈ 194 MiB (ws = 256 MiB)
    const size_t fixedF = (size_t)kH * kNN;                       // prod floats
    float* prod = (float*)d_ws;                                   // 128 MiB
    unsigned short* X1c = (unsigned short*)(prod + fixedF);       // 32 MiB bf16 (16 ch)
    unsigned short* X2c = X1c + (size_t)kCWb * kNN;               // 32 MiB bf16 (transposed)
    unsigned char* adj  = (unsigned char*)(X2c + (size_t)kCWb * kNN);  // 1 MiB
    unsigned char* adjT = adj + kNN;                                    // 1 MiB
    float* deg   = (float*)(adjT + kNN);
    float* dinv  = deg + kN;
    float* x0    = dinv + kN;
    float* h     = x0 + kN * kH;
    float* agg   = h + kN * kH;
    float* xa    = agg + kN * kH;
    float* xb    = xa + kN * kH;
    float* spart = xb + kN * kH;                 // 1024*64 floats (256 KB)
    float* stats = spart + (size_t)kStatsBlocks * 64;
    float* ss    = stats + 2 * kH;

    hipMemsetAsync(deg, 0, kN * sizeof(float), stream);
    hipMemsetAsync(adj, 0, 2 * kNN, stream);   // adj + adjT contiguous
    hipMemsetAsync(agg, 0, kN * kH * sizeof(float), stream);

    k_edge<<<(kE + 255) / 256, 256, 0, stream>>>(ei, deg, adj, adjT);
    k_dinv<<<4, 256, 0, stream>>>(deg, dinv);
    k_embed<<<kN * kH / 256, 256, 0, stream>>>(x_ids, emb, x0);

    // GCN layer 0
    k_node_mm<<<kN * kH / 256, 256, 0, stream>>>(x0, gw0, h);
    k_scatter<<<kE * kH / 256, 256, 0, stream>>>(ei, h, dinv, agg);
    k_gcn_post<<<kN * kH / 256, 256, 0, stream>>>(agg, h, dinv, gb0);
    k_graphnorm<<<kH, 256, 0, stream>>>(agg, xa, g0g, g0b, g0a, kN);

    // GCN layer 1
    hipMemsetAsync(agg, 0, kN * kH * sizeof(float), stream);
    k_node_mm<<<kN * kH / 256, 256, 0, stream>>>(xa, gw1, h);
    k_scatter<<<kE * kH / 256, 256, 0, stream>>>(ei, h, dinv, agg);
    k_gcn_post<<<kN * kH / 256, 256, 0, stream>>>(agg, h, dinv, gb1);
    k_graphnorm<<<kH, 256, 0, stream>>>(agg, xb, g1g, g1b, g1a, kN);

    // pairwise bf16 features (z-merged, vectorized stores) + 16-channel-batched MFMA GEMMs
    for (int c0 = 0; c0 < kH; c0 += kCWb) {
        k_genxz<kCWg><<<dim3(4, kN, 4), 256, 0, stream>>>(
            xb, adj, adjT, wm1, bm1, wm2, bm2,
            (__hip_bfloat16*)X1c, (__hip_bfloat16*)X2c, c0);
        k_bgemm_bf16<<<dim3(8, 8, kCWb), 256, 0, stream>>>(X1c, X2c, prod + (size_t)c0 * kNN);
    }

    // gn3 stats: MFMA projection, y never materialized
    k_stats_mfma<<<kStatsBlocks, 256, 0, stream>>>(xb, adj, prod, wm3, bm3, spart);
    k_reduce<<<64, 256, 0, stream>>>(spart, stats);
    k_finalize<<<1, 32, 0, stream>>>(stats, g3g, g3b, g3a, ss);

    // final gather: one wave per query
    k_out<<<kQ / 4, 256, 0, stream>>>(pos, xb, adj, prod, wm3, bm3, ss, wdir, bdir, out);
}

// Round 15
// 434.584 us; speedup vs baseline: 1.7795x; 1.0434x over previous
//
#include <hip/hip_runtime.h>
#include <hip/hip_bf16.h>
#include <cstddef>

constexpr int   kN  = 1024;
constexpr int   kE  = 16384;
constexpr int   kQ  = 8192;
constexpr int   kH  = 32;
constexpr size_t kNN = (size_t)kN * kN;
constexpr float kEPS = 1e-5f;
constexpr int   kCWg = 8;             // genx channels per z-slice (register-proven shape)
constexpr int   kCWb = 16;            // bgemm channels per launch (1024 blocks = 4/CU)
constexpr int   kStatsBlocks = kN;    // one i-row per block

using short8 = __attribute__((ext_vector_type(8))) short;
using f32x4  = __attribute__((ext_vector_type(4))) float;

__device__ __forceinline__ unsigned short f2bf(float f) {
    __hip_bfloat16 h = __float2bfloat16(f);
    return *reinterpret_cast<unsigned short*>(&h);
}

// ---------------- small graph kernels ----------------

__global__ void k_edge(const int* __restrict__ ei, float* __restrict__ deg,
                       unsigned char* __restrict__ adj, unsigned char* __restrict__ adjT) {
    int e = blockIdx.x * 256 + threadIdx.x;
    if (e < kE) {
        int s = ei[e], d = ei[kE + e];
        atomicAdd(&deg[d], 1.0f);
        adj [s * kN + d] = 1;   // eim[s][d]
        adjT[d * kN + s] = 1;   // eim^T
    }
}

__global__ void k_dinv(const float* __restrict__ deg, float* __restrict__ dinv) {
    int n = blockIdx.x * 256 + threadIdx.x;
    if (n < kN) dinv[n] = rsqrtf(deg[n] + 1.0f);
}

__global__ void k_embed(const int* __restrict__ xids, const float* __restrict__ emb,
                        float* __restrict__ x0) {
    int t = blockIdx.x * 256 + threadIdx.x;  // kN*kH threads
    int n = t >> 5, c = t & 31;
    x0[t] = emb[xids[n] * kH + c];
}

// h = x @ W   (kN x 32) @ (32 x 32)
__global__ void k_node_mm(const float* __restrict__ x, const float* __restrict__ W,
                          float* __restrict__ h) {
    __shared__ float Ws[kH * kH];
    int t = threadIdx.x;
    for (int u = t; u < kH * kH; u += 256) Ws[u] = W[u];
    __syncthreads();
    int g = blockIdx.x * 256 + t;
    int n = g >> 5, c = g & 31;
    float acc = 0.f;
#pragma unroll
    for (int d = 0; d < kH; d++) acc = fmaf(x[n * kH + d], Ws[d * kH + c], acc);
    h[g] = acc;
}

__global__ void k_scatter(const int* __restrict__ ei, const float* __restrict__ h,
                          const float* __restrict__ dinv, float* __restrict__ agg) {
    int t = blockIdx.x * 256 + threadIdx.x;  // kE*kH threads
    int e = t >> 5, c = t & 31;
    int s = ei[e], d = ei[kE + e];
    atomicAdd(&agg[d * kH + c], h[s * kH + c] * dinv[s] * dinv[d]);
}

__global__ void k_gcn_post(float* __restrict__ agg, const float* __restrict__ h,
                           const float* __restrict__ dinv, const float* __restrict__ b) {
    int t = blockIdx.x * 256 + threadIdx.x;  // kN*kH
    int n = t >> 5, c = t & 31;
    agg[t] += h[t] * dinv[n] * dinv[n] + b[c];
}

// graphnorm over nodes (per channel), then relu. One block per channel.
__global__ void k_graphnorm(const float* __restrict__ x, float* __restrict__ out,
                            const float* __restrict__ g, const float* __restrict__ b,
                            const float* __restrict__ a, int M) {
    int c = blockIdx.x, t = threadIdx.x;
    float s = 0.f, ss = 0.f;
    for (int m = t; m < M; m += 256) { float v = x[m * kH + c]; s += v; ss += v * v; }
    __shared__ float rs[256], rss[256];
    rs[t] = s; rss[t] = ss;
    __syncthreads();
    for (int o = 128; o > 0; o >>= 1) {
        if (t < o) { rs[t] += rs[t + o]; rss[t] += rss[t + o]; }
        __syncthreads();
    }
    __shared__ float scale, shift;
    if (t == 0) {
        float mu  = rs[0] / (float)M;
        float ac  = a[c];
        float var = rss[0] / (float)M - 2.f * ac * mu * mu + ac * ac * mu * mu;
        float sc  = g[c] * rsqrtf(var + kEPS);
        scale = sc;
        shift = b[c] - sc * ac * mu;
    }
    __syncthreads();
    for (int m = t; m < M; m += 256) {
        float v = scale * x[m * kH + c] + shift;
        out[m * kH + c] = v > 0.f ? v : 0.f;
    }
}

// ---------------- x1 / x2^T generation (bf16, channel-major) ----------------
// R15 structure: coalesced LDS staging of the xn tile (R8-proven) + s_load weights
// (R11-proven) + vectorized stores via LDS transpose (R14). blockIdx.z in [0,4):
// bit0 selects X1 (adj,w1) vs X2^T (adjT,w2), bit1 selects the 8-channel half.
// NOTE: do NOT fuse X1+X2 per-thread (R4/R9: dual accumulators -> 144 VGPR, 3.4x slower).
// NOTE: do NOT read xn rows directly per-thread (R13/R14: lane stride 128B -> 64
// transactions per load instr, VALUBusy 30%, 72 us).

template<int CW>
__global__ __launch_bounds__(256) void k_genxz(
        const float* __restrict__ xn,
        const unsigned char* __restrict__ adj, const unsigned char* __restrict__ adjT,
        const float* __restrict__ w1, const float* __restrict__ b1,
        const float* __restrict__ w2, const float* __restrict__ b2,
        __hip_bfloat16* __restrict__ X1, __hip_bfloat16* __restrict__ X2t, int c0base) {
    static_assert(CW * 32 == 256, "store re-partition assumes CW*32 == blockDim");
    int zc = blockIdx.z;
    int c0 = c0base + (zc >> 1) * CW;
    const unsigned char* adjX = (zc & 1) ? adjT : adj;
    const float* w = (zc & 1) ? w2 : w1;
    const float* b = (zc & 1) ? b2 : b1;
    __hip_bfloat16* X = ((zc & 1) ? X2t : X1) + (size_t)(zc >> 1) * CW * kNN;
    int o = blockIdx.y;
    int t = threadIdx.x;
    int i0 = blockIdx.x * 256;
    int in = i0 + t;

    __shared__ float xis[256][kH + 1];          // +1 pad: (t+d)%32 banks, 2 lanes/bank
    for (int u = t; u < 256 * kH; u += 256)     // fully coalesced: flat consecutive
        xis[u >> 5][u & 31] = xn[(size_t)i0 * kH + u];
    __syncthreads();

    float p[kH];
#pragma unroll
    for (int d = 0; d < kH; d++)
        p[d] = xn[o * kH + d] * xis[t][d];      // xn[o*..] uniform -> SGPR
    float e = (float)adjX[o * kN + in];
    float v[CW];
#pragma unroll
    for (int cc = 0; cc < CW; cc++) v[cc] = b[c0 + cc];
#pragma unroll
    for (int d = 0; d < kH; d++) {
#pragma unroll
        for (int cc = 0; cc < CW; cc++)
            v[cc] = fmaf(p[d], w[d * kH + c0 + cc], v[cc]);   // 32B s_load per d
    }
    __shared__ unsigned short lds[CW][256];
    __syncthreads();                             // xis reads done before lds reuse scope
#pragma unroll
    for (int cc = 0; cc < CW; cc++) {
        float r = fmaf(e, w[32 * kH + c0 + cc], v[cc]);
        lds[cc][t] = f2bf(r > 0.f ? r : 0.f);
    }
    __syncthreads();
    // re-partition: thread t -> channel t>>5, 8-elem segment t&31; one 16B store
    int cc = t >> 5, seg = t & 31;
    short8 val = *(const short8*)&lds[cc][seg * 8];
    unsigned short* Xp = (unsigned short*)X;
    *(short8*)&Xp[(size_t)cc * kNN + (size_t)o * kN + i0 + seg * 8] = val;
}

// ---------------- bf16 MFMA batched GEMM: C[c] = A[c] @ B[c], B given transposed ----------------
// XCD-aware remap (grid MUST be (8,8,16)): linear b = x+8y+64z, XCD = b&7 (round-robin).
// XCD g owns channels {2g, 2g+1}; C written with non-temporal stores.

__device__ __forceinline__ void g2l16(const unsigned short* g, unsigned short* l) {
    __builtin_amdgcn_global_load_lds(
        (const __attribute__((address_space(1))) void*)g,
        (__attribute__((address_space(3))) void*)l, 16, 0, 0);
}

__global__ __launch_bounds__(256) void k_bgemm_bf16(
        const unsigned short* __restrict__ A_, const unsigned short* __restrict__ Bt_,
        float* __restrict__ C_) {
    int b = blockIdx.x + 8 * blockIdx.y + 64 * blockIdx.z;   // [0,1024)
    int g = b & 7;                  // XCD id under round-robin dispatch
    int r = b >> 3;                 // [0,128): per-XCD sequence
    int c = 2 * g + (r >> 6);       // channel
    int tile = r & 63;
    int j0 = (tile & 7) * 128;
    int i0 = (tile >> 3) * 128;
    const unsigned short* A  = A_  + (size_t)c * kNN;
    const unsigned short* Bt = Bt_ + (size_t)c * kNN;
    float* C = C_ + (size_t)c * kNN;
    __shared__ unsigned short As[128 * 32];
    __shared__ unsigned short Bs[128 * 32];
    int t = threadIdx.x;
    int lane = t & 63, w = t >> 6;
    int wr = (w >> 1) * 64, wc = (w & 1) * 64;
    int l15 = lane & 15, lhi = lane >> 4;  // 0..3
    int srow = t >> 2, skel = (t & 3) * 8;
    f32x4 acc[4][4] = {};
    for (int k0 = 0; k0 < kN; k0 += 32) {
        g2l16(A  + (size_t)(i0 + srow)      * kN + k0 + skel, As + (size_t)t * 8);
        g2l16(A  + (size_t)(i0 + srow + 64) * kN + k0 + skel, As + (size_t)(t + 256) * 8);
        g2l16(Bt + (size_t)(j0 + srow)      * kN + k0 + skel, Bs + (size_t)t * 8);
        g2l16(Bt + (size_t)(j0 + srow + 64) * kN + k0 + skel, Bs + (size_t)(t + 256) * 8);
        asm volatile("s_waitcnt vmcnt(0)" ::: "memory");
        __syncthreads();
        short8 af[4], bf[4];
#pragma unroll
        for (int m = 0; m < 4; m++)
            af[m] = *(const short8*)&As[(wr + m * 16 + l15) * 32 + lhi * 8];
#pragma unroll
        for (int n = 0; n < 4; n++)
            bf[n] = *(const short8*)&Bs[(wc + n * 16 + l15) * 32 + lhi * 8];
#pragma unroll
        for (int m = 0; m < 4; m++)
#pragma unroll
            for (int n = 0; n < 4; n++)
                acc[m][n] = __builtin_amdgcn_mfma_f32_16x16x32_bf16(af[m], bf[n], acc[m][n], 0, 0, 0);
        __syncthreads();
    }
#pragma unroll
    for (int m = 0; m < 4; m++) {
        int row = i0 + wr + m * 16 + lhi * 4;
#pragma unroll
        for (int n = 0; n < 4; n++) {
            int col = j0 + wc + n * 16 + l15;
#pragma unroll
            for (int r2 = 0; r2 < 4; r2++)
                __builtin_nontemporal_store(acc[m][n][r2],
                                            &C[(size_t)(row + r2) * kN + col]);
        }
    }
}

// ---------------- gn3 statistics via MFMA (R8-proven) ----------------

__global__ __launch_bounds__(256) void k_stats_mfma(
        const float* __restrict__ xn, const unsigned char* __restrict__ adj,
        const float* __restrict__ prod, const float* __restrict__ w3,
        const float* __restrict__ b3, float* __restrict__ spart) {
    __shared__ unsigned short As[128 * 104];   // 26.6 KB feat tile
    __shared__ unsigned short Bs[32 * 104];    // 6.7 KB W3aug^T [c][k]
    __shared__ float xi[kH], lsum[kH], lssq[kH];
    int t = threadIdx.x;
    int i = blockIdx.x;
    int lane = t & 63, w = t >> 6;
    int l15 = lane & 15, lhi = lane >> 4;

    for (int u = t; u < 128 * 104 / 8; u += 256)
        *(short8*)&As[u * 8] = short8{0, 0, 0, 0, 0, 0, 0, 0};
    {   // W3aug^T: c = t&31, s-range (t>>5)*13..+13
        int c = t & 31, s0 = (t >> 5) * 13;
        for (int s = s0; s < s0 + 13; s++) {
            float v = 0.f;
            if (s <= 32)                 v = w3[s * kH + c];
            else if (s >= 34 && s <= 65) v = w3[(s - 1) * kH + c];
            else if (s == 66)            v = b3[c];
            Bs[c * 104 + s] = f2bf(v);
        }
    }
    if (t < kH) { xi[t] = xn[i * kH + t]; lsum[t] = 0.f; lssq[t] = 0.f; }
    __syncthreads();
    if (t < 128) As[t * 104 + 66] = f2bf(1.0f);   // bias column (persists)

    float s2[2] = {0.f, 0.f}, q22[2] = {0.f, 0.f};
    int wrow = w * 32;

    for (int kt = 0; kt < 8; kt++) {
        int kbase = kt * 128;
        {   // stage p (slots 0..31)
            int r = t >> 1, half = t & 1;
            int k = kbase + r;
            const float* xr = &xn[k * kH + half * 16];
            float4 v0 = *(const float4*)&xr[0];
            float4 v1 = *(const float4*)&xr[4];
            float4 v2 = *(const float4*)&xr[8];
            float4 v3 = *(const float4*)&xr[12];
            const float* xih = &xi[half * 16];
            short8 o0, o1;
            o0[0] = f2bf(xih[0] * v0.x);  o0[1] = f2bf(xih[1] * v0.y);
            o0[2] = f2bf(xih[2] * v0.z);  o0[3] = f2bf(xih[3] * v0.w);
            o0[4] = f2bf(xih[4] * v1.x);  o0[5] = f2bf(xih[5] * v1.y);
            o0[6] = f2bf(xih[6] * v1.z);  o0[7] = f2bf(xih[7] * v1.w);
            o1[0] = f2bf(xih[8] * v2.x);  o1[1] = f2bf(xih[9] * v2.y);
            o1[2] = f2bf(xih[10] * v2.z); o1[3] = f2bf(xih[11] * v2.w);
            o1[4] = f2bf(xih[12] * v3.x); o1[5] = f2bf(xih[13] * v3.y);
            o1[6] = f2bf(xih[14] * v3.z); o1[7] = f2bf(xih[15] * v3.w);
            *(short8*)&As[r * 104 + half * 16]     = o0;
            *(short8*)&As[r * 104 + half * 16 + 8] = o1;
        }
        if (t < 128) As[t * 104 + 32] = f2bf((float)adj[i * kN + kbase + t]);
        {   // stage pr (slots 34..65)
            int kq = t & 15, dp = t >> 4, d2 = dp * 2;
            const float* p0 = &prod[(size_t)d2 * kNN + (size_t)i * kN + kbase + kq * 8];
            const float* p1 = p0 + kNN;
            float4 a0 = *(const float4*)&p0[0];
            float4 a1 = *(const float4*)&p0[4];
            float4 b0 = *(const float4*)&p1[0];
            float4 b1 = *(const float4*)&p1[4];
            float r0[8] = {a0.x, a0.y, a0.z, a0.w, a1.x, a1.y, a1.z, a1.w};
            float r1[8] = {b0.x, b0.y, b0.z, b0.w, b1.x, b1.y, b1.z, b1.w};
            unsigned int* As32 = (unsigned int*)As;
#pragma unroll
            for (int j = 0; j < 8; j++) {
                int jr = (j + kq) & 7;
                int kl = kq * 8 + jr;
                unsigned int val = (unsigned int)f2bf(r0[jr]) |
                                   ((unsigned int)f2bf(r1[jr]) << 16);
                As32[kl * 52 + 17 + dp] = val;
            }
        }
        __syncthreads();
        f32x4 acc[2][2] = {};
#pragma unroll
        for (int ks = 0; ks < 3; ks++) {
            short8 af0 = *(const short8*)&As[(wrow + l15) * 104 + ks * 32 + lhi * 8];
            short8 af1 = *(const short8*)&As[(wrow + 16 + l15) * 104 + ks * 32 + lhi * 8];
            short8 bf0 = *(const short8*)&Bs[l15 * 104 + ks * 32 + lhi * 8];
            short8 bf1 = *(const short8*)&Bs[(16 + l15) * 104 + ks * 32 + lhi * 8];
            acc[0][0] = __builtin_amdgcn_mfma_f32_16x16x32_bf16(af0, bf0, acc[0][0], 0, 0, 0);
            acc[0][1] = __builtin_amdgcn_mfma_f32_16x16x32_bf16(af0, bf1, acc[0][1], 0, 0, 0);
            acc[1][0] = __builtin_amdgcn_mfma_f32_16x16x32_bf16(af1, bf0, acc[1][0], 0, 0, 0);
            acc[1][1] = __builtin_amdgcn_mfma_f32_16x16x32_bf16(af1, bf1, acc[1][1], 0, 0, 0);
        }
#pragma unroll
        for (int ct = 0; ct < 2; ct++)
#pragma unroll
            for (int rt = 0; rt < 2; rt++)
#pragma unroll
                for (int r = 0; r < 4; r++) {
                    float y = acc[rt][ct][r];
                    s2[ct] += y;
                    q22[ct] = fmaf(y, y, q22[ct]);
                }
        __syncthreads();
    }
#pragma unroll
    for (int ct = 0; ct < 2; ct++) {
        s2[ct]  += __shfl_xor(s2[ct], 16);  s2[ct]  += __shfl_xor(s2[ct], 32);
        q22[ct] += __shfl_xor(q22[ct], 16); q22[ct] += __shfl_xor(q22[ct], 32);
    }
    if (lane < 16) {
#pragma unroll
        for (int ct = 0; ct < 2; ct++) {
            atomicAdd(&lsum[ct * 16 + l15], s2[ct]);
            atomicAdd(&lssq[ct * 16 + l15], q22[ct]);
        }
    }
    __syncthreads();
    if (t < kH)          spart[(size_t)i * 64 + t]             = lsum[t];
    else if (t < 2 * kH) spart[(size_t)i * 64 + 32 + (t - kH)] = lssq[t - kH];
}

// parallel reduce spart[1024][64] -> stats[64]
__global__ __launch_bounds__(256) void k_reduce(const float* __restrict__ spart,
                                                float* __restrict__ stats) {
    int slot = blockIdx.x;   // 64 blocks
    int t = threadIdx.x;
    float acc = 0.f;
    for (int r = t; r < kStatsBlocks; r += 256) acc += spart[(size_t)r * 64 + slot];
    __shared__ float red[256];
    red[t] = acc;
    __syncthreads();
    for (int o = 128; o > 0; o >>= 1) {
        if (t < o) red[t] += red[t + o];
        __syncthreads();
    }
    if (t == 0) stats[slot] = red[0];
}

__global__ void k_finalize(const float* __restrict__ stats, const float* __restrict__ g,
                           const float* __restrict__ b, const float* __restrict__ a,
                           float* __restrict__ ss) {
    int c = threadIdx.x;  // 32 threads
    float M   = (float)((double)kNN);
    float mu  = stats[c] / M;
    float ac  = a[c];
    float var = stats[kH + c] / M - 2.f * ac * mu * mu + ac * ac * mu * mu;
    float sc  = g[c] * rsqrtf(var + kEPS);
    ss[c]      = sc;
    ss[kH + c] = b[c] - sc * ac * mu;
}

// ---------------- final: one wave per query (R9-verified) ----------------

__global__ __launch_bounds__(256) void k_out(
        const int* __restrict__ pos, const float* __restrict__ xn,
        const unsigned char* __restrict__ adj, const float* __restrict__ prod,
        const float* __restrict__ w3, const float* __restrict__ b3,
        const float* __restrict__ ss, const float* __restrict__ wdir,
        const float* __restrict__ bdir, float* __restrict__ out) {
    __shared__ float W3s[65 * kH], b3s[kH], scs[kH], shs[kH], wd[kH];
    int t = threadIdx.x;
    for (int u = t; u < 65 * kH; u += 256) W3s[u] = w3[u];
    if (t < kH) { b3s[t] = b3[t]; scs[t] = ss[t]; shs[t] = ss[kH + t]; wd[t] = wdir[t]; }
    __syncthreads();
    int q = blockIdx.x * 4 + (t >> 6);
    int lane = t & 63;
    int c = lane & 31, h = lane >> 5;
    int i = pos[2 * q], k = pos[2 * q + 1];
    size_t addr = h ? ((size_t)k * kN + i) : ((size_t)i * kN + k);
    float pr_reg = prod[(size_t)c * kNN + addr];      // my direction, channel index c
    float p_reg  = xn[i * kH + c] * xn[k * kH + c];   // symmetric in (i,k)
    float e_reg  = (float)adj[addr];
    float y = b3s[c];
#pragma unroll
    for (int d = 0; d < kH; d++)
        y = fmaf(__shfl(p_reg, d), W3s[d * kH + c], y);
    y = fmaf(e_reg, W3s[32 * kH + c], y);
#pragma unroll
    for (int d = 0; d < kH; d++)
        y = fmaf(__shfl(pr_reg, (h << 5) + d), W3s[(33 + d) * kH + c], y);
    float z = scs[c] * y + shs[c];
    z = z > 0.f ? z : 0.f;
    float zo = __shfl_xor(z, 32);        // other direction, same channel
    float v = z * zo * wd[c];
#pragma unroll
    for (int o = 16; o > 0; o >>= 1) v += __shfl_xor(v, o);
    if (lane == 0) out[q] = v + bdir[0];
}

// ---------------- launch ----------------

extern "C" void kernel_launch(void* const* d_in, const int* in_sizes, int n_in,
                              void* d_out, int out_size, void* d_ws, size_t ws_size,
                              hipStream_t stream) {
    const int*   x_ids = (const int*)d_in[0];
    const int*   ei    = (const int*)d_in[1];
    const int*   pos   = (const int*)d_in[2];
    const float* emb   = (const float*)d_in[3];
    const float* gw0   = (const float*)d_in[4];
    const float* gb0   = (const float*)d_in[5];
    const float* g0g   = (const float*)d_in[6];
    const float* g0b   = (const float*)d_in[7];
    const float* g0a   = (const float*)d_in[8];
    const float* gw1   = (const float*)d_in[9];
    const float* gb1   = (const float*)d_in[10];
    const float* g1g   = (const float*)d_in[11];
    const float* g1b   = (const float*)d_in[12];
    const float* g1a   = (const float*)d_in[13];
    const float* wm1   = (const float*)d_in[14];
    const float* bm1   = (const float*)d_in[15];
    const float* wm2   = (const float*)d_in[16];
    const float* bm2   = (const float*)d_in[17];
    const float* wm3   = (const float*)d_in[18];
    const float* bm3   = (const float*)d_in[19];
    const float* g3g   = (const float*)d_in[20];
    const float* g3b   = (const float*)d_in[21];
    const float* g3a   = (const float*)d_in[22];
    const float* wdir  = (const float*)d_in[23];
    const float* bdir  = (const float*)d_in[24];
    float* out = (float*)d_out;

    // workspace layout — 128 + 32 + 32 + ~2.3 MiB ≈ 194 MiB (ws = 256 MiB)
    const size_t fixedF = (size_t)kH * kNN;                       // prod floats
    float* prod = (float*)d_ws;                                   // 128 MiB
    unsigned short* X1c = (unsigned short*)(prod + fixedF);       // 32 MiB bf16 (16 ch)
    unsigned short* X2c = X1c + (size_t)kCWb * kNN;               // 32 MiB bf16 (transposed)
    unsigned char* adj  = (unsigned char*)(X2c + (size_t)kCWb * kNN);  // 1 MiB
    unsigned char* adjT = adj + kNN;                                    // 1 MiB
    float* deg   = (float*)(adjT + kNN);
    float* dinv  = deg + kN;
    float* x0    = dinv + kN;
    float* h     = x0 + kN * kH;
    float* agg   = h + kN * kH;
    float* xa    = agg + kN * kH;
    float* xb    = xa + kN * kH;
    float* spart = xb + kN * kH;                 // 1024*64 floats (256 KB)
    float* stats = spart + (size_t)kStatsBlocks * 64;
    float* ss    = stats + 2 * kH;

    hipMemsetAsync(deg, 0, kN * sizeof(float), stream);
    hipMemsetAsync(adj, 0, 2 * kNN, stream);   // adj + adjT contiguous
    hipMemsetAsync(agg, 0, kN * kH * sizeof(float), stream);

    k_edge<<<(kE + 255) / 256, 256, 0, stream>>>(ei, deg, adj, adjT);
    k_dinv<<<4, 256, 0, stream>>>(deg, dinv);
    k_embed<<<kN * kH / 256, 256, 0, stream>>>(x_ids, emb, x0);

    // GCN layer 0
    k_node_mm<<<kN * kH / 256, 256, 0, stream>>>(x0, gw0, h);
    k_scatter<<<kE * kH / 256, 256, 0, stream>>>(ei, h, dinv, agg);
    k_gcn_post<<<kN * kH / 256, 256, 0, stream>>>(agg, h, dinv, gb0);
    k_graphnorm<<<kH, 256, 0, stream>>>(agg, xa, g0g, g0b, g0a, kN);

    // GCN layer 1
    hipMemsetAsync(agg, 0, kN * kH * sizeof(float), stream);
    k_node_mm<<<kN * kH / 256, 256, 0, stream>>>(xa, gw1, h);
    k_scatter<<<kE * kH / 256, 256, 0, stream>>>(ei, h, dinv, agg);
    k_gcn_post<<<kN * kH / 256, 256, 0, stream>>>(agg, h, dinv, gb1);
    k_graphnorm<<<kH, 256, 0, stream>>>(agg, xb, g1g, g1b, g1a, kN);

    // pairwise bf16 features (coalesced-staged) + 16-channel-batched MFMA GEMMs
    for (int c0 = 0; c0 < kH; c0 += kCWb) {
        k_genxz<kCWg><<<dim3(4, kN, 4), 256, 0, stream>>>(
            xb, adj, adjT, wm1, bm1, wm2, bm2,
            (__hip_bfloat16*)X1c, (__hip_bfloat16*)X2c, c0);
        k_bgemm_bf16<<<dim3(8, 8, kCWb), 256, 0, stream>>>(X1c, X2c, prod + (size_t)c0 * kNN);
    }

    // gn3 stats: MFMA projection, y never materialized
    k_stats_mfma<<<kStatsBlocks, 256, 0, stream>>>(xb, adj, prod, wm3, bm3, spart);
    k_reduce<<<64, 256, 0, stream>>>(spart, stats);
    k_finalize<<<1, 32, 0, stream>>>(stats, g3g, g3b, g3a, ss);

    // final gather: one wave per query
    k_out<<<kQ / 4, 256, 0, stream>>>(pos, xb, adj, prod, wm3, bm3, ss, wdir, bdir, out);
}

// Round 16
// 412.970 us; speedup vs baseline: 1.8727x; 1.0523x over previous
//
#include <hip/hip_runtime.h>
#include <hip/hip_bf16.h>
#include <cstddef>

constexpr int   kN  = 1024;
constexpr int   kE  = 16384;
constexpr int   kQ  = 8192;
constexpr int   kH  = 32;
constexpr size_t kNN = (size_t)kN * kN;
constexpr float kEPS = 1e-5f;
constexpr int   kCWg = 8;             // genx channels per z-slice (register-proven shape)
constexpr int   kCWb = 16;            // bgemm channels per launch (1024 blocks = 4/CU)
constexpr int   kStatsBlocks = kN;    // one i-row per block

using short8 = __attribute__((ext_vector_type(8))) short;
using f32x4  = __attribute__((ext_vector_type(4))) float;

__device__ __forceinline__ unsigned short f2bf(float f) {
    __hip_bfloat16 h = __float2bfloat16(f);
    return *reinterpret_cast<unsigned short*>(&h);
}

// ---------------- small graph kernels ----------------

__global__ void k_edge(const int* __restrict__ ei, float* __restrict__ deg,
                       unsigned char* __restrict__ adj, unsigned char* __restrict__ adjT) {
    int e = blockIdx.x * 256 + threadIdx.x;
    if (e < kE) {
        int s = ei[e], d = ei[kE + e];
        atomicAdd(&deg[d], 1.0f);
        adj [s * kN + d] = 1;   // eim[s][d]
        adjT[d * kN + s] = 1;   // eim^T
    }
}

__global__ void k_dinv(const float* __restrict__ deg, float* __restrict__ dinv) {
    int n = blockIdx.x * 256 + threadIdx.x;
    if (n < kN) dinv[n] = rsqrtf(deg[n] + 1.0f);
}

__global__ void k_embed(const int* __restrict__ xids, const float* __restrict__ emb,
                        float* __restrict__ x0) {
    int t = blockIdx.x * 256 + threadIdx.x;  // kN*kH threads
    int n = t >> 5, c = t & 31;
    x0[t] = emb[xids[n] * kH + c];
}

// h = x @ W   (kN x 32) @ (32 x 32)
__global__ void k_node_mm(const float* __restrict__ x, const float* __restrict__ W,
                          float* __restrict__ h) {
    __shared__ float Ws[kH * kH];
    int t = threadIdx.x;
    for (int u = t; u < kH * kH; u += 256) Ws[u] = W[u];
    __syncthreads();
    int g = blockIdx.x * 256 + t;
    int n = g >> 5, c = g & 31;
    float acc = 0.f;
#pragma unroll
    for (int d = 0; d < kH; d++) acc = fmaf(x[n * kH + d], Ws[d * kH + c], acc);
    h[g] = acc;
}

__global__ void k_scatter(const int* __restrict__ ei, const float* __restrict__ h,
                          const float* __restrict__ dinv, float* __restrict__ agg) {
    int t = blockIdx.x * 256 + threadIdx.x;  // kE*kH threads
    int e = t >> 5, c = t & 31;
    int s = ei[e], d = ei[kE + e];
    atomicAdd(&agg[d * kH + c], h[s * kH + c] * dinv[s] * dinv[d]);
}

__global__ void k_gcn_post(float* __restrict__ agg, const float* __restrict__ h,
                           const float* __restrict__ dinv, const float* __restrict__ b) {
    int t = blockIdx.x * 256 + threadIdx.x;  // kN*kH
    int n = t >> 5, c = t & 31;
    agg[t] += h[t] * dinv[n] * dinv[n] + b[c];
}

// graphnorm over nodes (per channel), then relu. One block per channel.
__global__ void k_graphnorm(const float* __restrict__ x, float* __restrict__ out,
                            const float* __restrict__ g, const float* __restrict__ b,
                            const float* __restrict__ a, int M) {
    int c = blockIdx.x, t = threadIdx.x;
    float s = 0.f, ss = 0.f;
    for (int m = t; m < M; m += 256) { float v = x[m * kH + c]; s += v; ss += v * v; }
    __shared__ float rs[256], rss[256];
    rs[t] = s; rss[t] = ss;
    __syncthreads();
    for (int o = 128; o > 0; o >>= 1) {
        if (t < o) { rs[t] += rs[t + o]; rss[t] += rss[t + o]; }
        __syncthreads();
    }
    __shared__ float scale, shift;
    if (t == 0) {
        float mu  = rs[0] / (float)M;
        float ac  = a[c];
        float var = rss[0] / (float)M - 2.f * ac * mu * mu + ac * ac * mu * mu;
        float sc  = g[c] * rsqrtf(var + kEPS);
        scale = sc;
        shift = b[c] - sc * ac * mu;
    }
    __syncthreads();
    for (int m = t; m < M; m += 256) {
        float v = scale * x[m * kH + c] + shift;
        out[m * kH + c] = v > 0.f ? v : 0.f;
    }
}

// ---------------- x1 / x2^T generation (bf16, channel-major) — R15-proven ----------------
// Coalesced LDS staging of xn tile + s_load weights + vectorized stores via LDS.
// NOTE: do NOT fuse X1+X2 per-thread (R4/R9); do NOT read xn rows per-thread (R13/R14).

template<int CW>
__global__ __launch_bounds__(256) void k_genxz(
        const float* __restrict__ xn,
        const unsigned char* __restrict__ adj, const unsigned char* __restrict__ adjT,
        const float* __restrict__ w1, const float* __restrict__ b1,
        const float* __restrict__ w2, const float* __restrict__ b2,
        __hip_bfloat16* __restrict__ X1, __hip_bfloat16* __restrict__ X2t, int c0base) {
    static_assert(CW * 32 == 256, "store re-partition assumes CW*32 == blockDim");
    int zc = blockIdx.z;
    int c0 = c0base + (zc >> 1) * CW;
    const unsigned char* adjX = (zc & 1) ? adjT : adj;
    const float* w = (zc & 1) ? w2 : w1;
    const float* b = (zc & 1) ? b2 : b1;
    __hip_bfloat16* X = ((zc & 1) ? X2t : X1) + (size_t)(zc >> 1) * CW * kNN;
    int o = blockIdx.y;
    int t = threadIdx.x;
    int i0 = blockIdx.x * 256;
    int in = i0 + t;

    __shared__ float xis[256][kH + 1];          // +1 pad: (t+d)%32 banks, 2 lanes/bank
    for (int u = t; u < 256 * kH; u += 256)     // fully coalesced: flat consecutive
        xis[u >> 5][u & 31] = xn[(size_t)i0 * kH + u];
    __syncthreads();

    float p[kH];
#pragma unroll
    for (int d = 0; d < kH; d++)
        p[d] = xn[o * kH + d] * xis[t][d];      // xn[o*..] uniform -> SGPR
    float e = (float)adjX[o * kN + in];
    float v[CW];
#pragma unroll
    for (int cc = 0; cc < CW; cc++) v[cc] = b[c0 + cc];
#pragma unroll
    for (int d = 0; d < kH; d++) {
#pragma unroll
        for (int cc = 0; cc < CW; cc++)
            v[cc] = fmaf(p[d], w[d * kH + c0 + cc], v[cc]);   // 32B s_load per d
    }
    __shared__ unsigned short lds[CW][256];
    __syncthreads();                             // xis reads done before lds reuse scope
#pragma unroll
    for (int cc = 0; cc < CW; cc++) {
        float r = fmaf(e, w[32 * kH + c0 + cc], v[cc]);
        lds[cc][t] = f2bf(r > 0.f ? r : 0.f);
    }
    __syncthreads();
    // re-partition: thread t -> channel t>>5, 8-elem segment t&31; one 16B store
    int cc = t >> 5, seg = t & 31;
    short8 val = *(const short8*)&lds[cc][seg * 8];
    unsigned short* Xp = (unsigned short*)X;
    *(short8*)&Xp[(size_t)cc * kNN + (size_t)o * kN + i0 + seg * 8] = val;
}

// ---------------- bf16 MFMA batched GEMM: C[c] = A[c] @ B[c], B given transposed ----------------
// XCD-aware remap (grid MUST be (8,8,16)): linear b = x+8y+64z, XCD = b&7 (round-robin).
// XCD g owns channels {2g, 2g+1}. BK=64: half the barrier/vmcnt drains of BK=32 (R16).
// Regular C stores (NT stores caused 64B half-line write amplification, 90 vs 64 MB — R15).

__device__ __forceinline__ void g2l16(const unsigned short* g, unsigned short* l) {
    __builtin_amdgcn_global_load_lds(
        (const __attribute__((address_space(1))) void*)g,
        (__attribute__((address_space(3))) void*)l, 16, 0, 0);
}

__global__ __launch_bounds__(256) void k_bgemm_bf16(
        const unsigned short* __restrict__ A_, const unsigned short* __restrict__ Bt_,
        float* __restrict__ C_) {
    int b = blockIdx.x + 8 * blockIdx.y + 64 * blockIdx.z;   // [0,1024)
    int g = b & 7;                  // XCD id under round-robin dispatch
    int r = b >> 3;                 // [0,128): per-XCD sequence
    int c = 2 * g + (r >> 6);       // channel
    int tile = r & 63;
    int j0 = (tile & 7) * 128;
    int i0 = (tile >> 3) * 128;
    const unsigned short* A  = A_  + (size_t)c * kNN;
    const unsigned short* Bt = Bt_ + (size_t)c * kNN;
    float* C = C_ + (size_t)c * kNN;
    __shared__ unsigned short As[128 * 64];   // 16 KB
    __shared__ unsigned short Bs[128 * 64];   // 16 KB
    int t = threadIdx.x;
    int lane = t & 63, w = t >> 6;
    int wr = (w >> 1) * 64, wc = (w & 1) * 64;
    int l15 = lane & 15, lhi = lane >> 4;  // 0..3
    // staging: chunk q -> row q>>3, k-elems (q&7)*8; threads cover q = t, t+256, t+512, t+768
    int srow = t >> 3, skel = (t & 7) * 8;
    f32x4 acc[4][4] = {};
    for (int k0 = 0; k0 < kN; k0 += 64) {
#pragma unroll
        for (int qq = 0; qq < 4; qq++) {
            g2l16(A  + (size_t)(i0 + srow + qq * 32) * kN + k0 + skel,
                  As + ((size_t)t + qq * 256) * 8);
            g2l16(Bt + (size_t)(j0 + srow + qq * 32) * kN + k0 + skel,
                  Bs + ((size_t)t + qq * 256) * 8);
        }
        asm volatile("s_waitcnt vmcnt(0)" ::: "memory");
        __syncthreads();
#pragma unroll
        for (int ks = 0; ks < 2; ks++) {
            short8 af[4], bf[4];
#pragma unroll
            for (int m = 0; m < 4; m++)
                af[m] = *(const short8*)&As[(wr + m * 16 + l15) * 64 + ks * 32 + lhi * 8];
#pragma unroll
            for (int n = 0; n < 4; n++)
                bf[n] = *(const short8*)&Bs[(wc + n * 16 + l15) * 64 + ks * 32 + lhi * 8];
#pragma unroll
            for (int m = 0; m < 4; m++)
#pragma unroll
                for (int n = 0; n < 4; n++)
                    acc[m][n] = __builtin_amdgcn_mfma_f32_16x16x32_bf16(af[m], bf[n], acc[m][n], 0, 0, 0);
        }
        __syncthreads();
    }
#pragma unroll
    for (int m = 0; m < 4; m++) {
        int row = i0 + wr + m * 16 + lhi * 4;
#pragma unroll
        for (int n = 0; n < 4; n++) {
            int col = j0 + wc + n * 16 + l15;
#pragma unroll
            for (int r2 = 0; r2 < 4; r2++)
                C[(size_t)(row + r2) * kN + col] = acc[m][n][r2];
        }
    }
}

// ---------------- gn3 statistics via MFMA (R8-proven) ----------------

__global__ __launch_bounds__(256) void k_stats_mfma(
        const float* __restrict__ xn, const unsigned char* __restrict__ adj,
        const float* __restrict__ prod, const float* __restrict__ w3,
        const float* __restrict__ b3, float* __restrict__ spart) {
    __shared__ unsigned short As[128 * 104];   // 26.6 KB feat tile
    __shared__ unsigned short Bs[32 * 104];    // 6.7 KB W3aug^T [c][k]
    __shared__ float xi[kH], lsum[kH], lssq[kH];
    int t = threadIdx.x;
    int i = blockIdx.x;
    int lane = t & 63, w = t >> 6;
    int l15 = lane & 15, lhi = lane >> 4;

    for (int u = t; u < 128 * 104 / 8; u += 256)
        *(short8*)&As[u * 8] = short8{0, 0, 0, 0, 0, 0, 0, 0};
    {   // W3aug^T: c = t&31, s-range (t>>5)*13..+13
        int c = t & 31, s0 = (t >> 5) * 13;
        for (int s = s0; s < s0 + 13; s++) {
            float v = 0.f;
            if (s <= 32)                 v = w3[s * kH + c];
            else if (s >= 34 && s <= 65) v = w3[(s - 1) * kH + c];
            else if (s == 66)            v = b3[c];
            Bs[c * 104 + s] = f2bf(v);
        }
    }
    if (t < kH) { xi[t] = xn[i * kH + t]; lsum[t] = 0.f; lssq[t] = 0.f; }
    __syncthreads();
    if (t < 128) As[t * 104 + 66] = f2bf(1.0f);   // bias column (persists)

    float s2[2] = {0.f, 0.f}, q22[2] = {0.f, 0.f};
    int wrow = w * 32;

    for (int kt = 0; kt < 8; kt++) {
        int kbase = kt * 128;
        {   // stage p (slots 0..31)
            int r = t >> 1, half = t & 1;
            int k = kbase + r;
            const float* xr = &xn[k * kH + half * 16];
            float4 v0 = *(const float4*)&xr[0];
            float4 v1 = *(const float4*)&xr[4];
            float4 v2 = *(const float4*)&xr[8];
            float4 v3 = *(const float4*)&xr[12];
            const float* xih = &xi[half * 16];
            short8 o0, o1;
            o0[0] = f2bf(xih[0] * v0.x);  o0[1] = f2bf(xih[1] * v0.y);
            o0[2] = f2bf(xih[2] * v0.z);  o0[3] = f2bf(xih[3] * v0.w);
            o0[4] = f2bf(xih[4] * v1.x);  o0[5] = f2bf(xih[5] * v1.y);
            o0[6] = f2bf(xih[6] * v1.z);  o0[7] = f2bf(xih[7] * v1.w);
            o1[0] = f2bf(xih[8] * v2.x);  o1[1] = f2bf(xih[9] * v2.y);
            o1[2] = f2bf(xih[10] * v2.z); o1[3] = f2bf(xih[11] * v2.w);
            o1[4] = f2bf(xih[12] * v3.x); o1[5] = f2bf(xih[13] * v3.y);
            o1[6] = f2bf(xih[14] * v3.z); o1[7] = f2bf(xih[15] * v3.w);
            *(short8*)&As[r * 104 + half * 16]     = o0;
            *(short8*)&As[r * 104 + half * 16 + 8] = o1;
        }
        if (t < 128) As[t * 104 + 32] = f2bf((float)adj[i * kN + kbase + t]);
        {   // stage pr (slots 34..65)
            int kq = t & 15, dp = t >> 4, d2 = dp * 2;
            const float* p0 = &prod[(size_t)d2 * kNN + (size_t)i * kN + kbase + kq * 8];
            const float* p1 = p0 + kNN;
            float4 a0 = *(const float4*)&p0[0];
            float4 a1 = *(const float4*)&p0[4];
            float4 b0 = *(const float4*)&p1[0];
            float4 b1 = *(const float4*)&p1[4];
            float r0[8] = {a0.x, a0.y, a0.z, a0.w, a1.x, a1.y, a1.z, a1.w};
            float r1[8] = {b0.x, b0.y, b0.z, b0.w, b1.x, b1.y, b1.z, b1.w};
            unsigned int* As32 = (unsigned int*)As;
#pragma unroll
            for (int j = 0; j < 8; j++) {
                int jr = (j + kq) & 7;
                int kl = kq * 8 + jr;
                unsigned int val = (unsigned int)f2bf(r0[jr]) |
                                   ((unsigned int)f2bf(r1[jr]) << 16);
                As32[kl * 52 + 17 + dp] = val;
            }
        }
        __syncthreads();
        f32x4 acc[2][2] = {};
#pragma unroll
        for (int ks = 0; ks < 3; ks++) {
            short8 af0 = *(const short8*)&As[(wrow + l15) * 104 + ks * 32 + lhi * 8];
            short8 af1 = *(const short8*)&As[(wrow + 16 + l15) * 104 + ks * 32 + lhi * 8];
            short8 bf0 = *(const short8*)&Bs[l15 * 104 + ks * 32 + lhi * 8];
            short8 bf1 = *(const short8*)&Bs[(16 + l15) * 104 + ks * 32 + lhi * 8];
            acc[0][0] = __builtin_amdgcn_mfma_f32_16x16x32_bf16(af0, bf0, acc[0][0], 0, 0, 0);
            acc[0][1] = __builtin_amdgcn_mfma_f32_16x16x32_bf16(af0, bf1, acc[0][1], 0, 0, 0);
            acc[1][0] = __builtin_amdgcn_mfma_f32_16x16x32_bf16(af1, bf0, acc[1][0], 0, 0, 0);
            acc[1][1] = __builtin_amdgcn_mfma_f32_16x16x32_bf16(af1, bf1, acc[1][1], 0, 0, 0);
        }
#pragma unroll
        for (int ct = 0; ct < 2; ct++)
#pragma unroll
            for (int rt = 0; rt < 2; rt++)
#pragma unroll
                for (int r = 0; r < 4; r++) {
                    float y = acc[rt][ct][r];
                    s2[ct] += y;
                    q22[ct] = fmaf(y, y, q22[ct]);
                }
        __syncthreads();
    }
#pragma unroll
    for (int ct = 0; ct < 2; ct++) {
        s2[ct]  += __shfl_xor(s2[ct], 16);  s2[ct]  += __shfl_xor(s2[ct], 32);
        q22[ct] += __shfl_xor(q22[ct], 16); q22[ct] += __shfl_xor(q22[ct], 32);
    }
    if (lane < 16) {
#pragma unroll
        for (int ct = 0; ct < 2; ct++) {
            atomicAdd(&lsum[ct * 16 + l15], s2[ct]);
            atomicAdd(&lssq[ct * 16 + l15], q22[ct]);
        }
    }
    __syncthreads();
    if (t < kH)          spart[(size_t)i * 64 + t]             = lsum[t];
    else if (t < 2 * kH) spart[(size_t)i * 64 + 32 + (t - kH)] = lssq[t - kH];
}

// parallel reduce spart[1024][64] -> stats[64]
__global__ __launch_bounds__(256) void k_reduce(const float* __restrict__ spart,
                                                float* __restrict__ stats) {
    int slot = blockIdx.x;   // 64 blocks
    int t = threadIdx.x;
    float acc = 0.f;
    for (int r = t; r < kStatsBlocks; r += 256) acc += spart[(size_t)r * 64 + slot];
    __shared__ float red[256];
    red[t] = acc;
    __syncthreads();
    for (int o = 128; o > 0; o >>= 1) {
        if (t < o) red[t] += red[t + o];
        __syncthreads();
    }
    if (t == 0) stats[slot] = red[0];
}

__global__ void k_finalize(const float* __restrict__ stats, const float* __restrict__ g,
                           const float* __restrict__ b, const float* __restrict__ a,
                           float* __restrict__ ss) {
    int c = threadIdx.x;  // 32 threads
    float M   = (float)((double)kNN);
    float mu  = stats[c] / M;
    float ac  = a[c];
    float var = stats[kH + c] / M - 2.f * ac * mu * mu + ac * ac * mu * mu;
    float sc  = g[c] * rsqrtf(var + kEPS);
    ss[c]      = sc;
    ss[kH + c] = b[c] - sc * ac * mu;
}

// ---------------- final: one wave per query (R9-verified) ----------------

__global__ __launch_bounds__(256) void k_out(
        const int* __restrict__ pos, const float* __restrict__ xn,
        const unsigned char* __restrict__ adj, const float* __restrict__ prod,
        const float* __restrict__ w3, const float* __restrict__ b3,
        const float* __restrict__ ss, const float* __restrict__ wdir,
        const float* __restrict__ bdir, float* __restrict__ out) {
    __shared__ float W3s[65 * kH], b3s[kH], scs[kH], shs[kH], wd[kH];
    int t = threadIdx.x;
    for (int u = t; u < 65 * kH; u += 256) W3s[u] = w3[u];
    if (t < kH) { b3s[t] = b3[t]; scs[t] = ss[t]; shs[t] = ss[kH + t]; wd[t] = wdir[t]; }
    __syncthreads();
    int q = blockIdx.x * 4 + (t >> 6);
    int lane = t & 63;
    int c = lane & 31, h = lane >> 5;
    int i = pos[2 * q], k = pos[2 * q + 1];
    size_t addr = h ? ((size_t)k * kN + i) : ((size_t)i * kN + k);
    float pr_reg = prod[(size_t)c * kNN + addr];      // my direction, channel index c
    float p_reg  = xn[i * kH + c] * xn[k * kH + c];   // symmetric in (i,k)
    float e_reg  = (float)adj[addr];
    float y = b3s[c];
#pragma unroll
    for (int d = 0; d < kH; d++)
        y = fmaf(__shfl(p_reg, d), W3s[d * kH + c], y);
    y = fmaf(e_reg, W3s[32 * kH + c], y);
#pragma unroll
    for (int d = 0; d < kH; d++)
        y = fmaf(__shfl(pr_reg, (h << 5) + d), W3s[(33 + d) * kH + c], y);
    float z = scs[c] * y + shs[c];
    z = z > 0.f ? z : 0.f;
    float zo = __shfl_xor(z, 32);        // other direction, same channel
    float v = z * zo * wd[c];
#pragma unroll
    for (int o = 16; o > 0; o >>= 1) v += __shfl_xor(v, o);
    if (lane == 0) out[q] = v + bdir[0];
}

// ---------------- launch ----------------

extern "C" void kernel_launch(void* const* d_in, const int* in_sizes, int n_in,
                              void* d_out, int out_size, void* d_ws, size_t ws_size,
                              hipStream_t stream) {
    const int*   x_ids = (const int*)d_in[0];
    const int*   ei    = (const int*)d_in[1];
    const int*   pos   = (const int*)d_in[2];
    const float* emb   = (const float*)d_in[3];
    const float* gw0   = (const float*)d_in[4];
    const float* gb0   = (const float*)d_in[5];
    const float* g0g   = (const float*)d_in[6];
    const float* g0b   = (const float*)d_in[7];
    const float* g0a   = (const float*)d_in[8];
    const float* gw1   = (const float*)d_in[9];
    const float* gb1   = (const float*)d_in[10];
    const float* g1g   = (const float*)d_in[11];
    const float* g1b   = (const float*)d_in[12];
    const float* g1a   = (const float*)d_in[13];
    const float* wm1   = (const float*)d_in[14];
    const float* bm1   = (const float*)d_in[15];
    const float* wm2   = (const float*)d_in[16];
    const float* bm2   = (const float*)d_in[17];
    const float* wm3   = (const float*)d_in[18];
    const float* bm3   = (const float*)d_in[19];
    const float* g3g   = (const float*)d_in[20];
    const float* g3b   = (const float*)d_in[21];
    const float* g3a   = (const float*)d_in[22];
    const float* wdir  = (const float*)d_in[23];
    const float* bdir  = (const float*)d_in[24];
    float* out = (float*)d_out;

    // workspace layout — 128 + 32 + 32 + ~2.3 MiB ≈ 194 MiB (ws = 256 MiB)
    const size_t fixedF = (size_t)kH * kNN;                       // prod floats
    float* prod = (float*)d_ws;                                   // 128 MiB
    unsigned short* X1c = (unsigned short*)(prod + fixedF);       // 32 MiB bf16 (16 ch)
    unsigned short* X2c = X1c + (size_t)kCWb * kNN;               // 32 MiB bf16 (transposed)
    unsigned char* adj  = (unsigned char*)(X2c + (size_t)kCWb * kNN);  // 1 MiB
    unsigned char* adjT = adj + kNN;                                    // 1 MiB
    float* deg   = (float*)(adjT + kNN);
    float* dinv  = deg + kN;
    float* x0    = dinv + kN;
    float* h     = x0 + kN * kH;
    float* agg   = h + kN * kH;
    float* xa    = agg + kN * kH;
    float* xb    = xa + kN * kH;
    float* spart = xb + kN * kH;                 // 1024*64 floats (256 KB)
    float* stats = spart + (size_t)kStatsBlocks * 64;
    float* ss    = stats + 2 * kH;

    hipMemsetAsync(deg, 0, kN * sizeof(float), stream);
    hipMemsetAsync(adj, 0, 2 * kNN, stream);   // adj + adjT contiguous
    hipMemsetAsync(agg, 0, kN * kH * sizeof(float), stream);

    k_edge<<<(kE + 255) / 256, 256, 0, stream>>>(ei, deg, adj, adjT);
    k_dinv<<<4, 256, 0, stream>>>(deg, dinv);
    k_embed<<<kN * kH / 256, 256, 0, stream>>>(x_ids, emb, x0);

    // GCN layer 0
    k_node_mm<<<kN * kH / 256, 256, 0, stream>>>(x0, gw0, h);
    k_scatter<<<kE * kH / 256, 256, 0, stream>>>(ei, h, dinv, agg);
    k_gcn_post<<<kN * kH / 256, 256, 0, stream>>>(agg, h, dinv, gb0);
    k_graphnorm<<<kH, 256, 0, stream>>>(agg, xa, g0g, g0b, g0a, kN);

    // GCN layer 1
    hipMemsetAsync(agg, 0, kN * kH * sizeof(float), stream);
    k_node_mm<<<kN * kH / 256, 256, 0, stream>>>(xa, gw1, h);
    k_scatter<<<kE * kH / 256, 256, 0, stream>>>(ei, h, dinv, agg);
    k_gcn_post<<<kN * kH / 256, 256, 0, stream>>>(agg, h, dinv, gb1);
    k_graphnorm<<<kH, 256, 0, stream>>>(agg, xb, g1g, g1b, g1a, kN);

    // pairwise bf16 features (coalesced-staged) + 16-channel-batched MFMA GEMMs (BK=64)
    for (int c0 = 0; c0 < kH; c0 += kCWb) {
        k_genxz<kCWg><<<dim3(4, kN, 4), 256, 0, stream>>>(
            xb, adj, adjT, wm1, bm1, wm2, bm2,
            (__hip_bfloat16*)X1c, (__hip_bfloat16*)X2c, c0);
        k_bgemm_bf16<<<dim3(8, 8, kCWb), 256, 0, stream>>>(X1c, X2c, prod + (size_t)c0 * kNN);
    }

    // gn3 stats: MFMA projection, y never materialized
    k_stats_mfma<<<kStatsBlocks, 256, 0, stream>>>(xb, adj, prod, wm3, bm3, spart);
    k_reduce<<<64, 256, 0, stream>>>(spart, stats);
    k_finalize<<<1, 32, 0, stream>>>(stats, g3g, g3b, g3a, ss);

    // final gather: one wave per query
    k_out<<<kQ / 4, 256, 0, stream>>>(pos, xb, adj, prod, wm3, bm3, ss, wdir, bdir, out);
}

// Round 17
// 371.001 us; speedup vs baseline: 2.0845x; 1.1131x over previous
//
#include <hip/hip_runtime.h>
#include <hip/hip_bf16.h>
#include <cstddef>

constexpr int   kN  = 1024;
constexpr int   kE  = 16384;
constexpr int   kQ  = 8192;
constexpr int   kH  = 32;
constexpr size_t kNN = (size_t)kN * kN;
constexpr float kEPS = 1e-5f;
constexpr int   kCWb = 16;            // bgemm channels per launch (1024 blocks = 4/CU)
constexpr int   kStatsBlocks = kN;    // one i-row per block

using short8 = __attribute__((ext_vector_type(8))) short;
using f32x4  = __attribute__((ext_vector_type(4))) float;

__device__ __forceinline__ unsigned short f2bf(float f) {
    __hip_bfloat16 h = __float2bfloat16(f);
    return *reinterpret_cast<unsigned short*>(&h);
}
__device__ __forceinline__ unsigned int packbf2(float a, float b) {
    return (unsigned int)f2bf(a) | ((unsigned int)f2bf(b) << 16);
}

// ---------------- small graph kernels ----------------

__global__ void k_edge(const int* __restrict__ ei, float* __restrict__ deg,
                       unsigned char* __restrict__ adj, unsigned char* __restrict__ adjT) {
    int e = blockIdx.x * 256 + threadIdx.x;
    if (e < kE) {
        int s = ei[e], d = ei[kE + e];
        atomicAdd(&deg[d], 1.0f);
        adj [s * kN + d] = 1;   // eim[s][d]
        adjT[d * kN + s] = 1;   // eim^T
    }
}

__global__ void k_dinv(const float* __restrict__ deg, float* __restrict__ dinv) {
    int n = blockIdx.x * 256 + threadIdx.x;
    if (n < kN) dinv[n] = rsqrtf(deg[n] + 1.0f);
}

__global__ void k_embed(const int* __restrict__ xids, const float* __restrict__ emb,
                        float* __restrict__ x0) {
    int t = blockIdx.x * 256 + threadIdx.x;  // kN*kH threads
    int n = t >> 5, c = t & 31;
    x0[t] = emb[xids[n] * kH + c];
}

// h = x @ W   (kN x 32) @ (32 x 32)
__global__ void k_node_mm(const float* __restrict__ x, const float* __restrict__ W,
                          float* __restrict__ h) {
    __shared__ float Ws[kH * kH];
    int t = threadIdx.x;
    for (int u = t; u < kH * kH; u += 256) Ws[u] = W[u];
    __syncthreads();
    int g = blockIdx.x * 256 + t;
    int n = g >> 5, c = g & 31;
    float acc = 0.f;
#pragma unroll
    for (int d = 0; d < kH; d++) acc = fmaf(x[n * kH + d], Ws[d * kH + c], acc);
    h[g] = acc;
}

__global__ void k_scatter(const int* __restrict__ ei, const float* __restrict__ h,
                          const float* __restrict__ dinv, float* __restrict__ agg) {
    int t = blockIdx.x * 256 + threadIdx.x;  // kE*kH threads
    int e = t >> 5, c = t & 31;
    int s = ei[e], d = ei[kE + e];
    atomicAdd(&agg[d * kH + c], h[s * kH + c] * dinv[s] * dinv[d]);
}

__global__ void k_gcn_post(float* __restrict__ agg, const float* __restrict__ h,
                           const float* __restrict__ dinv, const float* __restrict__ b) {
    int t = blockIdx.x * 256 + threadIdx.x;  // kN*kH
    int n = t >> 5, c = t & 31;
    agg[t] += h[t] * dinv[n] * dinv[n] + b[c];
}

// graphnorm over nodes (per channel), then relu. One block per channel.
__global__ void k_graphnorm(const float* __restrict__ x, float* __restrict__ out,
                            const float* __restrict__ g, const float* __restrict__ b,
                            const float* __restrict__ a, int M) {
    int c = blockIdx.x, t = threadIdx.x;
    float s = 0.f, ss = 0.f;
    for (int m = t; m < M; m += 256) { float v = x[m * kH + c]; s += v; ss += v * v; }
    __shared__ float rs[256], rss[256];
    rs[t] = s; rss[t] = ss;
    __syncthreads();
    for (int o = 128; o > 0; o >>= 1) {
        if (t < o) { rs[t] += rs[t + o]; rss[t] += rss[t + o]; }
        __syncthreads();
    }
    __shared__ float scale, shift;
    if (t == 0) {
        float mu  = rs[0] / (float)M;
        float ac  = a[c];
        float var = rss[0] / (float)M - 2.f * ac * mu * mu + ac * ac * mu * mu;
        float sc  = g[c] * rsqrtf(var + kEPS);
        scale = sc;
        shift = b[c] - sc * ac * mu;
    }
    __syncthreads();
    for (int m = t; m < M; m += 256) {
        float v = scale * x[m * kH + c] + shift;
        out[m * kH + c] = v > 0.f ? v : 0.f;
    }
}

// ---------------- x1 / x2^T generation via MFMA (R17) ----------------
// Per 128-pair tile (o fixed, in = in0..in0+127): feat[row][K=64 pad 72] =
// [p(0..31), e1(32), e2(33), 1(34), 0...]; B[32][72]: n<16 -> W1 ch c0+n (we1@32,
// b1@34), n>=16 -> W2 ch c0+n-16 (we2@33, b2@34). y = feat @ B^T via
// mfma_16x16x32_bf16, relu, bf16, LDS transpose, coalesced stores.
// Replaces the VALU projection (R16: 63.6us/launch at 3x VALU floor).
// NOTE: p,w rounded to bf16 pre-projection (was fp32) — absmax may rise ~2x.

__global__ __launch_bounds__(256) void k_genx_mfma(
        const float* __restrict__ xn,
        const unsigned char* __restrict__ adj, const unsigned char* __restrict__ adjT,
        const float* __restrict__ w1, const float* __restrict__ b1,
        const float* __restrict__ w2, const float* __restrict__ b2,
        unsigned short* __restrict__ X1, unsigned short* __restrict__ X2t, int c0) {
    __shared__ unsigned short As[128 * 72];   // 18.0 KB feat tile
    __shared__ unsigned short Bs[32 * 72];    // 4.5 KB weights
    __shared__ unsigned short outb[32 * 136]; // 8.5 KB output transpose
    int t = threadIdx.x;
    int in0 = blockIdx.x * 128;
    int o   = blockIdx.y;
    int lane = t & 63, w = t >> 6;
    int l15 = lane & 15, lhi = lane >> 4;

    // zero-init feat + weights (pads must be 0)
    for (int u = t; u < 1152; u += 256) *(short8*)&As[u * 8] = short8{0,0,0,0,0,0,0,0};
    for (int u = t; u < 288; u += 256)  *(short8*)&Bs[u * 8] = short8{0,0,0,0,0,0,0,0};
    __syncthreads();

    {   // stage p: thread -> (row = t>>1, half = t&1)
        int row = t >> 1, half = t & 1;
        int in = in0 + row;
        const float* xr = &xn[(size_t)in * kH + half * 16];
        float4 v0 = *(const float4*)&xr[0];
        float4 v1 = *(const float4*)&xr[4];
        float4 v2 = *(const float4*)&xr[8];
        float4 v3 = *(const float4*)&xr[12];
        const float* xo = &xn[(size_t)o * kH + half * 16];   // uniform -> s_load
        short8 o0, o1;
        o0[0] = f2bf(xo[0] * v0.x);  o0[1] = f2bf(xo[1] * v0.y);
        o0[2] = f2bf(xo[2] * v0.z);  o0[3] = f2bf(xo[3] * v0.w);
        o0[4] = f2bf(xo[4] * v1.x);  o0[5] = f2bf(xo[5] * v1.y);
        o0[6] = f2bf(xo[6] * v1.z);  o0[7] = f2bf(xo[7] * v1.w);
        o1[0] = f2bf(xo[8] * v2.x);  o1[1] = f2bf(xo[9] * v2.y);
        o1[2] = f2bf(xo[10] * v2.z); o1[3] = f2bf(xo[11] * v2.w);
        o1[4] = f2bf(xo[12] * v3.x); o1[5] = f2bf(xo[13] * v3.y);
        o1[6] = f2bf(xo[14] * v3.z); o1[7] = f2bf(xo[15] * v3.w);
        *(short8*)&As[row * 72 + half * 16]     = o0;
        *(short8*)&As[row * 72 + half * 16 + 8] = o1;
    }
    if (t < 128) {   // e1, e2, bias-1 slots
        As[t * 72 + 32] = f2bf((float)adj [o * kN + in0 + t]);
        As[t * 72 + 33] = f2bf((float)adjT[o * kN + in0 + t]);
        As[t * 72 + 34] = f2bf(1.0f);
    }
    if (t < 32) {    // B: 32 output rows
        int n = t;
        int ch = c0 + (n & 15);
        const float* wsel = (n < 16) ? w1 : w2;
        const float* bsel = (n < 16) ? b1 : b2;
        for (int d = 0; d < kH; d++) Bs[n * 72 + d] = f2bf(wsel[d * kH + ch]);
        Bs[n * 72 + 32] = (n < 16) ? f2bf(w1[32 * kH + ch]) : (unsigned short)0;
        Bs[n * 72 + 33] = (n < 16) ? (unsigned short)0 : f2bf(w2[32 * kH + ch]);
        Bs[n * 72 + 34] = f2bf(bsel[ch]);
    }
    __syncthreads();

    // MFMA: wave w owns rows w*32..+31 (2 m-frags); N=32 (2 n-frags); K=64 (2 ks)
    int wrow = w * 32;
    f32x4 acc[2][2] = {};
#pragma unroll
    for (int ks = 0; ks < 2; ks++) {
        short8 af0 = *(const short8*)&As[(wrow + l15) * 72 + ks * 32 + lhi * 8];
        short8 af1 = *(const short8*)&As[(wrow + 16 + l15) * 72 + ks * 32 + lhi * 8];
        short8 bf0 = *(const short8*)&Bs[l15 * 72 + ks * 32 + lhi * 8];
        short8 bf1 = *(const short8*)&Bs[(16 + l15) * 72 + ks * 32 + lhi * 8];
        acc[0][0] = __builtin_amdgcn_mfma_f32_16x16x32_bf16(af0, bf0, acc[0][0], 0, 0, 0);
        acc[0][1] = __builtin_amdgcn_mfma_f32_16x16x32_bf16(af0, bf1, acc[0][1], 0, 0, 0);
        acc[1][0] = __builtin_amdgcn_mfma_f32_16x16x32_bf16(af1, bf0, acc[1][0], 0, 0, 0);
        acc[1][1] = __builtin_amdgcn_mfma_f32_16x16x32_bf16(af1, bf1, acc[1][1], 0, 0, 0);
    }
    // relu + bf16-pack -> outb[ch][row] (stride 136 shorts: 16B-aligned, 2-way banks)
    unsigned int* ob32 = (unsigned int*)outb;
#pragma unroll
    for (int mi = 0; mi < 2; mi++) {
        int brow = wrow + mi * 16 + lhi * 4;
#pragma unroll
        for (int nt = 0; nt < 2; nt++) {
            int ch = nt * 16 + l15;
            float y0 = acc[mi][nt][0]; y0 = y0 > 0.f ? y0 : 0.f;
            float y1 = acc[mi][nt][1]; y1 = y1 > 0.f ? y1 : 0.f;
            float y2 = acc[mi][nt][2]; y2 = y2 > 0.f ? y2 : 0.f;
            float y3 = acc[mi][nt][3]; y3 = y3 > 0.f ? y3 : 0.f;
            ob32[ch * 68 + (brow >> 1)]     = packbf2(y0, y1);
            ob32[ch * 68 + (brow >> 1) + 1] = packbf2(y2, y3);
        }
    }
    __syncthreads();
    // coalesced stores: thread -> ch = t>>3, seg = t&7 (16 shorts each)
    {
        int ch = t >> 3, seg = t & 7;
        short8 v0 = *(const short8*)&outb[ch * 136 + seg * 16];
        short8 v1 = *(const short8*)&outb[ch * 136 + seg * 16 + 8];
        unsigned short* base = (ch < 16) ? (X1 + (size_t)ch * kNN)
                                         : (X2t + (size_t)(ch - 16) * kNN);
        size_t off = (size_t)o * kN + in0 + seg * 16;
        *(short8*)&base[off]     = v0;
        *(short8*)&base[off + 8] = v1;
    }
}

// ---------------- bf16 MFMA batched GEMM: C[c] = A[c] @ B[c], B given transposed ----------------
// XCD-aware remap (grid MUST be (8,8,16)): linear b = x+8y+64z, XCD = b&7 (round-robin).
// XCD g owns channels {2g, 2g+1}. BK=64: half the barrier/vmcnt drains of BK=32 (R16).
// Regular C stores (NT stores caused 64B half-line write amplification — R15).

__device__ __forceinline__ void g2l16(const unsigned short* g, unsigned short* l) {
    __builtin_amdgcn_global_load_lds(
        (const __attribute__((address_space(1))) void*)g,
        (__attribute__((address_space(3))) void*)l, 16, 0, 0);
}

__global__ __launch_bounds__(256) void k_bgemm_bf16(
        const unsigned short* __restrict__ A_, const unsigned short* __restrict__ Bt_,
        float* __restrict__ C_) {
    int b = blockIdx.x + 8 * blockIdx.y + 64 * blockIdx.z;   // [0,1024)
    int g = b & 7;                  // XCD id under round-robin dispatch
    int r = b >> 3;                 // [0,128): per-XCD sequence
    int c = 2 * g + (r >> 6);       // channel
    int tile = r & 63;
    int j0 = (tile & 7) * 128;
    int i0 = (tile >> 3) * 128;
    const unsigned short* A  = A_  + (size_t)c * kNN;
    const unsigned short* Bt = Bt_ + (size_t)c * kNN;
    float* C = C_ + (size_t)c * kNN;
    __shared__ unsigned short As[128 * 64];   // 16 KB
    __shared__ unsigned short Bs[128 * 64];   // 16 KB
    int t = threadIdx.x;
    int lane = t & 63, w = t >> 6;
    int wr = (w >> 1) * 64, wc = (w & 1) * 64;
    int l15 = lane & 15, lhi = lane >> 4;  // 0..3
    int srow = t >> 3, skel = (t & 7) * 8;
    f32x4 acc[4][4] = {};
    for (int k0 = 0; k0 < kN; k0 += 64) {
#pragma unroll
        for (int qq = 0; qq < 4; qq++) {
            g2l16(A  + (size_t)(i0 + srow + qq * 32) * kN + k0 + skel,
                  As + ((size_t)t + qq * 256) * 8);
            g2l16(Bt + (size_t)(j0 + srow + qq * 32) * kN + k0 + skel,
                  Bs + ((size_t)t + qq * 256) * 8);
        }
        asm volatile("s_waitcnt vmcnt(0)" ::: "memory");
        __syncthreads();
#pragma unroll
        for (int ks = 0; ks < 2; ks++) {
            short8 af[4], bf[4];
#pragma unroll
            for (int m = 0; m < 4; m++)
                af[m] = *(const short8*)&As[(wr + m * 16 + l15) * 64 + ks * 32 + lhi * 8];
#pragma unroll
            for (int n = 0; n < 4; n++)
                bf[n] = *(const short8*)&Bs[(wc + n * 16 + l15) * 64 + ks * 32 + lhi * 8];
#pragma unroll
            for (int m = 0; m < 4; m++)
#pragma unroll
                for (int n = 0; n < 4; n++)
                    acc[m][n] = __builtin_amdgcn_mfma_f32_16x16x32_bf16(af[m], bf[n], acc[m][n], 0, 0, 0);
        }
        __syncthreads();
    }
#pragma unroll
    for (int m = 0; m < 4; m++) {
        int row = i0 + wr + m * 16 + lhi * 4;
#pragma unroll
        for (int n = 0; n < 4; n++) {
            int col = j0 + wc + n * 16 + l15;
#pragma unroll
            for (int r2 = 0; r2 < 4; r2++)
                C[(size_t)(row + r2) * kN + col] = acc[m][n][r2];
        }
    }
}

// ---------------- gn3 statistics via MFMA (R8-proven) ----------------

__global__ __launch_bounds__(256) void k_stats_mfma(
        const float* __restrict__ xn, const unsigned char* __restrict__ adj,
        const float* __restrict__ prod, const float* __restrict__ w3,
        const float* __restrict__ b3, float* __restrict__ spart) {
    __shared__ unsigned short As[128 * 104];   // 26.6 KB feat tile
    __shared__ unsigned short Bs[32 * 104];    // 6.7 KB W3aug^T [c][k]
    __shared__ float xi[kH], lsum[kH], lssq[kH];
    int t = threadIdx.x;
    int i = blockIdx.x;
    int lane = t & 63, w = t >> 6;
    int l15 = lane & 15, lhi = lane >> 4;

    for (int u = t; u < 128 * 104 / 8; u += 256)
        *(short8*)&As[u * 8] = short8{0, 0, 0, 0, 0, 0, 0, 0};
    {   // W3aug^T: c = t&31, s-range (t>>5)*13..+13
        int c = t & 31, s0 = (t >> 5) * 13;
        for (int s = s0; s < s0 + 13; s++) {
            float v = 0.f;
            if (s <= 32)                 v = w3[s * kH + c];
            else if (s >= 34 && s <= 65) v = w3[(s - 1) * kH + c];
            else if (s == 66)            v = b3[c];
            Bs[c * 104 + s] = f2bf(v);
        }
    }
    if (t < kH) { xi[t] = xn[i * kH + t]; lsum[t] = 0.f; lssq[t] = 0.f; }
    __syncthreads();
    if (t < 128) As[t * 104 + 66] = f2bf(1.0f);   // bias column (persists)

    float s2[2] = {0.f, 0.f}, q22[2] = {0.f, 0.f};
    int wrow = w * 32;

    for (int kt = 0; kt < 8; kt++) {
        int kbase = kt * 128;
        {   // stage p (slots 0..31)
            int r = t >> 1, half = t & 1;
            int k = kbase + r;
            const float* xr = &xn[k * kH + half * 16];
            float4 v0 = *(const float4*)&xr[0];
            float4 v1 = *(const float4*)&xr[4];
            float4 v2 = *(const float4*)&xr[8];
            float4 v3 = *(const float4*)&xr[12];
            const float* xih = &xi[half * 16];
            short8 o0, o1;
            o0[0] = f2bf(xih[0] * v0.x);  o0[1] = f2bf(xih[1] * v0.y);
            o0[2] = f2bf(xih[2] * v0.z);  o0[3] = f2bf(xih[3] * v0.w);
            o0[4] = f2bf(xih[4] * v1.x);  o0[5] = f2bf(xih[5] * v1.y);
            o0[6] = f2bf(xih[6] * v1.z);  o0[7] = f2bf(xih[7] * v1.w);
            o1[0] = f2bf(xih[8] * v2.x);  o1[1] = f2bf(xih[9] * v2.y);
            o1[2] = f2bf(xih[10] * v2.z); o1[3] = f2bf(xih[11] * v2.w);
            o1[4] = f2bf(xih[12] * v3.x); o1[5] = f2bf(xih[13] * v3.y);
            o1[6] = f2bf(xih[14] * v3.z); o1[7] = f2bf(xih[15] * v3.w);
            *(short8*)&As[r * 104 + half * 16]     = o0;
            *(short8*)&As[r * 104 + half * 16 + 8] = o1;
        }
        if (t < 128) As[t * 104 + 32] = f2bf((float)adj[i * kN + kbase + t]);
        {   // stage pr (slots 34..65)
            int kq = t & 15, dp = t >> 4, d2 = dp * 2;
            const float* p0 = &prod[(size_t)d2 * kNN + (size_t)i * kN + kbase + kq * 8];
            const float* p1 = p0 + kNN;
            float4 a0 = *(const float4*)&p0[0];
            float4 a1 = *(const float4*)&p0[4];
            float4 b0 = *(const float4*)&p1[0];
            float4 b1 = *(const float4*)&p1[4];
            float r0[8] = {a0.x, a0.y, a0.z, a0.w, a1.x, a1.y, a1.z, a1.w};
            float r1[8] = {b0.x, b0.y, b0.z, b0.w, b1.x, b1.y, b1.z, b1.w};
            unsigned int* As32 = (unsigned int*)As;
#pragma unroll
            for (int j = 0; j < 8; j++) {
                int jr = (j + kq) & 7;
                int kl = kq * 8 + jr;
                unsigned int val = (unsigned int)f2bf(r0[jr]) |
                                   ((unsigned int)f2bf(r1[jr]) << 16);
                As32[kl * 52 + 17 + dp] = val;
            }
        }
        __syncthreads();
        f32x4 acc[2][2] = {};
#pragma unroll
        for (int ks = 0; ks < 3; ks++) {
            short8 af0 = *(const short8*)&As[(wrow + l15) * 104 + ks * 32 + lhi * 8];
            short8 af1 = *(const short8*)&As[(wrow + 16 + l15) * 104 + ks * 32 + lhi * 8];
            short8 bf0 = *(const short8*)&Bs[l15 * 104 + ks * 32 + lhi * 8];
            short8 bf1 = *(const short8*)&Bs[(16 + l15) * 104 + ks * 32 + lhi * 8];
            acc[0][0] = __builtin_amdgcn_mfma_f32_16x16x32_bf16(af0, bf0, acc[0][0], 0, 0, 0);
            acc[0][1] = __builtin_amdgcn_mfma_f32_16x16x32_bf16(af0, bf1, acc[0][1], 0, 0, 0);
            acc[1][0] = __builtin_amdgcn_mfma_f32_16x16x32_bf16(af1, bf0, acc[1][0], 0, 0, 0);
            acc[1][1] = __builtin_amdgcn_mfma_f32_16x16x32_bf16(af1, bf1, acc[1][1], 0, 0, 0);
        }
#pragma unroll
        for (int ct = 0; ct < 2; ct++)
#pragma unroll
            for (int rt = 0; rt < 2; rt++)
#pragma unroll
                for (int r = 0; r < 4; r++) {
                    float y = acc[rt][ct][r];
                    s2[ct] += y;
                    q22[ct] = fmaf(y, y, q22[ct]);
                }
        __syncthreads();
    }
#pragma unroll
    for (int ct = 0; ct < 2; ct++) {
        s2[ct]  += __shfl_xor(s2[ct], 16);  s2[ct]  += __shfl_xor(s2[ct], 32);
        q22[ct] += __shfl_xor(q22[ct], 16); q22[ct] += __shfl_xor(q22[ct], 32);
    }
    if (lane < 16) {
#pragma unroll
        for (int ct = 0; ct < 2; ct++) {
            atomicAdd(&lsum[ct * 16 + l15], s2[ct]);
            atomicAdd(&lssq[ct * 16 + l15], q22[ct]);
        }
    }
    __syncthreads();
    if (t < kH)          spart[(size_t)i * 64 + t]             = lsum[t];
    else if (t < 2 * kH) spart[(size_t)i * 64 + 32 + (t - kH)] = lssq[t - kH];
}

// parallel reduce spart[1024][64] -> stats[64]
__global__ __launch_bounds__(256) void k_reduce(const float* __restrict__ spart,
                                                float* __restrict__ stats) {
    int slot = blockIdx.x;   // 64 blocks
    int t = threadIdx.x;
    float acc = 0.f;
    for (int r = t; r < kStatsBlocks; r += 256) acc += spart[(size_t)r * 64 + slot];
    __shared__ float red[256];
    red[t] = acc;
    __syncthreads();
    for (int o = 128; o > 0; o >>= 1) {
        if (t < o) red[t] += red[t + o];
        __syncthreads();
    }
    if (t == 0) stats[slot] = red[0];
}

__global__ void k_finalize(const float* __restrict__ stats, const float* __restrict__ g,
                           const float* __restrict__ b, const float* __restrict__ a,
                           float* __restrict__ ss) {
    int c = threadIdx.x;  // 32 threads
    float M   = (float)((double)kNN);
    float mu  = stats[c] / M;
    float ac  = a[c];
    float var = stats[kH + c] / M - 2.f * ac * mu * mu + ac * ac * mu * mu;
    float sc  = g[c] * rsqrtf(var + kEPS);
    ss[c]      = sc;
    ss[kH + c] = b[c] - sc * ac * mu;
}

// ---------------- final: one wave per query (R9-verified) ----------------

__global__ __launch_bounds__(256) void k_out(
        const int* __restrict__ pos, const float* __restrict__ xn,
        const unsigned char* __restrict__ adj, const float* __restrict__ prod,
        const float* __restrict__ w3, const float* __restrict__ b3,
        const float* __restrict__ ss, const float* __restrict__ wdir,
        const float* __restrict__ bdir, float* __restrict__ out) {
    __shared__ float W3s[65 * kH], b3s[kH], scs[kH], shs[kH], wd[kH];
    int t = threadIdx.x;
    for (int u = t; u < 65 * kH; u += 256) W3s[u] = w3[u];
    if (t < kH) { b3s[t] = b3[t]; scs[t] = ss[t]; shs[t] = ss[kH + t]; wd[t] = wdir[t]; }
    __syncthreads();
    int q = blockIdx.x * 4 + (t >> 6);
    int lane = t & 63;
    int c = lane & 31, h = lane >> 5;
    int i = pos[2 * q], k = pos[2 * q + 1];
    size_t addr = h ? ((size_t)k * kN + i) : ((size_t)i * kN + k);
    float pr_reg = prod[(size_t)c * kNN + addr];      // my direction, channel index c
    float p_reg  = xn[i * kH + c] * xn[k * kH + c];   // symmetric in (i,k)
    float e_reg  = (float)adj[addr];
    float y = b3s[c];
#pragma unroll
    for (int d = 0; d < kH; d++)
        y = fmaf(__shfl(p_reg, d), W3s[d * kH + c], y);
    y = fmaf(e_reg, W3s[32 * kH + c], y);
#pragma unroll
    for (int d = 0; d < kH; d++)
        y = fmaf(__shfl(pr_reg, (h << 5) + d), W3s[(33 + d) * kH + c], y);
    float z = scs[c] * y + shs[c];
    z = z > 0.f ? z : 0.f;
    float zo = __shfl_xor(z, 32);        // other direction, same channel
    float v = z * zo * wd[c];
#pragma unroll
    for (int o = 16; o > 0; o >>= 1) v += __shfl_xor(v, o);
    if (lane == 0) out[q] = v + bdir[0];
}

// ---------------- launch ----------------

extern "C" void kernel_launch(void* const* d_in, const int* in_sizes, int n_in,
                              void* d_out, int out_size, void* d_ws, size_t ws_size,
                              hipStream_t stream) {
    const int*   x_ids = (const int*)d_in[0];
    const int*   ei    = (const int*)d_in[1];
    const int*   pos   = (const int*)d_in[2];
    const float* emb   = (const float*)d_in[3];
    const float* gw0   = (const float*)d_in[4];
    const float* gb0   = (const float*)d_in[5];
    const float* g0g   = (const float*)d_in[6];
    const float* g0b   = (const float*)d_in[7];
    const float* g0a   = (const float*)d_in[8];
    const float* gw1   = (const float*)d_in[9];
    const float* gb1   = (const float*)d_in[10];
    const float* g1g   = (const float*)d_in[11];
    const float* g1b   = (const float*)d_in[12];
    const float* g1a   = (const float*)d_in[13];
    const float* wm1   = (const float*)d_in[14];
    const float* bm1   = (const float*)d_in[15];
    const float* wm2   = (const float*)d_in[16];
    const float* bm2   = (const float*)d_in[17];
    const float* wm3   = (const float*)d_in[18];
    const float* bm3   = (const float*)d_in[19];
    const float* g3g   = (const float*)d_in[20];
    const float* g3b   = (const float*)d_in[21];
    const float* g3a   = (const float*)d_in[22];
    const float* wdir  = (const float*)d_in[23];
    const float* bdir  = (const float*)d_in[24];
    float* out = (float*)d_out;

    // workspace layout — 128 + 32 + 32 + ~2.3 MiB ≈ 194 MiB (ws = 256 MiB)
    const size_t fixedF = (size_t)kH * kNN;                       // prod floats
    float* prod = (float*)d_ws;                                   // 128 MiB
    unsigned short* X1c = (unsigned short*)(prod + fixedF);       // 32 MiB bf16 (16 ch)
    unsigned short* X2c = X1c + (size_t)kCWb * kNN;               // 32 MiB bf16 (transposed)
    unsigned char* adj  = (unsigned char*)(X2c + (size_t)kCWb * kNN);  // 1 MiB
    unsigned char* adjT = adj + kNN;                                    // 1 MiB
    float* deg   = (float*)(adjT + kNN);
    float* dinv  = deg + kN;
    float* x0    = dinv + kN;
    float* h     = x0 + kN * kH;
    float* agg   = h + kN * kH;
    float* xa    = agg + kN * kH;
    float* xb    = xa + kN * kH;
    float* spart = xb + kN * kH;                 // 1024*64 floats (256 KB)
    float* stats = spart + (size_t)kStatsBlocks * 64;
    float* ss    = stats + 2 * kH;

    hipMemsetAsync(deg, 0, kN * sizeof(float), stream);
    hipMemsetAsync(adj, 0, 2 * kNN, stream);   // adj + adjT contiguous
    hipMemsetAsync(agg, 0, kN * kH * sizeof(float), stream);

    k_edge<<<(kE + 255) / 256, 256, 0, stream>>>(ei, deg, adj, adjT);
    k_dinv<<<4, 256, 0, stream>>>(deg, dinv);
    k_embed<<<kN * kH / 256, 256, 0, stream>>>(x_ids, emb, x0);

    // GCN layer 0
    k_node_mm<<<kN * kH / 256, 256, 0, stream>>>(x0, gw0, h);
    k_scatter<<<kE * kH / 256, 256, 0, stream>>>(ei, h, dinv, agg);
    k_gcn_post<<<kN * kH / 256, 256, 0, stream>>>(agg, h, dinv, gb0);
    k_graphnorm<<<kH, 256, 0, stream>>>(agg, xa, g0g, g0b, g0a, kN);

    // GCN layer 1
    hipMemsetAsync(agg, 0, kN * kH * sizeof(float), stream);
    k_node_mm<<<kN * kH / 256, 256, 0, stream>>>(xa, gw1, h);
    k_scatter<<<kE * kH / 256, 256, 0, stream>>>(ei, h, dinv, agg);
    k_gcn_post<<<kN * kH / 256, 256, 0, stream>>>(agg, h, dinv, gb1);
    k_graphnorm<<<kH, 256, 0, stream>>>(agg, xb, g1g, g1b, g1a, kN);

    // pairwise bf16 features via MFMA + 16-channel-batched MFMA GEMMs (BK=64)
    for (int c0 = 0; c0 < kH; c0 += kCWb) {
        k_genx_mfma<<<dim3(8, kN), 256, 0, stream>>>(
            xb, adj, adjT, wm1, bm1, wm2, bm2, X1c, X2c, c0);
        k_bgemm_bf16<<<dim3(8, 8, kCWb), 256, 0, stream>>>(X1c, X2c, prod + (size_t)c0 * kNN);
    }

    // gn3 stats: MFMA projection, y never materialized
    k_stats_mfma<<<kStatsBlocks, 256, 0, stream>>>(xb, adj, prod, wm3, bm3, spart);
    k_reduce<<<64, 256, 0, stream>>>(spart, stats);
    k_finalize<<<1, 32, 0, stream>>>(stats, g3g, g3b, g3a, ss);

    // final gather: one wave per query
    k_out<<<kQ / 4, 256, 0, stream>>>(pos, xb, adj, prod, wm3, bm3, ss, wdir, bdir, out);
}